// Round 2
// baseline (3934.608 us; speedup 1.0000x reference)
//
#include <hip/hip_runtime.h>
#include <hip/hip_bf16.h>
#include <stdint.h>

#define BNUM 8
#define PNUM 2048
#define KNN  30
#define KCAND 40
#define NPT  (BNUM*PNUM)   // 16384
#define EPSF 1e-5f

typedef unsigned long long u64;

__device__ __forceinline__ u64 dist_key(float d, int q) {
    unsigned u = __float_as_uint(d);
    u = (u & 0x80000000u) ? ~u : (u | 0x80000000u);   // monotone float->uint
    return ((u64)u << 32) | (unsigned)q;
}

// ---------- f0 = concat(x, pos) ----------
__global__ void k_concat6(const float* __restrict__ x, const float* __restrict__ pos,
                          float* __restrict__ f0) {
    int i = blockIdx.x*256 + threadIdx.x;        // < N*6
    int n = i/6, c = i%6;
    f0[i] = (c < 3) ? x[n*3 + c] : pos[n*3 + c - 3];
}

// ---------- s[n] = sum_c F[n][c]^2 ----------
template<int C>
__global__ void k_snorm(const float* __restrict__ F, float* __restrict__ s) {
    int n = blockIdx.x*256 + threadIdx.x;
    float a = 0.f;
    for (int c = 0; c < C; c++) { float t = F[(size_t)n*C + c]; a += t*t; }
    s[n] = a;
}

// ---------- D[b][p][q] = s_p + s_q - 2 f_p.f_q ; 64x64 tile per block ----------
template<int C>
__global__ __launch_bounds__(256) void k_dist(const float* __restrict__ F,
                                              const float* __restrict__ s,
                                              float* __restrict__ D) {
    __shared__ float FpT[C][68];
    __shared__ float FqT[C][68];
    __shared__ float sp[64], sq[64];
    int b = blockIdx.z;
    int p0 = blockIdx.x*64, q0 = blockIdx.y*64;
    int t = threadIdx.x;
    for (int e = t; e < 64*C; e += 256) {
        int r = e / C, c = e % C;
        FpT[c][r] = F[(size_t)(b*PNUM + p0 + r)*C + c];
        FqT[c][r] = F[(size_t)(b*PNUM + q0 + r)*C + c];
    }
    if (t < 64) { sp[t] = s[b*PNUM + p0 + t]; sq[t] = s[b*PNUM + q0 + t]; }
    __syncthreads();
    int tq = t & 15, tp = t >> 4;
    float acc[4][4] = {};
    for (int c = 0; c < C; c++) {
        float4 fp4 = *(const float4*)&FpT[c][tp*4];
        float4 fq4 = *(const float4*)&FqT[c][tq*4];
        float fp[4] = {fp4.x, fp4.y, fp4.z, fp4.w};
        float fq[4] = {fq4.x, fq4.y, fq4.z, fq4.w};
        #pragma unroll
        for (int i = 0; i < 4; i++)
            #pragma unroll
            for (int j = 0; j < 4; j++) acc[i][j] += fp[i]*fq[j];
    }
    #pragma unroll
    for (int i = 0; i < 4; i++) {
        float4 o;
        float* oo = (float*)&o;
        #pragma unroll
        for (int j = 0; j < 4; j++)
            oo[j] = sp[tp*4 + i] + sq[tq*4 + j] - 2.0f*acc[i][j];
        *(float4*)&D[(size_t)(b*PNUM + p0 + tp*4 + i)*PNUM + q0 + tq*4] = o;
    }
}

// ---------- top-KCAND smallest per row (f32, candidates only) ----------
__global__ __launch_bounds__(256) void k_topk(const float* __restrict__ D, int* __restrict__ cand) {
    __shared__ u64 keys[PNUM];
    __shared__ u64 wred[4];
    int n = blockIdx.x;
    int t = threadIdx.x;
    const float* drow = D + (size_t)n*PNUM;
    #pragma unroll
    for (int j = 0; j < PNUM/256; j++) {
        int q = t + 256*j;
        keys[q] = dist_key(drow[q], q);
    }
    __syncthreads();
    for (int it = 0; it < KCAND; it++) {
        u64 best = ~0ull;
        #pragma unroll
        for (int j = 0; j < PNUM/256; j++) {
            u64 k = keys[t + 256*j];
            best = (k < best) ? k : best;
        }
        #pragma unroll
        for (int off = 32; off >= 1; off >>= 1) {
            u64 o = __shfl_xor(best, off, 64);
            best = (o < best) ? o : best;
        }
        if ((t & 63) == 0) wred[t >> 6] = best;
        __syncthreads();
        if (t == 0) {
            u64 b0 = wred[0];
            for (int w = 1; w < 4; w++) b0 = (wred[w] < b0) ? wred[w] : b0;
            int q = (int)(b0 & 0xffffffffu);
            cand[(size_t)n*KCAND + it] = q;
            keys[q] = ~0ull;
        }
        __syncthreads();
    }
}

// ---------- refine: f64 direct squared distance over 40 candidates, exact top-30 ----------
// one wave per row; lane l holds candidate l
template<int C>
__global__ __launch_bounds__(256) void k_refine(const float* __restrict__ F,
                                                const int* __restrict__ cand,
                                                int* __restrict__ idx) {
    int t = threadIdx.x;
    int lane = t & 63;
    int row = blockIdx.x*4 + (t >> 6);
    int b = row >> 11;
    const float* fp = F + (size_t)row*C;
    bool act = lane < KCAND;
    int q = act ? cand[(size_t)row*KCAND + lane] : 0;
    const float* fq = F + (size_t)(b*PNUM + q)*C;
    double d = 1e300;
    if (act) {
        d = 0.0;
        if (C == 64) {
            #pragma unroll
            for (int c4 = 0; c4 < C/4; c4++) {
                float4 a = ((const float4*)fp)[c4];
                float4 bb = ((const float4*)fq)[c4];
                double d0 = (double)a.x - (double)bb.x;
                double d1 = (double)a.y - (double)bb.y;
                double d2 = (double)a.z - (double)bb.z;
                double d3 = (double)a.w - (double)bb.w;
                d += d0*d0 + d1*d1 + d2*d2 + d3*d3;
            }
        } else {
            #pragma unroll
            for (int c = 0; c < C; c++) {
                double df = (double)fp[c] - (double)fq[c];
                d += df*df;
            }
        }
    }
    for (int it = 0; it < KNN; it++) {
        double m = d;
        #pragma unroll
        for (int off = 32; off >= 1; off >>= 1) {
            double o = __shfl_xor(m, off, 64);
            m = (o < m) ? o : m;
        }
        int cid = (d == m) ? q : 0x7fffffff;
        int cm = cid;
        #pragma unroll
        for (int off = 32; off >= 1; off >>= 1) {
            int o = __shfl_xor(cm, off, 64);
            cm = (o < cm) ? o : cm;
        }
        if (d == m && q == cm) {
            idx[(size_t)row*KNN + it] = q;
            d = 1e300;
        }
    }
}

// ---------- W0c = W0a - W0b ----------
__global__ void k_diffw(const float* __restrict__ W0, float* __restrict__ W0c, int CE) {
    int i = blockIdx.x*256 + threadIdx.x;
    if (i < CE) W0c[i] = W0[i] - W0[CE + i];
}

// ---------- generic tiled f32 GEMM: out = [relu](A[M,Kd] @ W[Kd,Nd] + bias) ----------
template<int RELU>
__global__ __launch_bounds__(256) void k_gemm(const float* __restrict__ A,
                                              const float* __restrict__ W,
                                              const float* __restrict__ bias,
                                              float* __restrict__ out,
                                              int M, int Kd, int Nd) {
    __shared__ float As[64][17];
    __shared__ float Bs[16][64];
    int m0 = blockIdx.x*64, n0 = blockIdx.y*64;
    int t = threadIdx.x;
    int cb = (t & 15)*4, rb = (t >> 4)*4;
    float acc[4][4] = {};
    for (int k0 = 0; k0 < Kd; k0 += 16) {
        #pragma unroll
        for (int j = 0; j < 4; j++) {
            int e = t + 256*j;
            int r = e >> 4, c = e & 15;
            As[r][c] = (k0 + c < Kd) ? A[(size_t)(m0 + r)*Kd + k0 + c] : 0.f;
        }
        #pragma unroll
        for (int j = 0; j < 4; j++) {
            int e = t + 256*j;
            int r = e >> 6, c = e & 63;
            Bs[r][c] = (k0 + r < Kd && n0 + c < Nd) ? W[(size_t)(k0 + r)*Nd + n0 + c] : 0.f;
        }
        __syncthreads();
        #pragma unroll
        for (int kk = 0; kk < 16; kk++) {
            float a[4];
            #pragma unroll
            for (int i = 0; i < 4; i++) a[i] = As[rb + i][kk];
            float4 w4 = *(const float4*)&Bs[kk][cb];
            float w[4] = {w4.x, w4.y, w4.z, w4.w};
            #pragma unroll
            for (int i = 0; i < 4; i++)
                #pragma unroll
                for (int j = 0; j < 4; j++) acc[i][j] += a[i]*w[j];
        }
        __syncthreads();
    }
    #pragma unroll
    for (int i = 0; i < 4; i++) {
        int row = m0 + rb + i;
        #pragma unroll
        for (int j = 0; j < 4; j++) {
            int col = n0 + cb + j;
            if (col < Nd) {
                float v = acc[i][j] + (bias ? bias[col] : 0.f);
                if (RELU) v = fmaxf(v, 0.f);
                out[(size_t)row*Nd + col] = v;
            }
        }
    }
}

// ---------- stats of relu(u_p + v_q) over all edges (stats only; h1 not stored) ----------
__global__ __launch_bounds__(256) void k_e1stats(const float* __restrict__ u,
                                                 const float* __restrict__ v,
                                                 const int* __restrict__ idx,
                                                 float* __restrict__ psum, float* __restrict__ psq) {
    int t = threadIdx.x;
    float s = 0.f, sq = 0.f;
    const int stride = 4096*256;
    int i = blockIdx.x*256 + t;
    #pragma unroll 1
    for (int j = 0; j < 30; j++, i += stride) {   // N*K*64 / (4096*256) = 30 exactly
        int edge = i >> 6, c = i & 63;
        int p = edge / KNN;
        int q = idx[edge];
        int b = p >> 11;
        float h = u[(size_t)p*64 + c] + v[(size_t)(b*PNUM + q)*64 + c];
        h = fmaxf(h, 0.f);
        s += h; sq += h*h;
    }
    __shared__ float rs[256], rq[256];
    rs[t] = s; rq[t] = sq;
    __syncthreads();
    if (t < 128) { rs[t] += rs[t+128]; rq[t] += rq[t+128]; }
    __syncthreads();
    if (t < 64) {
        rs[t] += rs[t+64]; rq[t] += rq[t+64];
        psum[(size_t)blockIdx.x*64 + t] = rs[t];
        psq [(size_t)blockIdx.x*64 + t] = rq[t];
    }
}

// ---------- finalize BN stats ----------
__global__ void k_statsfin(const float* __restrict__ psum, const float* __restrict__ psq,
                           int npart, int C, float invM,
                           const float* __restrict__ g, const float* __restrict__ be,
                           float* __restrict__ scale, float* __restrict__ shift) {
    int c = blockIdx.x, t = threadIdx.x;
    float s = 0.f, q = 0.f;
    for (int i = t; i < npart; i += 256) {
        s += psum[(size_t)i*C + c];
        q += psq [(size_t)i*C + c];
    }
    __shared__ float rs[256], rq[256];
    rs[t] = s; rq[t] = q; __syncthreads();
    for (int off = 128; off >= 1; off >>= 1) {
        if (t < off) { rs[t] += rs[t+off]; rq[t] += rq[t+off]; }
        __syncthreads();
    }
    if (t == 0) {
        float m   = rs[0]*invM;
        float var = rq[0]*invM - m*m;
        float inv = rsqrtf(var + EPSF);
        float sc  = g[c]*inv;
        scale[c] = sc;
        shift[c] = be[c] - m*sc;
    }
}

// ---------- fold BN affine into next linear ----------
__global__ void k_fold(const float* __restrict__ W, const float* __restrict__ b,
                       const float* __restrict__ scale, const float* __restrict__ shift,
                       float* __restrict__ Wp, float* __restrict__ bp, int Cin, int Cout) {
    int co = blockIdx.x, t = threadIdx.x;
    float acc = 0.f;
    for (int ci = t; ci < Cin; ci += 256) {
        float w = W[(size_t)ci*Cout + co];
        Wp[(size_t)ci*Cout + co] = scale[ci]*w;
        acc += shift[ci]*w;
    }
    __shared__ float r[256];
    r[t] = acc; __syncthreads();
    for (int off = 128; off >= 1; off >>= 1) { if (t < off) r[t] += r[t+off]; __syncthreads(); }
    if (t == 0) bp[co] = b[co] + r[0];
}

// ---------- edge layer 1: rebuild h1 tile, GEMM vs folded W1, pool max/min, stats ----------
__global__ __launch_bounds__(256) void k_e2(const float* __restrict__ u, const float* __restrict__ v,
                                            const int* __restrict__ idx,
                                            const float* __restrict__ W1p, const float* __restrict__ b1p,
                                            float* __restrict__ pmax, float* __restrict__ pmin,
                                            float* __restrict__ psum, float* __restrict__ psq) {
    __shared__ float W1s[64][64];
    __shared__ float b1s[64];
    __shared__ float h1s[2][KNN][64];
    __shared__ float us[2][64];
    __shared__ int   idxs[2][KNN];
    __shared__ float rmax[16][64], rmin[16][64], rsum[16][64], rsq[16][64];
    int t = threadIdx.x;
    int n0 = blockIdx.x*2;
    int b = n0 >> 11;
    for (int e = t; e < 4096; e += 256) W1s[e >> 6][e & 63] = W1p[e];
    if (t < 64)  b1s[t] = b1p[t];
    if (t < 128) us[t >> 6][t & 63] = u[(size_t)(n0 + (t >> 6))*64 + (t & 63)];
    if (t < 2*KNN) idxs[t/KNN][t%KNN] = idx[(size_t)(n0 + t/KNN)*KNN + t%KNN];
    __syncthreads();
    for (int e = t; e < 2*KNN*64; e += 256) {
        int pt = e / (KNN*64);
        int r  = e - pt*KNN*64;
        int k  = r >> 6, c = r & 63;
        int q  = idxs[pt][k];
        float h = us[pt][c] + v[(size_t)(b*PNUM + q)*64 + c];
        h1s[pt][k][c] = fmaxf(h, 0.f);
    }
    __syncthreads();
    int co4 = (t & 15)*4;
    int k1 = t >> 4;             // 0..15
    int k2 = k1 + 16;
    bool has2 = (k2 < KNN);
    int k2c = has2 ? k2 : 0;
    float sum_acc = 0.f, sq_acc = 0.f;
    for (int pt = 0; pt < 2; pt++) {
        float a1[4] = {}, a2[4] = {};
        for (int c = 0; c < 64; c++) {
            float f1 = h1s[pt][k1][c];
            float f2 = h1s[pt][k2c][c];
            float4 w4 = *(const float4*)&W1s[c][co4];
            float w[4] = {w4.x, w4.y, w4.z, w4.w};
            #pragma unroll
            for (int j = 0; j < 4; j++) { a1[j] += f1*w[j]; a2[j] += f2*w[j]; }
        }
        #pragma unroll
        for (int j = 0; j < 4; j++) {
            int co = co4 + j;
            float v1 = fmaxf(a1[j] + b1s[co], 0.f);
            float v2 = fmaxf(a2[j] + b1s[co], 0.f);
            rmax[k1][co] = has2 ? fmaxf(v1, v2) : v1;
            rmin[k1][co] = has2 ? fminf(v1, v2) : v1;
            rsum[k1][co] = has2 ? (v1 + v2) : v1;
            rsq [k1][co] = has2 ? (v1*v1 + v2*v2) : v1*v1;
        }
        __syncthreads();
        if (t < 64) {
            float mx = rmax[0][t], mn = rmin[0][t], sm = rsum[0][t], s2 = rsq[0][t];
            #pragma unroll
            for (int kp = 1; kp < 16; kp++) {
                mx = fmaxf(mx, rmax[kp][t]);
                mn = fminf(mn, rmin[kp][t]);
                sm += rsum[kp][t];
                s2 += rsq [kp][t];
            }
            pmax[(size_t)(n0 + pt)*64 + t] = mx;
            pmin[(size_t)(n0 + pt)*64 + t] = mn;
            sum_acc += sm; sq_acc += s2;
        }
        __syncthreads();
    }
    if (t < 64) {
        psum[(size_t)blockIdx.x*64 + t] = sum_acc;
        psq [(size_t)blockIdx.x*64 + t] = sq_acc;
    }
}

// ---------- BN1 applied after pooling (max if scale>=0 else min) ----------
__global__ void k_applypool(const float* __restrict__ pmax, const float* __restrict__ pmin,
                            const float* __restrict__ scale, const float* __restrict__ shift,
                            float* __restrict__ out) {
    int i = blockIdx.x*256 + threadIdx.x;
    int c = i & 63;
    float sc = scale[c];
    float pooled = (sc >= 0.f) ? pmax[i] : pmin[i];
    out[i] = sc*pooled + shift[c];
}

// ---------- Hin = concat(x1,x2,x3) ----------
__global__ void k_concat192(const float* __restrict__ x1, const float* __restrict__ x2,
                            const float* __restrict__ x3, float* __restrict__ H) {
    int i = blockIdx.x*256 + threadIdx.x;
    int n = i / 192, c = i % 192;
    const float* src = (c < 64) ? x1 : (c < 128) ? x2 : x3;
    H[i] = src[(size_t)n*64 + (c & 63)];
}

// ---------- per-column partial sums over 64-row blocks ----------
__global__ void k_colstats(const float* __restrict__ Hbuf, float* __restrict__ psum,
                           float* __restrict__ psq, int Cout) {
    int m0 = blockIdx.x*64, c0 = blockIdx.y*64;
    int t = threadIdx.x;
    int c = t & 63, rg = t >> 6;
    float s = 0.f, q = 0.f;
    #pragma unroll 4
    for (int r = 0; r < 16; r++) {
        float hv = Hbuf[(size_t)(m0 + rg*16 + r)*Cout + c0 + c];
        s += hv; q += hv*hv;
    }
    __shared__ float rs[256], rq[256];
    rs[t] = s; rq[t] = q; __syncthreads();
    if (t < 128) { rs[t] += rs[t+128]; rq[t] += rq[t+128]; }
    __syncthreads();
    if (t < 64) {
        rs[t] += rs[t+64]; rq[t] += rq[t+64];
        psum[(size_t)blockIdx.x*Cout + c0 + t] = rs[t];
        psq [(size_t)blockIdx.x*Cout + c0 + t] = rq[t];
    }
}

// ---------- log_softmax over 50 cols, one wave per row ----------
__global__ void k_logsoftmax(const float* __restrict__ logits, float* __restrict__ out) {
    int t = threadIdx.x;
    int n = blockIdx.x*4 + (t >> 6);
    int l = t & 63;
    float z = (l < 50) ? logits[(size_t)n*50 + l] : -INFINITY;
    float mx = z;
    #pragma unroll
    for (int off = 32; off >= 1; off >>= 1) mx = fmaxf(mx, __shfl_xor(mx, off, 64));
    float ex = (l < 50) ? expf(z - mx) : 0.f;
    float sm = ex;
    #pragma unroll
    for (int off = 32; off >= 1; off >>= 1) sm += __shfl_xor(sm, off, 64);
    float lse = mx + logf(sm);
    if (l < 50) out[(size_t)n*50 + l] = z - lse;
}

extern "C" void kernel_launch(void* const* d_in, const int* in_sizes, int n_in,
                              void* d_out, int out_size, void* d_ws, size_t ws_size,
                              hipStream_t stream) {
    (void)in_sizes; (void)n_in; (void)out_size;
    const float* x   = (const float*)d_in[0];
    const float* pos = (const float*)d_in[1];
    const float* prm[38];
    for (int i = 0; i < 38; i++) prm[i] = (const float*)d_in[3 + i];
    // prm: c1[0..7] c2[8..15] c3[16..23] l1[24..27] h0[28..31] h1[32..35] ho[36..37]

    float* ws = (float*)d_ws;
    size_t off = 0;
    auto alloc = [&](size_t cnt) { float* p = ws + off; off += (cnt + 63) & ~((size_t)63); return p; };
    float* f0   = alloc((size_t)NPT*6);
    float* s    = alloc(NPT);
    float* x1   = alloc((size_t)NPT*64);
    float* x2   = alloc((size_t)NPT*64);
    float* x3   = alloc((size_t)NPT*64);
    float* u    = alloc((size_t)NPT*64);
    float* v    = alloc((size_t)NPT*64);
    float* pmax = alloc((size_t)NPT*64);
    float* pmin = alloc((size_t)NPT*64);
    int*   idx  = (int*)alloc((size_t)NPT*KNN);
    float* W0c  = alloc(64*64);
    float* W1p  = alloc(64*64);
    float* b1p  = alloc(64);
    float* scaleA = alloc(1024);
    float* shiftA = alloc(1024);
    float* Wp   = alloc(1024*256);
    float* bp   = alloc(1024);
    float* psum = alloc(524288);
    float* psq  = alloc(524288);
    float* big  = alloc((size_t)BNUM*PNUM*PNUM);   // shared: D, then head activations
    if (off*sizeof(float) > ws_size) return;       // insufficient workspace -> leave poisoned

    // cand (NPT*KCAND ints = 2.5 MB) aliases psum+psq (4 MB): dead ranges don't overlap in time
    int* cand = (int*)psum;

    auto conv = [&](const float* F, int C, const float* const* pp, float* xout) {
        if (C == 6) k_snorm<6><<<NPT/256, 256, 0, stream>>>(F, s);
        else        k_snorm<64><<<NPT/256, 256, 0, stream>>>(F, s);
        float* D = big;
        if (C == 6) k_dist<6><<<dim3(32,32,8), 256, 0, stream>>>(F, s, D);
        else        k_dist<64><<<dim3(32,32,8), 256, 0, stream>>>(F, s, D);
        k_topk<<<NPT, 256, 0, stream>>>(D, cand);
        if (C == 6) k_refine<6><<<NPT/4, 256, 0, stream>>>(F, cand, idx);
        else        k_refine<64><<<NPT/4, 256, 0, stream>>>(F, cand, idx);
        k_diffw<<<(C*64 + 255)/256, 256, 0, stream>>>(pp[0], W0c, C*64);
        k_gemm<0><<<dim3(NPT/64, 1), 256, 0, stream>>>(F, W0c, pp[1], u, NPT, C, 64);
        k_gemm<0><<<dim3(NPT/64, 1), 256, 0, stream>>>(F, pp[0] + C*64, nullptr, v, NPT, C, 64);
        k_e1stats<<<4096, 256, 0, stream>>>(u, v, idx, psum, psq);
        k_statsfin<<<64, 256, 0, stream>>>(psum, psq, 4096, 64, 1.f/((float)NPT*KNN),
                                           pp[2], pp[3], scaleA, shiftA);
        k_fold<<<64, 256, 0, stream>>>(pp[4], pp[5], scaleA, shiftA, W1p, b1p, 64, 64);
        k_e2<<<NPT/2, 256, 0, stream>>>(u, v, idx, W1p, b1p, pmax, pmin, psum, psq);
        k_statsfin<<<64, 256, 0, stream>>>(psum, psq, NPT/2, 64, 1.f/((float)NPT*KNN),
                                           pp[6], pp[7], scaleA, shiftA);
        k_applypool<<<NPT*64/256, 256, 0, stream>>>(pmax, pmin, scaleA, shiftA, xout);
    };

    k_concat6<<<NPT*6/256, 256, 0, stream>>>(x, pos, f0);
    conv(f0, 6,  &prm[0],  x1);
    conv(x1, 64, &prm[8],  x2);
    conv(x2, 64, &prm[16], x3);

    float* Hin    = big;
    float* Hb1    = big + 3145728;
    float* Hb2    = big + 19922944;
    float* Hb3    = big + 24117248;
    float* logits = big + 26214400;

    k_concat192<<<NPT*192/256, 256, 0, stream>>>(x1, x2, x3, Hin);
    k_gemm<1><<<dim3(NPT/64, 16), 256, 0, stream>>>(Hin, prm[24], prm[25], Hb1, NPT, 192, 1024);
    k_colstats<<<dim3(NPT/64, 16), 256, 0, stream>>>(Hb1, psum, psq, 1024);
    k_statsfin<<<1024, 256, 0, stream>>>(psum, psq, NPT/64, 1024, 1.f/(float)NPT,
                                         prm[26], prm[27], scaleA, shiftA);
    k_fold<<<256, 256, 0, stream>>>(prm[28], prm[29], scaleA, shiftA, Wp, bp, 1024, 256);
    k_gemm<1><<<dim3(NPT/64, 4), 256, 0, stream>>>(Hb1, Wp, bp, Hb2, NPT, 1024, 256);
    k_colstats<<<dim3(NPT/64, 4), 256, 0, stream>>>(Hb2, psum, psq, 256);
    k_statsfin<<<256, 256, 0, stream>>>(psum, psq, NPT/64, 256, 1.f/(float)NPT,
                                        prm[30], prm[31], scaleA, shiftA);
    k_fold<<<128, 256, 0, stream>>>(prm[32], prm[33], scaleA, shiftA, Wp, bp, 256, 128);
    k_gemm<1><<<dim3(NPT/64, 2), 256, 0, stream>>>(Hb2, Wp, bp, Hb3, NPT, 256, 128);
    k_colstats<<<dim3(NPT/64, 2), 256, 0, stream>>>(Hb3, psum, psq, 128);
    k_statsfin<<<128, 256, 0, stream>>>(psum, psq, NPT/64, 128, 1.f/(float)NPT,
                                        prm[34], prm[35], scaleA, shiftA);
    k_fold<<<50, 256, 0, stream>>>(prm[36], prm[37], scaleA, shiftA, Wp, bp, 128, 50);
    k_gemm<0><<<dim3(NPT/64, 1), 256, 0, stream>>>(Hb3, Wp, bp, logits, NPT, 128, 50);
    k_logsoftmax<<<NPT/4, 256, 0, stream>>>(logits, (float*)d_out);
}

// Round 3
// 2741.456 us; speedup vs baseline: 1.4352x; 1.4352x over previous
//
#include <hip/hip_runtime.h>
#include <hip/hip_bf16.h>
#include <stdint.h>

#define BNUM 8
#define PNUM 2048
#define KNN  30
#define KSEL 40      // rank threshold for candidate selection
#define KCAP 64      // max candidates per row (one wave)
#define NPT  (BNUM*PNUM)   // 16384
#define EPSF 1e-5f

typedef unsigned long long u64;

// ---------- f0 = concat(x, pos) ----------
__global__ void k_concat6(const float* __restrict__ x, const float* __restrict__ pos,
                          float* __restrict__ f0) {
    int i = blockIdx.x*256 + threadIdx.x;        // < N*6
    int n = i/6, c = i%6;
    f0[i] = (c < 3) ? x[n*3 + c] : pos[n*3 + c - 3];
}

// ---------- s[n] = sum_c F[n][c]^2 ----------
template<int C>
__global__ void k_snorm(const float* __restrict__ F, float* __restrict__ s) {
    int n = blockIdx.x*256 + threadIdx.x;
    float a = 0.f;
    for (int c = 0; c < C; c++) { float t = F[(size_t)n*C + c]; a += t*t; }
    s[n] = a;
}

// ---------- D[b][p][q] = s_p + s_q - 2 f_p.f_q ; 64x64 tile per block ----------
template<int C>
__global__ __launch_bounds__(256) void k_dist(const float* __restrict__ F,
                                              const float* __restrict__ s,
                                              float* __restrict__ D) {
    __shared__ float FpT[C][68];
    __shared__ float FqT[C][68];
    __shared__ float sp[64], sq[64];
    int b = blockIdx.z;
    int p0 = blockIdx.x*64, q0 = blockIdx.y*64;
    int t = threadIdx.x;
    for (int e = t; e < 64*C; e += 256) {
        int r = e / C, c = e % C;
        FpT[c][r] = F[(size_t)(b*PNUM + p0 + r)*C + c];
        FqT[c][r] = F[(size_t)(b*PNUM + q0 + r)*C + c];
    }
    if (t < 64) { sp[t] = s[b*PNUM + p0 + t]; sq[t] = s[b*PNUM + q0 + t]; }
    __syncthreads();
    int tq = t & 15, tp = t >> 4;
    float acc[4][4] = {};
    for (int c = 0; c < C; c++) {
        float4 fp4 = *(const float4*)&FpT[c][tp*4];
        float4 fq4 = *(const float4*)&FqT[c][tq*4];
        float fp[4] = {fp4.x, fp4.y, fp4.z, fp4.w};
        float fq[4] = {fq4.x, fq4.y, fq4.z, fq4.w};
        #pragma unroll
        for (int i = 0; i < 4; i++)
            #pragma unroll
            for (int j = 0; j < 4; j++) acc[i][j] += fp[i]*fq[j];
    }
    #pragma unroll
    for (int i = 0; i < 4; i++) {
        float4 o;
        float* oo = (float*)&o;
        #pragma unroll
        for (int j = 0; j < 4; j++)
            oo[j] = sp[tp*4 + i] + sq[tq*4 + j] - 2.0f*acc[i][j];
        *(float4*)&D[(size_t)(b*PNUM + p0 + tp*4 + i)*PNUM + q0 + tq*4] = o;
    }
}

// ---------- candidate select: all q with key <= (approx) 40th smallest, capped at 64 ----------
// 2-level radix histogram on monotone u32 keys; candidate SET superset of f32-top-40;
// exact ordering is done by k_refine in f64, so set membership is all that matters.
__global__ __launch_bounds__(256) void k_topk(const float* __restrict__ D,
                                              int* __restrict__ cand, int* __restrict__ ccnt) {
    __shared__ unsigned keys[PNUM];    // 8 KB
    __shared__ int hist[256];
    __shared__ int sel[2];             // bucket, base count
    __shared__ int cnt_s;
    int n = blockIdx.x, t = threadIdx.x;
    const float* drow = D + (size_t)n*PNUM;
    hist[t] = 0;
    if (t == 0) cnt_s = 0;
    __syncthreads();
    #pragma unroll
    for (int j = 0; j < PNUM/256; j++) {
        int q = t + 256*j;
        unsigned u = __float_as_uint(drow[q]);
        u = (u & 0x80000000u) ? ~u : (u | 0x80000000u);
        keys[q] = u;
        atomicAdd(&hist[u >> 24], 1);
    }
    __syncthreads();
    // level-1 scan: find bucket b1 where cumulative crosses KSEL
    if (t < 64) {
        int ss[4];
        #pragma unroll
        for (int i = 0; i < 4; i++) ss[i] = hist[4*t + i];
        int loc = ss[0] + ss[1] + ss[2] + ss[3];
        int pre = loc;
        #pragma unroll
        for (int o = 1; o < 64; o <<= 1) {
            int v = __shfl_up(pre, o, 64);
            if (t >= o) pre += v;
        }
        int c = pre - loc;   // exclusive
        #pragma unroll
        for (int i = 0; i < 4; i++) {
            if (c < KSEL && c + ss[i] >= KSEL) { sel[0] = 4*t + i; sel[1] = c; }
            c += ss[i];
        }
    }
    __syncthreads();
    int b1 = sel[0], base1 = sel[1];
    __syncthreads();
    hist[t] = 0;
    __syncthreads();
    #pragma unroll
    for (int j = 0; j < PNUM/256; j++) {
        unsigned u = keys[t + 256*j];
        if ((u >> 24) == (unsigned)b1) atomicAdd(&hist[(u >> 16) & 0xffu], 1);
    }
    __syncthreads();
    // level-2 scan: crossing of KSEL - base1
    if (t < 64) {
        int target = KSEL - base1;
        int ss[4];
        #pragma unroll
        for (int i = 0; i < 4; i++) ss[i] = hist[4*t + i];
        int loc = ss[0] + ss[1] + ss[2] + ss[3];
        int pre = loc;
        #pragma unroll
        for (int o = 1; o < 64; o <<= 1) {
            int v = __shfl_up(pre, o, 64);
            if (t >= o) pre += v;
        }
        int c = pre - loc;
        #pragma unroll
        for (int i = 0; i < 4; i++) {
            if (c < target && c + ss[i] >= target) sel[0] = 4*t + i;
            c += ss[i];
        }
    }
    __syncthreads();
    unsigned P = ((unsigned)b1 << 8) | (unsigned)sel[0];
    #pragma unroll
    for (int j = 0; j < PNUM/256; j++) {
        int q = t + 256*j;
        if ((keys[q] >> 16) <= P) {
            int pos = atomicAdd(&cnt_s, 1);
            if (pos < KCAP) cand[(size_t)n*KCAP + pos] = q;
        }
    }
    __syncthreads();
    if (t == 0) ccnt[n] = (cnt_s < KCAP) ? cnt_s : KCAP;
}

// ---------- refine: f64 direct squared distance over candidates, exact top-30 ----------
// one wave per row; lane l holds candidate l
template<int C>
__global__ __launch_bounds__(256) void k_refine(const float* __restrict__ F,
                                                const int* __restrict__ cand,
                                                const int* __restrict__ ccnt,
                                                int* __restrict__ idx) {
    int t = threadIdx.x;
    int lane = t & 63;
    int row = blockIdx.x*4 + (t >> 6);
    int b = row >> 11;
    const float* fp = F + (size_t)row*C;
    int cnt = ccnt[row];
    bool act = lane < cnt;
    int q = act ? cand[(size_t)row*KCAP + lane] : 0;
    const float* fq = F + (size_t)(b*PNUM + q)*C;
    double d = 1e300;
    if (act) {
        d = 0.0;
        if (C == 64) {
            #pragma unroll
            for (int c4 = 0; c4 < C/4; c4++) {
                float4 a = ((const float4*)fp)[c4];
                float4 bb = ((const float4*)fq)[c4];
                double d0 = (double)a.x - (double)bb.x;
                double d1 = (double)a.y - (double)bb.y;
                double d2 = (double)a.z - (double)bb.z;
                double d3 = (double)a.w - (double)bb.w;
                d += d0*d0 + d1*d1 + d2*d2 + d3*d3;
            }
        } else {
            #pragma unroll
            for (int c = 0; c < C; c++) {
                double df = (double)fp[c] - (double)fq[c];
                d += df*df;
            }
        }
    }
    for (int it = 0; it < KNN; it++) {
        double m = d;
        #pragma unroll
        for (int off = 32; off >= 1; off >>= 1) {
            double o = __shfl_xor(m, off, 64);
            m = (o < m) ? o : m;
        }
        int cid = (d == m) ? q : 0x7fffffff;
        int cm = cid;
        #pragma unroll
        for (int off = 32; off >= 1; off >>= 1) {
            int o = __shfl_xor(cm, off, 64);
            cm = (o < cm) ? o : cm;
        }
        if (d == m && q == cm) {
            idx[(size_t)row*KNN + it] = q;
            d = 1e300;
        }
    }
}

// ---------- W0c = W0a - W0b ----------
__global__ void k_diffw(const float* __restrict__ W0, float* __restrict__ W0c, int CE) {
    int i = blockIdx.x*256 + threadIdx.x;
    if (i < CE) W0c[i] = W0[i] - W0[CE + i];
}

// ---------- generic tiled f32 GEMM: out = [relu](A[M,Kd] @ W[Kd,Nd] + bias) ----------
template<int RELU>
__global__ __launch_bounds__(256) void k_gemm(const float* __restrict__ A,
                                              const float* __restrict__ W,
                                              const float* __restrict__ bias,
                                              float* __restrict__ out,
                                              int M, int Kd, int Nd) {
    __shared__ float As[64][17];
    __shared__ float Bs[16][64];
    int m0 = blockIdx.x*64, n0 = blockIdx.y*64;
    int t = threadIdx.x;
    int cb = (t & 15)*4, rb = (t >> 4)*4;
    float acc[4][4] = {};
    for (int k0 = 0; k0 < Kd; k0 += 16) {
        #pragma unroll
        for (int j = 0; j < 4; j++) {
            int e = t + 256*j;
            int r = e >> 4, c = e & 15;
            As[r][c] = (k0 + c < Kd) ? A[(size_t)(m0 + r)*Kd + k0 + c] : 0.f;
        }
        #pragma unroll
        for (int j = 0; j < 4; j++) {
            int e = t + 256*j;
            int r = e >> 6, c = e & 63;
            Bs[r][c] = (k0 + r < Kd && n0 + c < Nd) ? W[(size_t)(k0 + r)*Nd + n0 + c] : 0.f;
        }
        __syncthreads();
        #pragma unroll
        for (int kk = 0; kk < 16; kk++) {
            float a[4];
            #pragma unroll
            for (int i = 0; i < 4; i++) a[i] = As[rb + i][kk];
            float4 w4 = *(const float4*)&Bs[kk][cb];
            float w[4] = {w4.x, w4.y, w4.z, w4.w};
            #pragma unroll
            for (int i = 0; i < 4; i++)
                #pragma unroll
                for (int j = 0; j < 4; j++) acc[i][j] += a[i]*w[j];
        }
        __syncthreads();
    }
    #pragma unroll
    for (int i = 0; i < 4; i++) {
        int row = m0 + rb + i;
        #pragma unroll
        for (int j = 0; j < 4; j++) {
            int col = n0 + cb + j;
            if (col < Nd) {
                float v = acc[i][j] + (bias ? bias[col] : 0.f);
                if (RELU) v = fmaxf(v, 0.f);
                out[(size_t)row*Nd + col] = v;
            }
        }
    }
}

// ---------- stats of relu(u_p + v_q) over all edges (stats only; h1 not stored) ----------
__global__ __launch_bounds__(256) void k_e1stats(const float* __restrict__ u,
                                                 const float* __restrict__ v,
                                                 const int* __restrict__ idx,
                                                 float* __restrict__ psum, float* __restrict__ psq) {
    int t = threadIdx.x;
    float s = 0.f, sq = 0.f;
    const int stride = 4096*256;
    int i = blockIdx.x*256 + t;
    #pragma unroll 1
    for (int j = 0; j < 30; j++, i += stride) {   // N*K*64 / (4096*256) = 30 exactly
        int edge = i >> 6, c = i & 63;
        int p = edge / KNN;
        int q = idx[edge];
        int b = p >> 11;
        float h = u[(size_t)p*64 + c] + v[(size_t)(b*PNUM + q)*64 + c];
        h = fmaxf(h, 0.f);
        s += h; sq += h*h;
    }
    __shared__ float rs[256], rq[256];
    rs[t] = s; rq[t] = sq;
    __syncthreads();
    if (t < 128) { rs[t] += rs[t+128]; rq[t] += rq[t+128]; }
    __syncthreads();
    if (t < 64) {
        rs[t] += rs[t+64]; rq[t] += rq[t+64];
        psum[(size_t)blockIdx.x*64 + t] = rs[t];
        psq [(size_t)blockIdx.x*64 + t] = rq[t];
    }
}

// ---------- finalize BN stats ----------
__global__ void k_statsfin(const float* __restrict__ psum, const float* __restrict__ psq,
                           int npart, int C, float invM,
                           const float* __restrict__ g, const float* __restrict__ be,
                           float* __restrict__ scale, float* __restrict__ shift) {
    int c = blockIdx.x, t = threadIdx.x;
    float s = 0.f, q = 0.f;
    for (int i = t; i < npart; i += 256) {
        s += psum[(size_t)i*C + c];
        q += psq [(size_t)i*C + c];
    }
    __shared__ float rs[256], rq[256];
    rs[t] = s; rq[t] = q; __syncthreads();
    for (int off = 128; off >= 1; off >>= 1) {
        if (t < off) { rs[t] += rs[t+off]; rq[t] += rq[t+off]; }
        __syncthreads();
    }
    if (t == 0) {
        float m   = rs[0]*invM;
        float var = rq[0]*invM - m*m;
        float inv = rsqrtf(var + EPSF);
        float sc  = g[c]*inv;
        scale[c] = sc;
        shift[c] = be[c] - m*sc;
    }
}

// ---------- fold BN affine into next linear ----------
__global__ void k_fold(const float* __restrict__ W, const float* __restrict__ b,
                       const float* __restrict__ scale, const float* __restrict__ shift,
                       float* __restrict__ Wp, float* __restrict__ bp, int Cin, int Cout) {
    int co = blockIdx.x, t = threadIdx.x;
    float acc = 0.f;
    for (int ci = t; ci < Cin; ci += 256) {
        float w = W[(size_t)ci*Cout + co];
        Wp[(size_t)ci*Cout + co] = scale[ci]*w;
        acc += shift[ci]*w;
    }
    __shared__ float r[256];
    r[t] = acc; __syncthreads();
    for (int off = 128; off >= 1; off >>= 1) { if (t < off) r[t] += r[t+off]; __syncthreads(); }
    if (t == 0) bp[co] = b[co] + r[0];
}

// ---------- edge layer 1: rebuild h1 tile, GEMM vs folded W1, pool max/min, stats ----------
__global__ __launch_bounds__(256) void k_e2(const float* __restrict__ u, const float* __restrict__ v,
                                            const int* __restrict__ idx,
                                            const float* __restrict__ W1p, const float* __restrict__ b1p,
                                            float* __restrict__ pmax, float* __restrict__ pmin,
                                            float* __restrict__ psum, float* __restrict__ psq) {
    __shared__ float W1s[64][64];
    __shared__ float b1s[64];
    __shared__ float h1s[2][KNN][64];
    __shared__ float us[2][64];
    __shared__ int   idxs[2][KNN];
    __shared__ float rmax[16][64], rmin[16][64], rsum[16][64], rsq[16][64];
    int t = threadIdx.x;
    int n0 = blockIdx.x*2;
    int b = n0 >> 11;
    for (int e = t; e < 4096; e += 256) W1s[e >> 6][e & 63] = W1p[e];
    if (t < 64)  b1s[t] = b1p[t];
    if (t < 128) us[t >> 6][t & 63] = u[(size_t)(n0 + (t >> 6))*64 + (t & 63)];
    if (t < 2*KNN) idxs[t/KNN][t%KNN] = idx[(size_t)(n0 + t/KNN)*KNN + t%KNN];
    __syncthreads();
    for (int e = t; e < 2*KNN*64; e += 256) {
        int pt = e / (KNN*64);
        int r  = e - pt*KNN*64;
        int k  = r >> 6, c = r & 63;
        int q  = idxs[pt][k];
        float h = us[pt][c] + v[(size_t)(b*PNUM + q)*64 + c];
        h1s[pt][k][c] = fmaxf(h, 0.f);
    }
    __syncthreads();
    int co4 = (t & 15)*4;
    int k1 = t >> 4;             // 0..15
    int k2 = k1 + 16;
    bool has2 = (k2 < KNN);
    int k2c = has2 ? k2 : 0;
    float sum_acc = 0.f, sq_acc = 0.f;
    for (int pt = 0; pt < 2; pt++) {
        float a1[4] = {}, a2[4] = {};
        for (int c = 0; c < 64; c++) {
            float f1 = h1s[pt][k1][c];
            float f2 = h1s[pt][k2c][c];
            float4 w4 = *(const float4*)&W1s[c][co4];
            float w[4] = {w4.x, w4.y, w4.z, w4.w};
            #pragma unroll
            for (int j = 0; j < 4; j++) { a1[j] += f1*w[j]; a2[j] += f2*w[j]; }
        }
        #pragma unroll
        for (int j = 0; j < 4; j++) {
            int co = co4 + j;
            float v1 = fmaxf(a1[j] + b1s[co], 0.f);
            float v2 = fmaxf(a2[j] + b1s[co], 0.f);
            rmax[k1][co] = has2 ? fmaxf(v1, v2) : v1;
            rmin[k1][co] = has2 ? fminf(v1, v2) : v1;
            rsum[k1][co] = has2 ? (v1 + v2) : v1;
            rsq [k1][co] = has2 ? (v1*v1 + v2*v2) : v1*v1;
        }
        __syncthreads();
        if (t < 64) {
            float mx = rmax[0][t], mn = rmin[0][t], sm = rsum[0][t], s2 = rsq[0][t];
            #pragma unroll
            for (int kp = 1; kp < 16; kp++) {
                mx = fmaxf(mx, rmax[kp][t]);
                mn = fminf(mn, rmin[kp][t]);
                sm += rsum[kp][t];
                s2 += rsq [kp][t];
            }
            pmax[(size_t)(n0 + pt)*64 + t] = mx;
            pmin[(size_t)(n0 + pt)*64 + t] = mn;
            sum_acc += sm; sq_acc += s2;
        }
        __syncthreads();
    }
    if (t < 64) {
        psum[(size_t)blockIdx.x*64 + t] = sum_acc;
        psq [(size_t)blockIdx.x*64 + t] = sq_acc;
    }
}

// ---------- BN1 applied after pooling (max if scale>=0 else min) ----------
__global__ void k_applypool(const float* __restrict__ pmax, const float* __restrict__ pmin,
                            const float* __restrict__ scale, const float* __restrict__ shift,
                            float* __restrict__ out) {
    int i = blockIdx.x*256 + threadIdx.x;
    int c = i & 63;
    float sc = scale[c];
    float pooled = (sc >= 0.f) ? pmax[i] : pmin[i];
    out[i] = sc*pooled + shift[c];
}

// ---------- Hin = concat(x1,x2,x3) ----------
__global__ void k_concat192(const float* __restrict__ x1, const float* __restrict__ x2,
                            const float* __restrict__ x3, float* __restrict__ H) {
    int i = blockIdx.x*256 + threadIdx.x;
    int n = i / 192, c = i % 192;
    const float* src = (c < 64) ? x1 : (c < 128) ? x2 : x3;
    H[i] = src[(size_t)n*64 + (c & 63)];
}

// ---------- per-column partial sums over 64-row blocks ----------
__global__ void k_colstats(const float* __restrict__ Hbuf, float* __restrict__ psum,
                           float* __restrict__ psq, int Cout) {
    int m0 = blockIdx.x*64, c0 = blockIdx.y*64;
    int t = threadIdx.x;
    int c = t & 63, rg = t >> 6;
    float s = 0.f, q = 0.f;
    #pragma unroll 4
    for (int r = 0; r < 16; r++) {
        float hv = Hbuf[(size_t)(m0 + rg*16 + r)*Cout + c0 + c];
        s += hv; q += hv*hv;
    }
    __shared__ float rs[256], rq[256];
    rs[t] = s; rq[t] = q; __syncthreads();
    if (t < 128) { rs[t] += rs[t+128]; rq[t] += rq[t+128]; }
    __syncthreads();
    if (t < 64) {
        rs[t] += rs[t+64]; rq[t] += rq[t+64];
        psum[(size_t)blockIdx.x*Cout + c0 + t] = rs[t];
        psq [(size_t)blockIdx.x*Cout + c0 + t] = rq[t];
    }
}

// ---------- log_softmax over 50 cols, one wave per row ----------
__global__ void k_logsoftmax(const float* __restrict__ logits, float* __restrict__ out) {
    int t = threadIdx.x;
    int n = blockIdx.x*4 + (t >> 6);
    int l = t & 63;
    float z = (l < 50) ? logits[(size_t)n*50 + l] : -INFINITY;
    float mx = z;
    #pragma unroll
    for (int off = 32; off >= 1; off >>= 1) mx = fmaxf(mx, __shfl_xor(mx, off, 64));
    float ex = (l < 50) ? expf(z - mx) : 0.f;
    float sm = ex;
    #pragma unroll
    for (int off = 32; off >= 1; off >>= 1) sm += __shfl_xor(sm, off, 64);
    float lse = mx + logf(sm);
    if (l < 50) out[(size_t)n*50 + l] = z - lse;
}

extern "C" void kernel_launch(void* const* d_in, const int* in_sizes, int n_in,
                              void* d_out, int out_size, void* d_ws, size_t ws_size,
                              hipStream_t stream) {
    (void)in_sizes; (void)n_in; (void)out_size;
    const float* x   = (const float*)d_in[0];
    const float* pos = (const float*)d_in[1];
    const float* prm[38];
    for (int i = 0; i < 38; i++) prm[i] = (const float*)d_in[3 + i];
    // prm: c1[0..7] c2[8..15] c3[16..23] l1[24..27] h0[28..31] h1[32..35] ho[36..37]

    float* ws = (float*)d_ws;
    size_t off = 0;
    auto alloc = [&](size_t cnt) { float* p = ws + off; off += (cnt + 63) & ~((size_t)63); return p; };
    float* f0   = alloc((size_t)NPT*6);
    float* s    = alloc(NPT);
    float* x1   = alloc((size_t)NPT*64);
    float* x2   = alloc((size_t)NPT*64);
    float* x3   = alloc((size_t)NPT*64);
    float* u    = alloc((size_t)NPT*64);
    float* v    = alloc((size_t)NPT*64);
    float* pmax = alloc((size_t)NPT*64);
    float* pmin = alloc((size_t)NPT*64);
    int*   idx  = (int*)alloc((size_t)NPT*KNN);
    int*   ccnt = (int*)alloc(NPT);
    float* W0c  = alloc(64*64);
    float* W1p  = alloc(64*64);
    float* b1p  = alloc(64);
    float* scaleA = alloc(1024);
    float* shiftA = alloc(1024);
    float* Wp   = alloc(1024*256);
    float* bp   = alloc(1024);
    float* psum = alloc(524288);
    float* psq  = alloc(524288);
    float* big  = alloc((size_t)BNUM*PNUM*PNUM);   // shared: D, then head activations
    if (off*sizeof(float) > ws_size) return;       // insufficient workspace -> leave poisoned

    // cand (NPT*KCAP ints = 4 MB) aliases psum+psq (4 MB): dead ranges don't overlap in time
    int* cand = (int*)psum;

    auto conv = [&](const float* F, int C, const float* const* pp, float* xout) {
        if (C == 6) k_snorm<6><<<NPT/256, 256, 0, stream>>>(F, s);
        else        k_snorm<64><<<NPT/256, 256, 0, stream>>>(F, s);
        float* D = big;
        if (C == 6) k_dist<6><<<dim3(32,32,8), 256, 0, stream>>>(F, s, D);
        else        k_dist<64><<<dim3(32,32,8), 256, 0, stream>>>(F, s, D);
        k_topk<<<NPT, 256, 0, stream>>>(D, cand, ccnt);
        if (C == 6) k_refine<6><<<NPT/4, 256, 0, stream>>>(F, cand, ccnt, idx);
        else        k_refine<64><<<NPT/4, 256, 0, stream>>>(F, cand, ccnt, idx);
        k_diffw<<<(C*64 + 255)/256, 256, 0, stream>>>(pp[0], W0c, C*64);
        k_gemm<0><<<dim3(NPT/64, 1), 256, 0, stream>>>(F, W0c, pp[1], u, NPT, C, 64);
        k_gemm<0><<<dim3(NPT/64, 1), 256, 0, stream>>>(F, pp[0] + C*64, nullptr, v, NPT, C, 64);
        k_e1stats<<<4096, 256, 0, stream>>>(u, v, idx, psum, psq);
        k_statsfin<<<64, 256, 0, stream>>>(psum, psq, 4096, 64, 1.f/((float)NPT*KNN),
                                           pp[2], pp[3], scaleA, shiftA);
        k_fold<<<64, 256, 0, stream>>>(pp[4], pp[5], scaleA, shiftA, W1p, b1p, 64, 64);
        k_e2<<<NPT/2, 256, 0, stream>>>(u, v, idx, W1p, b1p, pmax, pmin, psum, psq);
        k_statsfin<<<64, 256, 0, stream>>>(psum, psq, NPT/2, 64, 1.f/((float)NPT*KNN),
                                           pp[6], pp[7], scaleA, shiftA);
        k_applypool<<<NPT*64/256, 256, 0, stream>>>(pmax, pmin, scaleA, shiftA, xout);
    };

    k_concat6<<<NPT*6/256, 256, 0, stream>>>(x, pos, f0);
    conv(f0, 6,  &prm[0],  x1);
    conv(x1, 64, &prm[8],  x2);
    conv(x2, 64, &prm[16], x3);

    float* Hin    = big;
    float* Hb1    = big + 3145728;
    float* Hb2    = big + 19922944;
    float* Hb3    = big + 24117248;
    float* logits = big + 26214400;

    k_concat192<<<NPT*192/256, 256, 0, stream>>>(x1, x2, x3, Hin);
    k_gemm<1><<<dim3(NPT/64, 16), 256, 0, stream>>>(Hin, prm[24], prm[25], Hb1, NPT, 192, 1024);
    k_colstats<<<dim3(NPT/64, 16), 256, 0, stream>>>(Hb1, psum, psq, 1024);
    k_statsfin<<<1024, 256, 0, stream>>>(psum, psq, NPT/64, 1024, 1.f/(float)NPT,
                                         prm[26], prm[27], scaleA, shiftA);
    k_fold<<<256, 256, 0, stream>>>(prm[28], prm[29], scaleA, shiftA, Wp, bp, 1024, 256);
    k_gemm<1><<<dim3(NPT/64, 4), 256, 0, stream>>>(Hb1, Wp, bp, Hb2, NPT, 1024, 256);
    k_colstats<<<dim3(NPT/64, 4), 256, 0, stream>>>(Hb2, psum, psq, 256);
    k_statsfin<<<256, 256, 0, stream>>>(psum, psq, NPT/64, 256, 1.f/(float)NPT,
                                        prm[30], prm[31], scaleA, shiftA);
    k_fold<<<128, 256, 0, stream>>>(prm[32], prm[33], scaleA, shiftA, Wp, bp, 256, 128);
    k_gemm<1><<<dim3(NPT/64, 2), 256, 0, stream>>>(Hb2, Wp, bp, Hb3, NPT, 256, 128);
    k_colstats<<<dim3(NPT/64, 2), 256, 0, stream>>>(Hb3, psum, psq, 128);
    k_statsfin<<<128, 256, 0, stream>>>(psum, psq, NPT/64, 128, 1.f/(float)NPT,
                                        prm[34], prm[35], scaleA, shiftA);
    k_fold<<<50, 256, 0, stream>>>(prm[36], prm[37], scaleA, shiftA, Wp, bp, 128, 50);
    k_gemm<0><<<dim3(NPT/64, 1), 256, 0, stream>>>(Hb3, Wp, bp, logits, NPT, 128, 50);
    k_logsoftmax<<<NPT/4, 256, 0, stream>>>(logits, (float*)d_out);
}

// Round 4
// 1894.839 us; speedup vs baseline: 2.0765x; 1.4468x over previous
//
#include <hip/hip_runtime.h>
#include <hip/hip_bf16.h>
#include <stdint.h>

#define BNUM 8
#define PNUM 2048
#define KNN  30
#define KSEL 40      // rank threshold for candidate selection
#define KCAP 64      // max candidates per row (one wave)
#define NPT  (BNUM*PNUM)   // 16384
#define EPSF 1e-5f

typedef unsigned long long u64;

__device__ __forceinline__ float lane_bcast(float x, int l) {
    return __int_as_float(__builtin_amdgcn_readlane(__float_as_int(x), l));
}

// ---------- f0 = concat(x, pos) ----------
__global__ void k_concat6(const float* __restrict__ x, const float* __restrict__ pos,
                          float* __restrict__ f0) {
    int i = blockIdx.x*256 + threadIdx.x;        // < N*6
    int n = i/6, c = i%6;
    f0[i] = (c < 3) ? x[n*3 + c] : pos[n*3 + c - 3];
}

// ---------- s[n] = sum_c F[n][c]^2 ----------
template<int C>
__global__ void k_snorm(const float* __restrict__ F, float* __restrict__ s) {
    int n = blockIdx.x*256 + threadIdx.x;
    float a = 0.f;
    for (int c = 0; c < C; c++) { float t = F[(size_t)n*C + c]; a += t*t; }
    s[n] = a;
}

// ---------- D[b][p][q] = s_p + s_q - 2 f_p.f_q ; 64x64 tile per block ----------
template<int C>
__global__ __launch_bounds__(256) void k_dist(const float* __restrict__ F,
                                              const float* __restrict__ s,
                                              float* __restrict__ D) {
    __shared__ float FpT[C][68];
    __shared__ float FqT[C][68];
    __shared__ float sp[64], sq[64];
    int b = blockIdx.z;
    int p0 = blockIdx.x*64, q0 = blockIdx.y*64;
    int t = threadIdx.x;
    for (int e = t; e < 64*C; e += 256) {
        int r = e / C, c = e % C;
        FpT[c][r] = F[(size_t)(b*PNUM + p0 + r)*C + c];
        FqT[c][r] = F[(size_t)(b*PNUM + q0 + r)*C + c];
    }
    if (t < 64) { sp[t] = s[b*PNUM + p0 + t]; sq[t] = s[b*PNUM + q0 + t]; }
    __syncthreads();
    int tq = t & 15, tp = t >> 4;
    float acc[4][4] = {};
    for (int c = 0; c < C; c++) {
        float4 fp4 = *(const float4*)&FpT[c][tp*4];
        float4 fq4 = *(const float4*)&FqT[c][tq*4];
        float fp[4] = {fp4.x, fp4.y, fp4.z, fp4.w};
        float fq[4] = {fq4.x, fq4.y, fq4.z, fq4.w};
        #pragma unroll
        for (int i = 0; i < 4; i++)
            #pragma unroll
            for (int j = 0; j < 4; j++) acc[i][j] += fp[i]*fq[j];
    }
    #pragma unroll
    for (int i = 0; i < 4; i++) {
        float4 o;
        float* oo = (float*)&o;
        #pragma unroll
        for (int j = 0; j < 4; j++)
            oo[j] = sp[tp*4 + i] + sq[tq*4 + j] - 2.0f*acc[i][j];
        *(float4*)&D[(size_t)(b*PNUM + p0 + tp*4 + i)*PNUM + q0 + tq*4] = o;
    }
}

// ---------- candidate select: all q with key <= (approx) 40th smallest, capped at 64 ----------
__global__ __launch_bounds__(256) void k_topk(const float* __restrict__ D,
                                              int* __restrict__ cand, int* __restrict__ ccnt) {
    __shared__ unsigned keys[PNUM];    // 8 KB
    __shared__ int hist[256];
    __shared__ int sel[2];             // bucket, base count
    __shared__ int cnt_s;
    int n = blockIdx.x, t = threadIdx.x;
    const float* drow = D + (size_t)n*PNUM;
    hist[t] = 0;
    if (t == 0) cnt_s = 0;
    __syncthreads();
    #pragma unroll
    for (int j = 0; j < PNUM/256; j++) {
        int q = t + 256*j;
        unsigned u = __float_as_uint(drow[q]);
        u = (u & 0x80000000u) ? ~u : (u | 0x80000000u);
        keys[q] = u;
        atomicAdd(&hist[u >> 24], 1);
    }
    __syncthreads();
    if (t < 64) {
        int ss[4];
        #pragma unroll
        for (int i = 0; i < 4; i++) ss[i] = hist[4*t + i];
        int loc = ss[0] + ss[1] + ss[2] + ss[3];
        int pre = loc;
        #pragma unroll
        for (int o = 1; o < 64; o <<= 1) {
            int v = __shfl_up(pre, o, 64);
            if (t >= o) pre += v;
        }
        int c = pre - loc;   // exclusive
        #pragma unroll
        for (int i = 0; i < 4; i++) {
            if (c < KSEL && c + ss[i] >= KSEL) { sel[0] = 4*t + i; sel[1] = c; }
            c += ss[i];
        }
    }
    __syncthreads();
    int b1 = sel[0], base1 = sel[1];
    __syncthreads();
    hist[t] = 0;
    __syncthreads();
    #pragma unroll
    for (int j = 0; j < PNUM/256; j++) {
        unsigned u = keys[t + 256*j];
        if ((u >> 24) == (unsigned)b1) atomicAdd(&hist[(u >> 16) & 0xffu], 1);
    }
    __syncthreads();
    if (t < 64) {
        int target = KSEL - base1;
        int ss[4];
        #pragma unroll
        for (int i = 0; i < 4; i++) ss[i] = hist[4*t + i];
        int loc = ss[0] + ss[1] + ss[2] + ss[3];
        int pre = loc;
        #pragma unroll
        for (int o = 1; o < 64; o <<= 1) {
            int v = __shfl_up(pre, o, 64);
            if (t >= o) pre += v;
        }
        int c = pre - loc;
        #pragma unroll
        for (int i = 0; i < 4; i++) {
            if (c < target && c + ss[i] >= target) sel[0] = 4*t + i;
            c += ss[i];
        }
    }
    __syncthreads();
    unsigned P = ((unsigned)b1 << 8) | (unsigned)sel[0];
    #pragma unroll
    for (int j = 0; j < PNUM/256; j++) {
        int q = t + 256*j;
        if ((keys[q] >> 16) <= P) {
            int pos = atomicAdd(&cnt_s, 1);
            if (pos < KCAP) cand[(size_t)n*KCAP + pos] = q;
        }
    }
    __syncthreads();
    if (t == 0) ccnt[n] = (cnt_s < KCAP) ? cnt_s : KCAP;
}

// ---------- refine: f64 direct squared distance over candidates, exact top-30 ----------
template<int C>
__global__ __launch_bounds__(256) void k_refine(const float* __restrict__ F,
                                                const int* __restrict__ cand,
                                                const int* __restrict__ ccnt,
                                                int* __restrict__ idx) {
    int t = threadIdx.x;
    int lane = t & 63;
    int row = blockIdx.x*4 + (t >> 6);
    int b = row >> 11;
    const float* fp = F + (size_t)row*C;
    int cnt = ccnt[row];
    bool act = lane < cnt;
    int q = act ? cand[(size_t)row*KCAP + lane] : 0;
    const float* fq = F + (size_t)(b*PNUM + q)*C;
    double d = 1e300;
    if (act) {
        d = 0.0;
        if (C == 64) {
            #pragma unroll
            for (int c4 = 0; c4 < C/4; c4++) {
                float4 a = ((const float4*)fp)[c4];
                float4 bb = ((const float4*)fq)[c4];
                double d0 = (double)a.x - (double)bb.x;
                double d1 = (double)a.y - (double)bb.y;
                double d2 = (double)a.z - (double)bb.z;
                double d3 = (double)a.w - (double)bb.w;
                d += d0*d0 + d1*d1 + d2*d2 + d3*d3;
            }
        } else {
            #pragma unroll
            for (int c = 0; c < C; c++) {
                double df = (double)fp[c] - (double)fq[c];
                d += df*df;
            }
        }
    }
    for (int it = 0; it < KNN; it++) {
        double m = d;
        #pragma unroll
        for (int off = 32; off >= 1; off >>= 1) {
            double o = __shfl_xor(m, off, 64);
            m = (o < m) ? o : m;
        }
        int cid = (d == m) ? q : 0x7fffffff;
        int cm = cid;
        #pragma unroll
        for (int off = 32; off >= 1; off >>= 1) {
            int o = __shfl_xor(cm, off, 64);
            cm = (o < cm) ? o : cm;
        }
        if (d == m && q == cm) {
            idx[(size_t)row*KNN + it] = q;
            d = 1e300;
        }
    }
}

// ---------- W0c = W0a - W0b ----------
__global__ void k_diffw(const float* __restrict__ W0, float* __restrict__ W0c, int CE) {
    int i = blockIdx.x*256 + threadIdx.x;
    if (i < CE) W0c[i] = W0[i] - W0[CE + i];
}

// ---------- generic tiled f32 GEMM ----------
template<int RELU>
__global__ __launch_bounds__(256) void k_gemm(const float* __restrict__ A,
                                              const float* __restrict__ W,
                                              const float* __restrict__ bias,
                                              float* __restrict__ out,
                                              int M, int Kd, int Nd) {
    __shared__ float As[64][17];
    __shared__ float Bs[16][64];
    int m0 = blockIdx.x*64, n0 = blockIdx.y*64;
    int t = threadIdx.x;
    int cb = (t & 15)*4, rb = (t >> 4)*4;
    float acc[4][4] = {};
    for (int k0 = 0; k0 < Kd; k0 += 16) {
        #pragma unroll
        for (int j = 0; j < 4; j++) {
            int e = t + 256*j;
            int r = e >> 4, c = e & 15;
            As[r][c] = (k0 + c < Kd) ? A[(size_t)(m0 + r)*Kd + k0 + c] : 0.f;
        }
        #pragma unroll
        for (int j = 0; j < 4; j++) {
            int e = t + 256*j;
            int r = e >> 6, c = e & 63;
            Bs[r][c] = (k0 + r < Kd && n0 + c < Nd) ? W[(size_t)(k0 + r)*Nd + n0 + c] : 0.f;
        }
        __syncthreads();
        #pragma unroll
        for (int kk = 0; kk < 16; kk++) {
            float a[4];
            #pragma unroll
            for (int i = 0; i < 4; i++) a[i] = As[rb + i][kk];
            float4 w4 = *(const float4*)&Bs[kk][cb];
            float w[4] = {w4.x, w4.y, w4.z, w4.w};
            #pragma unroll
            for (int i = 0; i < 4; i++)
                #pragma unroll
                for (int j = 0; j < 4; j++) acc[i][j] += a[i]*w[j];
        }
        __syncthreads();
    }
    #pragma unroll
    for (int i = 0; i < 4; i++) {
        int row = m0 + rb + i;
        #pragma unroll
        for (int j = 0; j < 4; j++) {
            int col = n0 + cb + j;
            if (col < Nd) {
                float v = acc[i][j] + (bias ? bias[col] : 0.f);
                if (RELU) v = fmaxf(v, 0.f);
                out[(size_t)row*Nd + col] = v;
            }
        }
    }
}

// ---------- stats of relu(u_p + v_q) over all edges ----------
__global__ __launch_bounds__(256) void k_e1stats(const float* __restrict__ u,
                                                 const float* __restrict__ v,
                                                 const int* __restrict__ idx,
                                                 float* __restrict__ psum, float* __restrict__ psq) {
    int t = threadIdx.x;
    float s = 0.f, sq = 0.f;
    const int stride = 4096*256;
    int i = blockIdx.x*256 + t;
    #pragma unroll 1
    for (int j = 0; j < 30; j++, i += stride) {
        int edge = i >> 6, c = i & 63;
        int p = edge / KNN;
        int q = idx[edge];
        int b = p >> 11;
        float h = u[(size_t)p*64 + c] + v[(size_t)(b*PNUM + q)*64 + c];
        h = fmaxf(h, 0.f);
        s += h; sq += h*h;
    }
    __shared__ float rs[256], rq[256];
    rs[t] = s; rq[t] = sq;
    __syncthreads();
    if (t < 128) { rs[t] += rs[t+128]; rq[t] += rq[t+128]; }
    __syncthreads();
    if (t < 64) {
        rs[t] += rs[t+64]; rq[t] += rq[t+64];
        psum[(size_t)blockIdx.x*64 + t] = rs[t];
        psq [(size_t)blockIdx.x*64 + t] = rq[t];
    }
}

// ---------- finalize BN stats ----------
__global__ void k_statsfin(const float* __restrict__ psum, const float* __restrict__ psq,
                           int npart, int C, float invM,
                           const float* __restrict__ g, const float* __restrict__ be,
                           float* __restrict__ scale, float* __restrict__ shift) {
    int c = blockIdx.x, t = threadIdx.x;
    float s = 0.f, q = 0.f;
    for (int i = t; i < npart; i += 256) {
        s += psum[(size_t)i*C + c];
        q += psq [(size_t)i*C + c];
    }
    __shared__ float rs[256], rq[256];
    rs[t] = s; rq[t] = q; __syncthreads();
    for (int off = 128; off >= 1; off >>= 1) {
        if (t < off) { rs[t] += rs[t+off]; rq[t] += rq[t+off]; }
        __syncthreads();
    }
    if (t == 0) {
        float m   = rs[0]*invM;
        float var = rq[0]*invM - m*m;
        float inv = rsqrtf(var + EPSF);
        float sc  = g[c]*inv;
        scale[c] = sc;
        shift[c] = be[c] - m*sc;
    }
}

// ---------- fold BN affine into next linear ----------
__global__ void k_fold(const float* __restrict__ W, const float* __restrict__ b,
                       const float* __restrict__ scale, const float* __restrict__ shift,
                       float* __restrict__ Wp, float* __restrict__ bp, int Cin, int Cout) {
    int co = blockIdx.x, t = threadIdx.x;
    float acc = 0.f;
    for (int ci = t; ci < Cin; ci += 256) {
        float w = W[(size_t)ci*Cout + co];
        Wp[(size_t)ci*Cout + co] = scale[ci]*w;
        acc += shift[ci]*w;
    }
    __shared__ float r[256];
    r[t] = acc; __syncthreads();
    for (int off = 128; off >= 1; off >>= 1) { if (t < off) r[t] += r[t+off]; __syncthreads(); }
    if (t == 0) bp[co] = b[co] + r[0];
}

// ---------- edge layer 1: wave-per-point register GEMM + pool + stats ----------
// lane = output channel; W1 column in 64 VGPRs; inner loop = readlane broadcast + FMA.
__global__ __launch_bounds__(256, 4) void k_e2(const float* __restrict__ u, const float* __restrict__ v,
                                               const int* __restrict__ idx,
                                               const float* __restrict__ W1p, const float* __restrict__ b1p,
                                               float* __restrict__ pmax, float* __restrict__ pmin,
                                               float* __restrict__ psum, float* __restrict__ psq) {
    __shared__ float W1s[64][64];   // 16 KB: W1s[c][co]
    int t = threadIdx.x, lane = t & 63, w = t >> 6;
    int p = blockIdx.x*4 + w;
    int b = p >> 11;
    for (int e = t; e < 4096; e += 256) W1s[e >> 6][e & 63] = W1p[e];
    __syncthreads();
    float wcol[64];
    #pragma unroll
    for (int c = 0; c < 64; c++) wcol[c] = W1s[c][lane];   // conflict-free column read
    float ureg = u[(size_t)p*64 + lane];
    float bias = b1p[lane];
    const int* myidx = idx + (size_t)p*KNN;
    const float* vb = v + (size_t)b*PNUM*64;
    float mx = -1e30f, mn = 1e30f, sm = 0.f, sq = 0.f;
    int q = myidx[0];
    float vk = vb[(size_t)q*64 + lane];
    #pragma unroll 1
    for (int k = 0; k < KNN; k++) {
        float h = fmaxf(ureg + vk, 0.f);
        if (k + 1 < KNN) {               // prefetch next neighbor row
            int qn = myidx[k + 1];
            vk = vb[(size_t)qn*64 + lane];
        }
        float a0 = 0.f, a1 = 0.f, a2 = 0.f, a3 = 0.f;
        #pragma unroll
        for (int c = 0; c < 64; c += 4) {
            a0 = fmaf(lane_bcast(h, c    ), wcol[c    ], a0);
            a1 = fmaf(lane_bcast(h, c + 1), wcol[c + 1], a1);
            a2 = fmaf(lane_bcast(h, c + 2), wcol[c + 2], a2);
            a3 = fmaf(lane_bcast(h, c + 3), wcol[c + 3], a3);
        }
        float o = fmaxf((a0 + a1) + (a2 + a3) + bias, 0.f);
        mx = fmaxf(mx, o);
        mn = fminf(mn, o);
        sm += o;
        sq += o*o;
    }
    pmax[(size_t)p*64 + lane] = mx;
    pmin[(size_t)p*64 + lane] = mn;
    psum[(size_t)p*64 + lane] = sm;
    psq [(size_t)p*64 + lane] = sq;
}

// ---------- BN1 applied after pooling (max if scale>=0 else min) ----------
__global__ void k_applypool(const float* __restrict__ pmax, const float* __restrict__ pmin,
                            const float* __restrict__ scale, const float* __restrict__ shift,
                            float* __restrict__ out) {
    int i = blockIdx.x*256 + threadIdx.x;
    int c = i & 63;
    float sc = scale[c];
    float pooled = (sc >= 0.f) ? pmax[i] : pmin[i];
    out[i] = sc*pooled + shift[c];
}

// ---------- Hin = concat(x1,x2,x3) ----------
__global__ void k_concat192(const float* __restrict__ x1, const float* __restrict__ x2,
                            const float* __restrict__ x3, float* __restrict__ H) {
    int i = blockIdx.x*256 + threadIdx.x;
    int n = i / 192, c = i % 192;
    const float* src = (c < 64) ? x1 : (c < 128) ? x2 : x3;
    H[i] = src[(size_t)n*64 + (c & 63)];
}

// ---------- per-column partial sums over 64-row blocks ----------
__global__ void k_colstats(const float* __restrict__ Hbuf, float* __restrict__ psum,
                           float* __restrict__ psq, int Cout) {
    int m0 = blockIdx.x*64, c0 = blockIdx.y*64;
    int t = threadIdx.x;
    int c = t & 63, rg = t >> 6;
    float s = 0.f, q = 0.f;
    #pragma unroll 4
    for (int r = 0; r < 16; r++) {
        float hv = Hbuf[(size_t)(m0 + rg*16 + r)*Cout + c0 + c];
        s += hv; q += hv*hv;
    }
    __shared__ float rs[256], rq[256];
    rs[t] = s; rq[t] = q; __syncthreads();
    if (t < 128) { rs[t] += rs[t+128]; rq[t] += rq[t+128]; }
    __syncthreads();
    if (t < 64) {
        rs[t] += rs[t+64]; rq[t] += rq[t+64];
        psum[(size_t)blockIdx.x*Cout + c0 + t] = rs[t];
        psq [(size_t)blockIdx.x*Cout + c0 + t] = rq[t];
    }
}

// ---------- log_softmax over 50 cols, one wave per row ----------
__global__ void k_logsoftmax(const float* __restrict__ logits, float* __restrict__ out) {
    int t = threadIdx.x;
    int n = blockIdx.x*4 + (t >> 6);
    int l = t & 63;
    float z = (l < 50) ? logits[(size_t)n*50 + l] : -INFINITY;
    float mx = z;
    #pragma unroll
    for (int off = 32; off >= 1; off >>= 1) mx = fmaxf(mx, __shfl_xor(mx, off, 64));
    float ex = (l < 50) ? expf(z - mx) : 0.f;
    float sm = ex;
    #pragma unroll
    for (int off = 32; off >= 1; off >>= 1) sm += __shfl_xor(sm, off, 64);
    float lse = mx + logf(sm);
    if (l < 50) out[(size_t)n*50 + l] = z - lse;
}

extern "C" void kernel_launch(void* const* d_in, const int* in_sizes, int n_in,
                              void* d_out, int out_size, void* d_ws, size_t ws_size,
                              hipStream_t stream) {
    (void)in_sizes; (void)n_in; (void)out_size;
    const float* x   = (const float*)d_in[0];
    const float* pos = (const float*)d_in[1];
    const float* prm[38];
    for (int i = 0; i < 38; i++) prm[i] = (const float*)d_in[3 + i];
    // prm: c1[0..7] c2[8..15] c3[16..23] l1[24..27] h0[28..31] h1[32..35] ho[36..37]

    float* ws = (float*)d_ws;
    size_t off = 0;
    auto alloc = [&](size_t cnt) { float* p = ws + off; off += (cnt + 63) & ~((size_t)63); return p; };
    float* f0   = alloc((size_t)NPT*6);
    float* s    = alloc(NPT);
    float* x1   = alloc((size_t)NPT*64);
    float* x2   = alloc((size_t)NPT*64);
    float* x3   = alloc((size_t)NPT*64);
    float* u    = alloc((size_t)NPT*64);
    float* v    = alloc((size_t)NPT*64);
    float* pmax = alloc((size_t)NPT*64);
    float* pmin = alloc((size_t)NPT*64);
    int*   idx  = (int*)alloc((size_t)NPT*KNN);
    int*   ccnt = (int*)alloc(NPT);
    float* W0c  = alloc(64*64);
    float* W1p  = alloc(64*64);
    float* b1p  = alloc(64);
    float* scaleA = alloc(1024);
    float* shiftA = alloc(1024);
    float* Wp   = alloc(1024*256);
    float* bp   = alloc(1024);
    float* psum = alloc((size_t)NPT*64);
    float* psq  = alloc((size_t)NPT*64);
    float* big  = alloc((size_t)BNUM*PNUM*PNUM);   // shared: D, then head activations
    if (off*sizeof(float) > ws_size) return;       // insufficient workspace -> leave poisoned

    // cand (NPT*KCAP ints = 4 MB) aliases psum (4 MB): dead ranges don't overlap in time
    int* cand = (int*)psum;

    auto conv = [&](const float* F, int C, const float* const* pp, float* xout) {
        if (C == 6) k_snorm<6><<<NPT/256, 256, 0, stream>>>(F, s);
        else        k_snorm<64><<<NPT/256, 256, 0, stream>>>(F, s);
        float* D = big;
        if (C == 6) k_dist<6><<<dim3(32,32,8), 256, 0, stream>>>(F, s, D);
        else        k_dist<64><<<dim3(32,32,8), 256, 0, stream>>>(F, s, D);
        k_topk<<<NPT, 256, 0, stream>>>(D, cand, ccnt);
        if (C == 6) k_refine<6><<<NPT/4, 256, 0, stream>>>(F, cand, ccnt, idx);
        else        k_refine<64><<<NPT/4, 256, 0, stream>>>(F, cand, ccnt, idx);
        k_diffw<<<(C*64 + 255)/256, 256, 0, stream>>>(pp[0], W0c, C*64);
        k_gemm<0><<<dim3(NPT/64, 1), 256, 0, stream>>>(F, W0c, pp[1], u, NPT, C, 64);
        k_gemm<0><<<dim3(NPT/64, 1), 256, 0, stream>>>(F, pp[0] + C*64, nullptr, v, NPT, C, 64);
        k_e1stats<<<4096, 256, 0, stream>>>(u, v, idx, psum, psq);
        k_statsfin<<<64, 256, 0, stream>>>(psum, psq, 4096, 64, 1.f/((float)NPT*KNN),
                                           pp[2], pp[3], scaleA, shiftA);
        k_fold<<<64, 256, 0, stream>>>(pp[4], pp[5], scaleA, shiftA, W1p, b1p, 64, 64);
        k_e2<<<NPT/4, 256, 0, stream>>>(u, v, idx, W1p, b1p, pmax, pmin, psum, psq);
        k_statsfin<<<64, 256, 0, stream>>>(psum, psq, NPT, 64, 1.f/((float)NPT*KNN),
                                           pp[6], pp[7], scaleA, shiftA);
        k_applypool<<<NPT*64/256, 256, 0, stream>>>(pmax, pmin, scaleA, shiftA, xout);
    };

    k_concat6<<<NPT*6/256, 256, 0, stream>>>(x, pos, f0);
    conv(f0, 6,  &prm[0],  x1);
    conv(x1, 64, &prm[8],  x2);
    conv(x2, 64, &prm[16], x3);

    float* Hin    = big;
    float* Hb1    = big + 3145728;
    float* Hb2    = big + 19922944;
    float* Hb3    = big + 24117248;
    float* logits = big + 26214400;

    k_concat192<<<NPT*192/256, 256, 0, stream>>>(x1, x2, x3, Hin);
    k_gemm<1><<<dim3(NPT/64, 16), 256, 0, stream>>>(Hin, prm[24], prm[25], Hb1, NPT, 192, 1024);
    k_colstats<<<dim3(NPT/64, 16), 256, 0, stream>>>(Hb1, psum, psq, 1024);
    k_statsfin<<<1024, 256, 0, stream>>>(psum, psq, NPT/64, 1024, 1.f/(float)NPT,
                                         prm[26], prm[27], scaleA, shiftA);
    k_fold<<<256, 256, 0, stream>>>(prm[28], prm[29], scaleA, shiftA, Wp, bp, 1024, 256);
    k_gemm<1><<<dim3(NPT/64, 4), 256, 0, stream>>>(Hb1, Wp, bp, Hb2, NPT, 1024, 256);
    k_colstats<<<dim3(NPT/64, 4), 256, 0, stream>>>(Hb2, psum, psq, 256);
    k_statsfin<<<256, 256, 0, stream>>>(psum, psq, NPT/64, 256, 1.f/(float)NPT,
                                        prm[30], prm[31], scaleA, shiftA);
    k_fold<<<128, 256, 0, stream>>>(prm[32], prm[33], scaleA, shiftA, Wp, bp, 256, 128);
    k_gemm<1><<<dim3(NPT/64, 2), 256, 0, stream>>>(Hb2, Wp, bp, Hb3, NPT, 256, 128);
    k_colstats<<<dim3(NPT/64, 2), 256, 0, stream>>>(Hb3, psum, psq, 128);
    k_statsfin<<<128, 256, 0, stream>>>(psum, psq, NPT/64, 128, 1.f/(float)NPT,
                                        prm[34], prm[35], scaleA, shiftA);
    k_fold<<<50, 256, 0, stream>>>(prm[36], prm[37], scaleA, shiftA, Wp, bp, 128, 50);
    k_gemm<0><<<dim3(NPT/64, 1), 256, 0, stream>>>(Hb3, Wp, bp, logits, NPT, 128, 50);
    k_logsoftmax<<<NPT/4, 256, 0, stream>>>(logits, (float*)d_out);
}

// Round 5
// 1749.675 us; speedup vs baseline: 2.2488x; 1.0830x over previous
//
#include <hip/hip_runtime.h>
#include <hip/hip_bf16.h>
#include <stdint.h>

#define BNUM 8
#define PNUM 2048
#define KNN  30
#define KSEL 40      // rank threshold for candidate selection
#define KCAP 64      // max candidates per row (one wave)
#define NPT  (BNUM*PNUM)   // 16384
#define EPSF 1e-5f

typedef unsigned long long u64;
typedef unsigned short ushort_t;

__device__ __forceinline__ float lane_bcast(float x, int l) {
    return __int_as_float(__builtin_amdgcn_readlane(__float_as_int(x), l));
}

__device__ __forceinline__ unsigned mono_key(float d) {
    unsigned u = __float_as_uint(d);
    return (u & 0x80000000u) ? ~u : (u | 0x80000000u);   // monotone float->uint
}

// ---------- f0 = concat(x, pos) ----------
__global__ void k_concat6(const float* __restrict__ x, const float* __restrict__ pos,
                          float* __restrict__ f0) {
    int i = blockIdx.x*256 + threadIdx.x;        // < N*6
    int n = i/6, c = i%6;
    f0[i] = (c < 3) ? x[n*3 + c] : pos[n*3 + c - 3];
}

// ---------- s[n] = sum_c F[n][c]^2 ----------
template<int C>
__global__ void k_snorm(const float* __restrict__ F, float* __restrict__ s) {
    int n = blockIdx.x*256 + threadIdx.x;
    float a = 0.f;
    for (int c = 0; c < C; c++) { float t = F[(size_t)n*C + c]; a += t*t; }
    s[n] = a;
}

// ---------- dist 128x128 tile: Dk[b][p][q] = top16(monokey(s_p + s_q - 2 f_p.f_q)) ----------
template<int C>
__global__ __launch_bounds__(256) void k_dist(const float* __restrict__ F,
                                              const float* __restrict__ s,
                                              ushort_t* __restrict__ Dk) {
    __shared__ float FpT[C][132];
    __shared__ float FqT[C][132];
    __shared__ float sp[128], sq[128];
    int b = blockIdx.z;
    int p0 = blockIdx.x*128, q0 = blockIdx.y*128;
    int t = threadIdx.x;
    for (int e = t; e < 128*C; e += 256) {
        int r = e / C, c = e % C;
        FpT[c][r] = F[(size_t)(b*PNUM + p0 + r)*C + c];
        FqT[c][r] = F[(size_t)(b*PNUM + q0 + r)*C + c];
    }
    if (t < 128) { sp[t] = s[b*PNUM + p0 + t]; sq[t] = s[b*PNUM + q0 + t]; }
    __syncthreads();
    int tc = (t & 15)*8, tr = (t >> 4)*8;
    float acc[8][8] = {};
    #pragma unroll 4
    for (int c = 0; c < C; c++) {
        float4 p0v = *(const float4*)&FpT[c][tr];
        float4 p1v = *(const float4*)&FpT[c][tr+4];
        float4 q0v = *(const float4*)&FqT[c][tc];
        float4 q1v = *(const float4*)&FqT[c][tc+4];
        float av[8] = {p0v.x,p0v.y,p0v.z,p0v.w,p1v.x,p1v.y,p1v.z,p1v.w};
        float bv[8] = {q0v.x,q0v.y,q0v.z,q0v.w,q1v.x,q1v.y,q1v.z,q1v.w};
        #pragma unroll
        for (int i = 0; i < 8; i++)
            #pragma unroll
            for (int j = 0; j < 8; j++) acc[i][j] = fmaf(av[i], bv[j], acc[i][j]);
    }
    #pragma unroll
    for (int i = 0; i < 8; i++) {
        unsigned ks[8];
        #pragma unroll
        for (int j = 0; j < 8; j++) {
            float d = sp[tr + i] + sq[tc + j] - 2.0f*acc[i][j];
            ks[j] = mono_key(d) >> 16;
        }
        uint4 w;
        w.x = ks[0] | (ks[1] << 16);
        w.y = ks[2] | (ks[3] << 16);
        w.z = ks[4] | (ks[5] << 16);
        w.w = ks[6] | (ks[7] << 16);
        *(uint4*)&Dk[(size_t)(b*PNUM + p0 + tr + i)*PNUM + q0 + tc] = w;
    }
}

// ---------- candidate select on u16 keys: all q with key <= (approx) 40th smallest ----------
__global__ __launch_bounds__(256) void k_topk(const ushort_t* __restrict__ Dk,
                                              int* __restrict__ cand, int* __restrict__ ccnt) {
    __shared__ int hist[256];
    __shared__ int sel[2];             // bucket, base count
    __shared__ int cnt_s;
    int n = blockIdx.x, t = threadIdx.x;
    const ushort_t* drow = Dk + (size_t)n*PNUM;
    hist[t] = 0;
    if (t == 0) cnt_s = 0;
    __syncthreads();
    uint4 wv = *(const uint4*)&drow[t*8];
    unsigned ks[8];
    ks[0] = wv.x & 0xffffu; ks[1] = wv.x >> 16;
    ks[2] = wv.y & 0xffffu; ks[3] = wv.y >> 16;
    ks[4] = wv.z & 0xffffu; ks[5] = wv.z >> 16;
    ks[6] = wv.w & 0xffffu; ks[7] = wv.w >> 16;
    #pragma unroll
    for (int e = 0; e < 8; e++) atomicAdd(&hist[ks[e] >> 8], 1);
    __syncthreads();
    if (t < 64) {
        int ss[4];
        #pragma unroll
        for (int i = 0; i < 4; i++) ss[i] = hist[4*t + i];
        int loc = ss[0] + ss[1] + ss[2] + ss[3];
        int pre = loc;
        #pragma unroll
        for (int o = 1; o < 64; o <<= 1) {
            int v = __shfl_up(pre, o, 64);
            if (t >= o) pre += v;
        }
        int c = pre - loc;   // exclusive
        #pragma unroll
        for (int i = 0; i < 4; i++) {
            if (c < KSEL && c + ss[i] >= KSEL) { sel[0] = 4*t + i; sel[1] = c; }
            c += ss[i];
        }
    }
    __syncthreads();
    int b1 = sel[0], base1 = sel[1];
    __syncthreads();
    hist[t] = 0;
    __syncthreads();
    #pragma unroll
    for (int e = 0; e < 8; e++)
        if ((int)(ks[e] >> 8) == b1) atomicAdd(&hist[ks[e] & 0xffu], 1);
    __syncthreads();
    if (t < 64) {
        int target = KSEL - base1;
        int ss[4];
        #pragma unroll
        for (int i = 0; i < 4; i++) ss[i] = hist[4*t + i];
        int loc = ss[0] + ss[1] + ss[2] + ss[3];
        int pre = loc;
        #pragma unroll
        for (int o = 1; o < 64; o <<= 1) {
            int v = __shfl_up(pre, o, 64);
            if (t >= o) pre += v;
        }
        int c = pre - loc;
        #pragma unroll
        for (int i = 0; i < 4; i++) {
            if (c < target && c + ss[i] >= target) sel[0] = 4*t + i;
            c += ss[i];
        }
    }
    __syncthreads();
    unsigned P = ((unsigned)b1 << 8) | (unsigned)sel[0];
    #pragma unroll
    for (int e = 0; e < 8; e++) {
        if (ks[e] <= P) {
            int pos = atomicAdd(&cnt_s, 1);
            if (pos < KCAP) cand[(size_t)n*KCAP + pos] = t*8 + e;
        }
    }
    __syncthreads();
    if (t == 0) ccnt[n] = (cnt_s < KCAP) ? cnt_s : KCAP;
}

// ---------- refine: f64 direct squared distance over candidates, exact top-30 ----------
template<int C>
__global__ __launch_bounds__(256) void k_refine(const float* __restrict__ F,
                                                const int* __restrict__ cand,
                                                const int* __restrict__ ccnt,
                                                int* __restrict__ idx) {
    int t = threadIdx.x;
    int lane = t & 63;
    int row = blockIdx.x*4 + (t >> 6);
    int b = row >> 11;
    const float* fp = F + (size_t)row*C;
    int cnt = ccnt[row];
    bool act = lane < cnt;
    int q = act ? cand[(size_t)row*KCAP + lane] : 0;
    const float* fq = F + (size_t)(b*PNUM + q)*C;
    double d = 1e300;
    if (act) {
        d = 0.0;
        if (C == 64) {
            #pragma unroll
            for (int c4 = 0; c4 < C/4; c4++) {
                float4 a = ((const float4*)fp)[c4];
                float4 bb = ((const float4*)fq)[c4];
                double d0 = (double)a.x - (double)bb.x;
                double d1 = (double)a.y - (double)bb.y;
                double d2 = (double)a.z - (double)bb.z;
                double d3 = (double)a.w - (double)bb.w;
                d += d0*d0 + d1*d1 + d2*d2 + d3*d3;
            }
        } else {
            #pragma unroll
            for (int c = 0; c < C; c++) {
                double df = (double)fp[c] - (double)fq[c];
                d += df*df;
            }
        }
    }
    for (int it = 0; it < KNN; it++) {
        double m = d;
        #pragma unroll
        for (int off = 32; off >= 1; off >>= 1) {
            double o = __shfl_xor(m, off, 64);
            m = (o < m) ? o : m;
        }
        int cid = (d == m) ? q : 0x7fffffff;
        int cm = cid;
        #pragma unroll
        for (int off = 32; off >= 1; off >>= 1) {
            int o = __shfl_xor(cm, off, 64);
            cm = (o < cm) ? o : cm;
        }
        if (d == m && q == cm) {
            idx[(size_t)row*KNN + it] = q;
            d = 1e300;
        }
    }
}

// ---------- W0c = W0a - W0b ----------
__global__ void k_diffw(const float* __restrict__ W0, float* __restrict__ W0c, int CE) {
    int i = blockIdx.x*256 + threadIdx.x;
    if (i < CE) W0c[i] = W0[i] - W0[CE + i];
}

// ---------- 64-wide tiled f32 GEMM (small N / small K cases) ----------
template<int RELU>
__global__ __launch_bounds__(256) void k_gemm(const float* __restrict__ A,
                                              const float* __restrict__ W,
                                              const float* __restrict__ bias,
                                              float* __restrict__ out,
                                              int M, int Kd, int Nd) {
    __shared__ float As[64][17];
    __shared__ float Bs[16][64];
    int m0 = blockIdx.x*64, n0 = blockIdx.y*64;
    int t = threadIdx.x;
    int cb = (t & 15)*4, rb = (t >> 4)*4;
    float acc[4][4] = {};
    for (int k0 = 0; k0 < Kd; k0 += 16) {
        #pragma unroll
        for (int j = 0; j < 4; j++) {
            int e = t + 256*j;
            int r = e >> 4, c = e & 15;
            As[r][c] = (k0 + c < Kd) ? A[(size_t)(m0 + r)*Kd + k0 + c] : 0.f;
        }
        #pragma unroll
        for (int j = 0; j < 4; j++) {
            int e = t + 256*j;
            int r = e >> 6, c = e & 63;
            Bs[r][c] = (k0 + r < Kd && n0 + c < Nd) ? W[(size_t)(k0 + r)*Nd + n0 + c] : 0.f;
        }
        __syncthreads();
        #pragma unroll
        for (int kk = 0; kk < 16; kk++) {
            float a[4];
            #pragma unroll
            for (int i = 0; i < 4; i++) a[i] = As[rb + i][kk];
            float4 w4 = *(const float4*)&Bs[kk][cb];
            float w[4] = {w4.x, w4.y, w4.z, w4.w};
            #pragma unroll
            for (int i = 0; i < 4; i++)
                #pragma unroll
                for (int j = 0; j < 4; j++) acc[i][j] += a[i]*w[j];
        }
        __syncthreads();
    }
    #pragma unroll
    for (int i = 0; i < 4; i++) {
        int row = m0 + rb + i;
        #pragma unroll
        for (int j = 0; j < 4; j++) {
            int col = n0 + cb + j;
            if (col < Nd) {
                float v = acc[i][j] + (bias ? bias[col] : 0.f);
                if (RELU) v = fmaxf(v, 0.f);
                out[(size_t)row*Nd + col] = v;
            }
        }
    }
}

// ---------- 128x128 tiled f32 GEMM, 8x8 acc/thread. Requires M%128==0, Nd%128==0, Kd%16==0 ----------
template<int RELU>
__global__ __launch_bounds__(256) void k_gemm128(const float* __restrict__ A,
                                                 const float* __restrict__ W,
                                                 const float* __restrict__ bias,
                                                 float* __restrict__ out,
                                                 int M, int Kd, int Nd) {
    __shared__ float As[16][132];
    __shared__ float Bs[16][132];
    int m0 = blockIdx.x*128, n0 = blockIdx.y*128;
    int t = threadIdx.x;
    int tc = (t & 15)*8, tr = (t >> 4)*8;
    float acc[8][8] = {};
    for (int k0 = 0; k0 < Kd; k0 += 16) {
        #pragma unroll
        for (int h = 0; h < 2; h++) {
            int f4 = t + 256*h;
            int r = f4 >> 2, c4 = (f4 & 3)*4;
            float4 a4 = *(const float4*)&A[(size_t)(m0 + r)*Kd + k0 + c4];
            As[c4+0][r] = a4.x; As[c4+1][r] = a4.y; As[c4+2][r] = a4.z; As[c4+3][r] = a4.w;
        }
        #pragma unroll
        for (int h = 0; h < 2; h++) {
            int f4 = t + 256*h;
            int r = f4 >> 5, c4 = (f4 & 31)*4;
            *(float4*)&Bs[r][c4] = *(const float4*)&W[(size_t)(k0 + r)*Nd + n0 + c4];
        }
        __syncthreads();
        #pragma unroll
        for (int kk = 0; kk < 16; kk++) {
            float4 a0 = *(const float4*)&As[kk][tr];
            float4 a1 = *(const float4*)&As[kk][tr+4];
            float4 b0 = *(const float4*)&Bs[kk][tc];
            float4 b1 = *(const float4*)&Bs[kk][tc+4];
            float av[8] = {a0.x,a0.y,a0.z,a0.w,a1.x,a1.y,a1.z,a1.w};
            float bv[8] = {b0.x,b0.y,b0.z,b0.w,b1.x,b1.y,b1.z,b1.w};
            #pragma unroll
            for (int i = 0; i < 8; i++)
                #pragma unroll
                for (int j = 0; j < 8; j++) acc[i][j] = fmaf(av[i], bv[j], acc[i][j]);
        }
        __syncthreads();
    }
    float bv[8];
    #pragma unroll
    for (int j = 0; j < 8; j++) bv[j] = bias ? bias[n0 + tc + j] : 0.f;
    #pragma unroll
    for (int i = 0; i < 8; i++) {
        int row = m0 + tr + i;
        float o[8];
        #pragma unroll
        for (int j = 0; j < 8; j++) {
            float v = acc[i][j] + bv[j];
            o[j] = RELU ? fmaxf(v, 0.f) : v;
        }
        *(float4*)&out[(size_t)row*Nd + n0 + tc]     = make_float4(o[0], o[1], o[2], o[3]);
        *(float4*)&out[(size_t)row*Nd + n0 + tc + 4] = make_float4(o[4], o[5], o[6], o[7]);
    }
}

// ---------- stats of relu(u_p + v_q) over all edges ----------
__global__ __launch_bounds__(256) void k_e1stats(const float* __restrict__ u,
                                                 const float* __restrict__ v,
                                                 const int* __restrict__ idx,
                                                 float* __restrict__ psum, float* __restrict__ psq) {
    int t = threadIdx.x;
    float s = 0.f, sq = 0.f;
    const int stride = 4096*256;
    int i = blockIdx.x*256 + t;
    #pragma unroll 1
    for (int j = 0; j < 30; j++, i += stride) {
        int edge = i >> 6, c = i & 63;
        int p = edge / KNN;
        int q = idx[edge];
        int b = p >> 11;
        float h = u[(size_t)p*64 + c] + v[(size_t)(b*PNUM + q)*64 + c];
        h = fmaxf(h, 0.f);
        s += h; sq += h*h;
    }
    __shared__ float rs[256], rq[256];
    rs[t] = s; rq[t] = sq;
    __syncthreads();
    if (t < 128) { rs[t] += rs[t+128]; rq[t] += rq[t+128]; }
    __syncthreads();
    if (t < 64) {
        rs[t] += rs[t+64]; rq[t] += rq[t+64];
        psum[(size_t)blockIdx.x*64 + t] = rs[t];
        psq [(size_t)blockIdx.x*64 + t] = rq[t];
    }
}

// ---------- finalize BN stats ----------
__global__ void k_statsfin(const float* __restrict__ psum, const float* __restrict__ psq,
                           int npart, int C, float invM,
                           const float* __restrict__ g, const float* __restrict__ be,
                           float* __restrict__ scale, float* __restrict__ shift) {
    int c = blockIdx.x, t = threadIdx.x;
    float s = 0.f, q = 0.f;
    for (int i = t; i < npart; i += 256) {
        s += psum[(size_t)i*C + c];
        q += psq [(size_t)i*C + c];
    }
    __shared__ float rs[256], rq[256];
    rs[t] = s; rq[t] = q; __syncthreads();
    for (int off = 128; off >= 1; off >>= 1) {
        if (t < off) { rs[t] += rs[t+off]; rq[t] += rq[t+off]; }
        __syncthreads();
    }
    if (t == 0) {
        float m   = rs[0]*invM;
        float var = rq[0]*invM - m*m;
        float inv = rsqrtf(var + EPSF);
        float sc  = g[c]*inv;
        scale[c] = sc;
        shift[c] = be[c] - m*sc;
    }
}

// ---------- fold BN affine into next linear ----------
__global__ void k_fold(const float* __restrict__ W, const float* __restrict__ b,
                       const float* __restrict__ scale, const float* __restrict__ shift,
                       float* __restrict__ Wp, float* __restrict__ bp, int Cin, int Cout) {
    int co = blockIdx.x, t = threadIdx.x;
    float acc = 0.f;
    for (int ci = t; ci < Cin; ci += 256) {
        float w = W[(size_t)ci*Cout + co];
        Wp[(size_t)ci*Cout + co] = scale[ci]*w;
        acc += shift[ci]*w;
    }
    __shared__ float r[256];
    r[t] = acc; __syncthreads();
    for (int off = 128; off >= 1; off >>= 1) { if (t < off) r[t] += r[t+off]; __syncthreads(); }
    if (t == 0) bp[co] = b[co] + r[0];
}

// ---------- edge layer 1: wave-per-point register GEMM + pool + stats ----------
__global__ __launch_bounds__(256, 4) void k_e2(const float* __restrict__ u, const float* __restrict__ v,
                                               const int* __restrict__ idx,
                                               const float* __restrict__ W1p, const float* __restrict__ b1p,
                                               float* __restrict__ pmax, float* __restrict__ pmin,
                                               float* __restrict__ psum, float* __restrict__ psq) {
    __shared__ float W1s[64][64];   // 16 KB: W1s[c][co]
    int t = threadIdx.x, lane = t & 63, w = t >> 6;
    int p = blockIdx.x*4 + w;
    int b = p >> 11;
    for (int e = t; e < 4096; e += 256) W1s[e >> 6][e & 63] = W1p[e];
    __syncthreads();
    float wcol[64];
    #pragma unroll
    for (int c = 0; c < 64; c++) wcol[c] = W1s[c][lane];   // conflict-free column read
    float ureg = u[(size_t)p*64 + lane];
    float bias = b1p[lane];
    const int* myidx = idx + (size_t)p*KNN;
    const float* vb = v + (size_t)b*PNUM*64;
    float mx = -1e30f, mn = 1e30f, sm = 0.f, sq = 0.f;
    int q = myidx[0];
    float vk = vb[(size_t)q*64 + lane];
    #pragma unroll 1
    for (int k = 0; k < KNN; k++) {
        float h = fmaxf(ureg + vk, 0.f);
        if (k + 1 < KNN) {               // prefetch next neighbor row
            int qn = myidx[k + 1];
            vk = vb[(size_t)qn*64 + lane];
        }
        float a0 = 0.f, a1 = 0.f, a2 = 0.f, a3 = 0.f;
        #pragma unroll
        for (int c = 0; c < 64; c += 4) {
            a0 = fmaf(lane_bcast(h, c    ), wcol[c    ], a0);
            a1 = fmaf(lane_bcast(h, c + 1), wcol[c + 1], a1);
            a2 = fmaf(lane_bcast(h, c + 2), wcol[c + 2], a2);
            a3 = fmaf(lane_bcast(h, c + 3), wcol[c + 3], a3);
        }
        float o = fmaxf((a0 + a1) + (a2 + a3) + bias, 0.f);
        mx = fmaxf(mx, o);
        mn = fminf(mn, o);
        sm += o;
        sq += o*o;
    }
    pmax[(size_t)p*64 + lane] = mx;
    pmin[(size_t)p*64 + lane] = mn;
    psum[(size_t)p*64 + lane] = sm;
    psq [(size_t)p*64 + lane] = sq;
}

// ---------- BN1 applied after pooling (max if scale>=0 else min) ----------
__global__ void k_applypool(const float* __restrict__ pmax, const float* __restrict__ pmin,
                            const float* __restrict__ scale, const float* __restrict__ shift,
                            float* __restrict__ out) {
    int i = blockIdx.x*256 + threadIdx.x;
    int c = i & 63;
    float sc = scale[c];
    float pooled = (sc >= 0.f) ? pmax[i] : pmin[i];
    out[i] = sc*pooled + shift[c];
}

// ---------- Hin = concat(x1,x2,x3) ----------
__global__ void k_concat192(const float* __restrict__ x1, const float* __restrict__ x2,
                            const float* __restrict__ x3, float* __restrict__ H) {
    int i = blockIdx.x*256 + threadIdx.x;
    int n = i / 192, c = i % 192;
    const float* src = (c < 64) ? x1 : (c < 128) ? x2 : x3;
    H[i] = src[(size_t)n*64 + (c & 63)];
}

// ---------- per-column partial sums over 64-row blocks ----------
__global__ void k_colstats(const float* __restrict__ Hbuf, float* __restrict__ psum,
                           float* __restrict__ psq, int Cout) {
    int m0 = blockIdx.x*64, c0 = blockIdx.y*64;
    int t = threadIdx.x;
    int c = t & 63, rg = t >> 6;
    float s = 0.f, q = 0.f;
    #pragma unroll 4
    for (int r = 0; r < 16; r++) {
        float hv = Hbuf[(size_t)(m0 + rg*16 + r)*Cout + c0 + c];
        s += hv; q += hv*hv;
    }
    __shared__ float rs[256], rq[256];
    rs[t] = s; rq[t] = q; __syncthreads();
    if (t < 128) { rs[t] += rs[t+128]; rq[t] += rq[t+128]; }
    __syncthreads();
    if (t < 64) {
        rs[t] += rs[t+64]; rq[t] += rq[t+64];
        psum[(size_t)blockIdx.x*Cout + c0 + t] = rs[t];
        psq [(size_t)blockIdx.x*Cout + c0 + t] = rq[t];
    }
}

// ---------- log_softmax over 50 cols, one wave per row ----------
__global__ void k_logsoftmax(const float* __restrict__ logits, float* __restrict__ out) {
    int t = threadIdx.x;
    int n = blockIdx.x*4 + (t >> 6);
    int l = t & 63;
    float z = (l < 50) ? logits[(size_t)n*50 + l] : -INFINITY;
    float mx = z;
    #pragma unroll
    for (int off = 32; off >= 1; off >>= 1) mx = fmaxf(mx, __shfl_xor(mx, off, 64));
    float ex = (l < 50) ? expf(z - mx) : 0.f;
    float sm = ex;
    #pragma unroll
    for (int off = 32; off >= 1; off >>= 1) sm += __shfl_xor(sm, off, 64);
    float lse = mx + logf(sm);
    if (l < 50) out[(size_t)n*50 + l] = z - lse;
}

extern "C" void kernel_launch(void* const* d_in, const int* in_sizes, int n_in,
                              void* d_out, int out_size, void* d_ws, size_t ws_size,
                              hipStream_t stream) {
    (void)in_sizes; (void)n_in; (void)out_size;
    const float* x   = (const float*)d_in[0];
    const float* pos = (const float*)d_in[1];
    const float* prm[38];
    for (int i = 0; i < 38; i++) prm[i] = (const float*)d_in[3 + i];
    // prm: c1[0..7] c2[8..15] c3[16..23] l1[24..27] h0[28..31] h1[32..35] ho[36..37]

    float* ws = (float*)d_ws;
    size_t off = 0;
    auto alloc = [&](size_t cnt) { float* p = ws + off; off += (cnt + 63) & ~((size_t)63); return p; };
    float* f0   = alloc((size_t)NPT*6);
    float* s    = alloc(NPT);
    float* x1   = alloc((size_t)NPT*64);
    float* x2   = alloc((size_t)NPT*64);
    float* x3   = alloc((size_t)NPT*64);
    float* u    = alloc((size_t)NPT*64);
    float* v    = alloc((size_t)NPT*64);
    float* pmax = alloc((size_t)NPT*64);
    float* pmin = alloc((size_t)NPT*64);
    int*   idx  = (int*)alloc((size_t)NPT*KNN);
    int*   ccnt = (int*)alloc(NPT);
    float* W0c  = alloc(64*64);
    float* W1p  = alloc(64*64);
    float* b1p  = alloc(64);
    float* scaleA = alloc(1024);
    float* shiftA = alloc(1024);
    float* Wp   = alloc(1024*256);
    float* bp   = alloc(1024);
    float* psum = alloc((size_t)NPT*64);
    float* psq  = alloc((size_t)NPT*64);
    float* big  = alloc((size_t)BNUM*PNUM*PNUM);   // shared: Dk (u16), then head activations
    if (off*sizeof(float) > ws_size) return;       // insufficient workspace -> leave poisoned

    // cand (NPT*KCAP ints = 4 MB) aliases psum (4 MB): dead ranges don't overlap in time
    int* cand = (int*)psum;
    ushort_t* Dk = (ushort_t*)big;

    auto conv = [&](const float* F, int C, const float* const* pp, float* xout) {
        if (C == 6) k_snorm<6><<<NPT/256, 256, 0, stream>>>(F, s);
        else        k_snorm<64><<<NPT/256, 256, 0, stream>>>(F, s);
        if (C == 6) k_dist<6><<<dim3(16,16,8), 256, 0, stream>>>(F, s, Dk);
        else        k_dist<64><<<dim3(16,16,8), 256, 0, stream>>>(F, s, Dk);
        k_topk<<<NPT, 256, 0, stream>>>(Dk, cand, ccnt);
        if (C == 6) k_refine<6><<<NPT/4, 256, 0, stream>>>(F, cand, ccnt, idx);
        else        k_refine<64><<<NPT/4, 256, 0, stream>>>(F, cand, ccnt, idx);
        k_diffw<<<(C*64 + 255)/256, 256, 0, stream>>>(pp[0], W0c, C*64);
        k_gemm<0><<<dim3(NPT/64, 1), 256, 0, stream>>>(F, W0c, pp[1], u, NPT, C, 64);
        k_gemm<0><<<dim3(NPT/64, 1), 256, 0, stream>>>(F, pp[0] + C*64, nullptr, v, NPT, C, 64);
        k_e1stats<<<4096, 256, 0, stream>>>(u, v, idx, psum, psq);
        k_statsfin<<<64, 256, 0, stream>>>(psum, psq, 4096, 64, 1.f/((float)NPT*KNN),
                                           pp[2], pp[3], scaleA, shiftA);
        k_fold<<<64, 256, 0, stream>>>(pp[4], pp[5], scaleA, shiftA, W1p, b1p, 64, 64);
        k_e2<<<NPT/4, 256, 0, stream>>>(u, v, idx, W1p, b1p, pmax, pmin, psum, psq);
        k_statsfin<<<64, 256, 0, stream>>>(psum, psq, NPT, 64, 1.f/((float)NPT*KNN),
                                           pp[6], pp[7], scaleA, shiftA);
        k_applypool<<<NPT*64/256, 256, 0, stream>>>(pmax, pmin, scaleA, shiftA, xout);
    };

    k_concat6<<<NPT*6/256, 256, 0, stream>>>(x, pos, f0);
    conv(f0, 6,  &prm[0],  x1);
    conv(x1, 64, &prm[8],  x2);
    conv(x2, 64, &prm[16], x3);

    float* Hin    = big;
    float* Hb1    = big + 3145728;
    float* Hb2    = big + 19922944;
    float* Hb3    = big + 24117248;
    float* logits = big + 26214400;

    k_concat192<<<NPT*192/256, 256, 0, stream>>>(x1, x2, x3, Hin);
    k_gemm128<1><<<dim3(NPT/128, 8), 256, 0, stream>>>(Hin, prm[24], prm[25], Hb1, NPT, 192, 1024);
    k_colstats<<<dim3(NPT/64, 16), 256, 0, stream>>>(Hb1, psum, psq, 1024);
    k_statsfin<<<1024, 256, 0, stream>>>(psum, psq, NPT/64, 1024, 1.f/(float)NPT,
                                         prm[26], prm[27], scaleA, shiftA);
    k_fold<<<256, 256, 0, stream>>>(prm[28], prm[29], scaleA, shiftA, Wp, bp, 1024, 256);
    k_gemm128<1><<<dim3(NPT/128, 2), 256, 0, stream>>>(Hb1, Wp, bp, Hb2, NPT, 1024, 256);
    k_colstats<<<dim3(NPT/64, 4), 256, 0, stream>>>(Hb2, psum, psq, 256);
    k_statsfin<<<256, 256, 0, stream>>>(psum, psq, NPT/64, 256, 1.f/(float)NPT,
                                        prm[30], prm[31], scaleA, shiftA);
    k_fold<<<128, 256, 0, stream>>>(prm[32], prm[33], scaleA, shiftA, Wp, bp, 256, 128);
    k_gemm128<1><<<dim3(NPT/128, 1), 256, 0, stream>>>(Hb2, Wp, bp, Hb3, NPT, 256, 128);
    k_colstats<<<dim3(NPT/64, 2), 256, 0, stream>>>(Hb3, psum, psq, 128);
    k_statsfin<<<128, 256, 0, stream>>>(psum, psq, NPT/64, 128, 1.f/(float)NPT,
                                        prm[34], prm[35], scaleA, shiftA);
    k_fold<<<50, 256, 0, stream>>>(prm[36], prm[37], scaleA, shiftA, Wp, bp, 128, 50);
    k_gemm<0><<<dim3(NPT/64, 1), 256, 0, stream>>>(Hb3, Wp, bp, logits, NPT, 128, 50);
    k_logsoftmax<<<NPT/4, 256, 0, stream>>>(logits, (float*)d_out);
}

// Round 6
// 1623.946 us; speedup vs baseline: 2.4229x; 1.0774x over previous
//
#include <hip/hip_runtime.h>
#include <hip/hip_bf16.h>
#include <stdint.h>

#define BNUM 8
#define PNUM 2048
#define KNN  30
#define KSEL 40      // rank threshold for candidate selection
#define KCAP 64      // max candidates per row (one wave in refine)
#define NPT  (BNUM*PNUM)   // 16384
#define EPSF 1e-5f

typedef unsigned long long u64;
typedef unsigned short ushort_t;

__device__ __forceinline__ float lane_bcast(float x, int l) {
    return __int_as_float(__builtin_amdgcn_readlane(__float_as_int(x), l));
}

__device__ __forceinline__ unsigned mono_key(float d) {
    unsigned u = __float_as_uint(d);
    return (u & 0x80000000u) ? ~u : (u | 0x80000000u);   // monotone float->uint
}

// ---------- f0 = concat(x, pos) ----------
__global__ void k_concat6(const float* __restrict__ x, const float* __restrict__ pos,
                          float* __restrict__ f0) {
    int i = blockIdx.x*256 + threadIdx.x;        // < N*6
    int n = i/6, c = i%6;
    f0[i] = (c < 3) ? x[n*3 + c] : pos[n*3 + c - 3];
}

// ---------- dist 128x128 tile (snorm fused): Dk = top16(monokey(s_p+s_q-2 f_p.f_q)) ----------
template<int C>
__global__ __launch_bounds__(256) void k_dist(const float* __restrict__ F,
                                              ushort_t* __restrict__ Dk) {
    __shared__ float FpT[C][132];
    __shared__ float FqT[C][132];
    __shared__ float sp[128], sq[128];
    int b = blockIdx.z;
    int p0 = blockIdx.x*128, q0 = blockIdx.y*128;
    int t = threadIdx.x;
    for (int e = t; e < 128*C; e += 256) {
        int r = e / C, c = e % C;
        FpT[c][r] = F[(size_t)(b*PNUM + p0 + r)*C + c];
        FqT[c][r] = F[(size_t)(b*PNUM + q0 + r)*C + c];
    }
    __syncthreads();
    if (t < 128) {
        float a = 0.f;
        for (int c = 0; c < C; c++) { float xv = FpT[c][t]; a = fmaf(xv, xv, a); }
        sp[t] = a;
    } else {
        int r = t - 128;
        float a = 0.f;
        for (int c = 0; c < C; c++) { float xv = FqT[c][r]; a = fmaf(xv, xv, a); }
        sq[r] = a;
    }
    __syncthreads();
    int tc = (t & 15)*8, tr = (t >> 4)*8;
    float acc[8][8] = {};
    #pragma unroll 4
    for (int c = 0; c < C; c++) {
        float4 p0v = *(const float4*)&FpT[c][tr];
        float4 p1v = *(const float4*)&FpT[c][tr+4];
        float4 q0v = *(const float4*)&FqT[c][tc];
        float4 q1v = *(const float4*)&FqT[c][tc+4];
        float av[8] = {p0v.x,p0v.y,p0v.z,p0v.w,p1v.x,p1v.y,p1v.z,p1v.w};
        float bv[8] = {q0v.x,q0v.y,q0v.z,q0v.w,q1v.x,q1v.y,q1v.z,q1v.w};
        #pragma unroll
        for (int i = 0; i < 8; i++)
            #pragma unroll
            for (int j = 0; j < 8; j++) acc[i][j] = fmaf(av[i], bv[j], acc[i][j]);
    }
    #pragma unroll
    for (int i = 0; i < 8; i++) {
        unsigned ks[8];
        #pragma unroll
        for (int j = 0; j < 8; j++) {
            float d = sp[tr + i] + sq[tc + j] - 2.0f*acc[i][j];
            ks[j] = mono_key(d) >> 16;
        }
        uint4 w;
        w.x = ks[0] | (ks[1] << 16);
        w.y = ks[2] | (ks[3] << 16);
        w.z = ks[4] | (ks[5] << 16);
        w.w = ks[6] | (ks[7] << 16);
        *(uint4*)&Dk[(size_t)(b*PNUM + p0 + tr + i)*PNUM + q0 + tc] = w;
    }
}

// ---------- candidate select: binary search threshold on u16 keys; no atomics ----------
// P = smallest key with count(keys<=P) >= KSEL; emit all q with key<=P (first KCAP in
// index order, deterministic). Superset of f32-top-KSEL unless >KCAP ties (then still
// deterministic). Exact order/membership fixed downstream by f64 k_refine.
__global__ __launch_bounds__(256) void k_topk(const ushort_t* __restrict__ Dk,
                                              int* __restrict__ cand, int* __restrict__ ccnt) {
    __shared__ int red[4];
    __shared__ int wbase[4];
    int n = blockIdx.x, t = threadIdx.x, lane = t & 63, w = t >> 6;
    uint4 wv = *(const uint4*)(Dk + (size_t)n*PNUM + t*8);
    int ks[8];
    ks[0] = wv.x & 0xffff; ks[1] = wv.x >> 16;
    ks[2] = wv.y & 0xffff; ks[3] = wv.y >> 16;
    ks[4] = wv.z & 0xffff; ks[5] = wv.z >> 16;
    ks[6] = wv.w & 0xffff; ks[7] = wv.w >> 16;
    int lo = 0, hi = 65535;
    while (lo < hi) {                      // 16 iterations, block-uniform
        int mid = (lo + hi) >> 1;
        int c = 0;
        #pragma unroll
        for (int e = 0; e < 8; e++) c += (ks[e] <= mid);
        #pragma unroll
        for (int o = 32; o >= 1; o >>= 1) c += __shfl_xor(c, o, 64);
        if (lane == 0) red[w] = c;
        __syncthreads();
        int tot = red[0] + red[1] + red[2] + red[3];
        __syncthreads();
        if (tot >= KSEL) hi = mid; else lo = mid + 1;
    }
    int P = lo;
    int lc = 0;
    #pragma unroll
    for (int e = 0; e < 8; e++) lc += (ks[e] <= P);
    int pre = lc;                          // inclusive prefix within wave
    #pragma unroll
    for (int o = 1; o < 64; o <<= 1) { int vv = __shfl_up(pre, o, 64); if (lane >= o) pre += vv; }
    int excl = pre - lc;
    if (lane == 63) red[w] = pre;          // wave totals
    __syncthreads();
    if (t == 0) {
        int s0 = 0;
        #pragma unroll
        for (int i = 0; i < 4; i++) { wbase[i] = s0; s0 += red[i]; }
        ccnt[n] = (s0 < KCAP) ? s0 : KCAP;
    }
    __syncthreads();
    int base = wbase[w] + excl;
    #pragma unroll
    for (int e = 0; e < 8; e++) {
        if (ks[e] <= P) {
            if (base < KCAP) cand[(size_t)n*KCAP + base] = t*8 + e;
            base++;
        }
    }
}

// ---------- refine: f64 direct squared distance over candidates, exact top-30 ----------
template<int C>
__global__ __launch_bounds__(256) void k_refine(const float* __restrict__ F,
                                                const int* __restrict__ cand,
                                                const int* __restrict__ ccnt,
                                                int* __restrict__ idx) {
    int t = threadIdx.x;
    int lane = t & 63;
    int row = blockIdx.x*4 + (t >> 6);
    int b = row >> 11;
    const float* fp = F + (size_t)row*C;
    int cnt = ccnt[row];
    bool act = lane < cnt;
    int q = act ? cand[(size_t)row*KCAP + lane] : 0;
    const float* fq = F + (size_t)(b*PNUM + q)*C;
    double d = 1e300;
    if (act) {
        d = 0.0;
        if (C == 64) {
            #pragma unroll
            for (int c4 = 0; c4 < C/4; c4++) {
                float4 a = ((const float4*)fp)[c4];
                float4 bb = ((const float4*)fq)[c4];
                double d0 = (double)a.x - (double)bb.x;
                double d1 = (double)a.y - (double)bb.y;
                double d2 = (double)a.z - (double)bb.z;
                double d3 = (double)a.w - (double)bb.w;
                d += d0*d0 + d1*d1 + d2*d2 + d3*d3;
            }
        } else {
            #pragma unroll
            for (int c = 0; c < C; c++) {
                double df = (double)fp[c] - (double)fq[c];
                d += df*df;
            }
        }
    }
    for (int it = 0; it < KNN; it++) {
        double m = d;
        #pragma unroll
        for (int off = 32; off >= 1; off >>= 1) {
            double o = __shfl_xor(m, off, 64);
            m = (o < m) ? o : m;
        }
        int cid = (d == m) ? q : 0x7fffffff;
        int cm = cid;
        #pragma unroll
        for (int off = 32; off >= 1; off >>= 1) {
            int o = __shfl_xor(cm, off, 64);
            cm = (o < cm) ? o : cm;
        }
        if (d == m && q == cm) {
            idx[(size_t)row*KNN + it] = q;
            d = 1e300;
        }
    }
}

// ---------- fused u/v GEMM: u = F@(W0a-W0b)+b0, v = F@W0b ----------
template<int C>
__global__ __launch_bounds__(256) void k_uv(const float* __restrict__ F,
                                            const float* __restrict__ W0,
                                            const float* __restrict__ b0,
                                            float* __restrict__ u, float* __restrict__ v) {
    __shared__ float As[64][17];
    __shared__ float Wa[16][64];
    __shared__ float Wb[16][64];
    int m0 = blockIdx.x*64;
    int t = threadIdx.x;
    int cb = (t & 15)*4, rb = (t >> 4)*4;
    float aU[4][4] = {}, aV[4][4] = {};
    for (int k0 = 0; k0 < C; k0 += 16) {
        #pragma unroll
        for (int j = 0; j < 4; j++) {
            int e = t + 256*j;
            int r = e >> 4, c = e & 15;
            As[r][c] = (k0 + c < C) ? F[(size_t)(m0 + r)*C + k0 + c] : 0.f;
        }
        {
            int r = t >> 4, c4 = (t & 15)*4;
            bool ok = (k0 + r < C);
            float4 wa = ok ? *(const float4*)&W0[(size_t)(k0 + r)*64 + c4] : make_float4(0,0,0,0);
            float4 wb = ok ? *(const float4*)&W0[(size_t)(C + k0 + r)*64 + c4] : make_float4(0,0,0,0);
            *(float4*)&Wa[r][c4] = wa;
            *(float4*)&Wb[r][c4] = wb;
        }
        __syncthreads();
        #pragma unroll
        for (int kk = 0; kk < 16; kk++) {
            float a[4];
            #pragma unroll
            for (int i = 0; i < 4; i++) a[i] = As[rb + i][kk];
            float4 wa4 = *(const float4*)&Wa[kk][cb];
            float4 wb4 = *(const float4*)&Wb[kk][cb];
            float wa[4] = {wa4.x, wa4.y, wa4.z, wa4.w};
            float wb[4] = {wb4.x, wb4.y, wb4.z, wb4.w};
            #pragma unroll
            for (int i = 0; i < 4; i++)
                #pragma unroll
                for (int j = 0; j < 4; j++) {
                    aU[i][j] = fmaf(a[i], wa[j] - wb[j], aU[i][j]);
                    aV[i][j] = fmaf(a[i], wb[j], aV[i][j]);
                }
        }
        __syncthreads();
    }
    #pragma unroll
    for (int i = 0; i < 4; i++) {
        int row = m0 + rb + i;
        #pragma unroll
        for (int j = 0; j < 4; j++) {
            int col = cb + j;
            u[(size_t)row*64 + col] = aU[i][j] + b0[col];
            v[(size_t)row*64 + col] = aV[i][j];
        }
    }
}

// ---------- 64-wide tiled f32 GEMM (final ho layer) ----------
template<int RELU>
__global__ __launch_bounds__(256) void k_gemm(const float* __restrict__ A,
                                              const float* __restrict__ W,
                                              const float* __restrict__ bias,
                                              float* __restrict__ out,
                                              int M, int Kd, int Nd) {
    __shared__ float As[64][17];
    __shared__ float Bs[16][64];
    int m0 = blockIdx.x*64, n0 = blockIdx.y*64;
    int t = threadIdx.x;
    int cb = (t & 15)*4, rb = (t >> 4)*4;
    float acc[4][4] = {};
    for (int k0 = 0; k0 < Kd; k0 += 16) {
        #pragma unroll
        for (int j = 0; j < 4; j++) {
            int e = t + 256*j;
            int r = e >> 4, c = e & 15;
            As[r][c] = (k0 + c < Kd) ? A[(size_t)(m0 + r)*Kd + k0 + c] : 0.f;
        }
        #pragma unroll
        for (int j = 0; j < 4; j++) {
            int e = t + 256*j;
            int r = e >> 6, c = e & 63;
            Bs[r][c] = (k0 + r < Kd && n0 + c < Nd) ? W[(size_t)(k0 + r)*Nd + n0 + c] : 0.f;
        }
        __syncthreads();
        #pragma unroll
        for (int kk = 0; kk < 16; kk++) {
            float a[4];
            #pragma unroll
            for (int i = 0; i < 4; i++) a[i] = As[rb + i][kk];
            float4 w4 = *(const float4*)&Bs[kk][cb];
            float w[4] = {w4.x, w4.y, w4.z, w4.w};
            #pragma unroll
            for (int i = 0; i < 4; i++)
                #pragma unroll
                for (int j = 0; j < 4; j++) acc[i][j] += a[i]*w[j];
        }
        __syncthreads();
    }
    #pragma unroll
    for (int i = 0; i < 4; i++) {
        int row = m0 + rb + i;
        #pragma unroll
        for (int j = 0; j < 4; j++) {
            int col = n0 + cb + j;
            if (col < Nd) {
                float v = acc[i][j] + (bias ? bias[col] : 0.f);
                if (RELU) v = fmaxf(v, 0.f);
                out[(size_t)row*Nd + col] = v;
            }
        }
    }
}

// ---------- 128x128 tiled f32 GEMM for l1, A read directly from x1|x2|x3 ----------
__global__ __launch_bounds__(256) void k_gemm128_l1(const float* __restrict__ x1,
                                                    const float* __restrict__ x2,
                                                    const float* __restrict__ x3,
                                                    const float* __restrict__ W,
                                                    const float* __restrict__ bias,
                                                    float* __restrict__ out) {
    const int Kd = 192, Nd = 1024;
    __shared__ float As[16][132];
    __shared__ float Bs[16][132];
    int m0 = blockIdx.x*128, n0 = blockIdx.y*128;
    int t = threadIdx.x;
    int tc = (t & 15)*8, tr = (t >> 4)*8;
    float acc[8][8] = {};
    for (int k0 = 0; k0 < Kd; k0 += 16) {
        #pragma unroll
        for (int h = 0; h < 2; h++) {
            int f4 = t + 256*h;
            int r = f4 >> 2, c4 = (f4 & 3)*4;
            int k = k0 + c4;
            const float* src = (k < 64) ? x1 : (k < 128) ? x2 : x3;
            float4 a4 = *(const float4*)&src[(size_t)(m0 + r)*64 + (k & 63)];
            As[c4+0][r] = a4.x; As[c4+1][r] = a4.y; As[c4+2][r] = a4.z; As[c4+3][r] = a4.w;
        }
        #pragma unroll
        for (int h = 0; h < 2; h++) {
            int f4 = t + 256*h;
            int r = f4 >> 5, c4 = (f4 & 31)*4;
            *(float4*)&Bs[r][c4] = *(const float4*)&W[(size_t)(k0 + r)*Nd + n0 + c4];
        }
        __syncthreads();
        #pragma unroll
        for (int kk = 0; kk < 16; kk++) {
            float4 a0 = *(const float4*)&As[kk][tr];
            float4 a1 = *(const float4*)&As[kk][tr+4];
            float4 b0 = *(const float4*)&Bs[kk][tc];
            float4 b1 = *(const float4*)&Bs[kk][tc+4];
            float av[8] = {a0.x,a0.y,a0.z,a0.w,a1.x,a1.y,a1.z,a1.w};
            float bv[8] = {b0.x,b0.y,b0.z,b0.w,b1.x,b1.y,b1.z,b1.w};
            #pragma unroll
            for (int i = 0; i < 8; i++)
                #pragma unroll
                for (int j = 0; j < 8; j++) acc[i][j] = fmaf(av[i], bv[j], acc[i][j]);
        }
        __syncthreads();
    }
    float bv[8];
    #pragma unroll
    for (int j = 0; j < 8; j++) bv[j] = bias[n0 + tc + j];
    #pragma unroll
    for (int i = 0; i < 8; i++) {
        int row = m0 + tr + i;
        float o[8];
        #pragma unroll
        for (int j = 0; j < 8; j++) o[j] = fmaxf(acc[i][j] + bv[j], 0.f);
        *(float4*)&out[(size_t)row*Nd + n0 + tc]     = make_float4(o[0], o[1], o[2], o[3]);
        *(float4*)&out[(size_t)row*Nd + n0 + tc + 4] = make_float4(o[4], o[5], o[6], o[7]);
    }
}

// ---------- 128x64 tiled f32 GEMM, 8x4 acc (better grid occupancy for narrow N) ----------
template<int RELU>
__global__ __launch_bounds__(256) void k_gemm12864(const float* __restrict__ A,
                                                   const float* __restrict__ W,
                                                   const float* __restrict__ bias,
                                                   float* __restrict__ out,
                                                   int M, int Kd, int Nd) {
    __shared__ float As[16][132];
    __shared__ float Bs[16][68];
    int m0 = blockIdx.x*128, n0 = blockIdx.y*64;
    int t = threadIdx.x;
    int tc = (t & 15)*4, tr = (t >> 4)*8;
    float acc[8][4] = {};
    for (int k0 = 0; k0 < Kd; k0 += 16) {
        #pragma unroll
        for (int h = 0; h < 2; h++) {
            int f4 = t + 256*h;
            int r = f4 >> 2, c4 = (f4 & 3)*4;
            float4 a4 = *(const float4*)&A[(size_t)(m0 + r)*Kd + k0 + c4];
            As[c4+0][r] = a4.x; As[c4+1][r] = a4.y; As[c4+2][r] = a4.z; As[c4+3][r] = a4.w;
        }
        {
            int r = t >> 4, c4 = (t & 15)*4;
            *(float4*)&Bs[r][c4] = *(const float4*)&W[(size_t)(k0 + r)*Nd + n0 + c4];
        }
        __syncthreads();
        #pragma unroll
        for (int kk = 0; kk < 16; kk++) {
            float4 a0 = *(const float4*)&As[kk][tr];
            float4 a1 = *(const float4*)&As[kk][tr+4];
            float4 b0 = *(const float4*)&Bs[kk][tc];
            float av[8] = {a0.x,a0.y,a0.z,a0.w,a1.x,a1.y,a1.z,a1.w};
            float bv[4] = {b0.x,b0.y,b0.z,b0.w};
            #pragma unroll
            for (int i = 0; i < 8; i++)
                #pragma unroll
                for (int j = 0; j < 4; j++) acc[i][j] = fmaf(av[i], bv[j], acc[i][j]);
        }
        __syncthreads();
    }
    float bv[4];
    #pragma unroll
    for (int j = 0; j < 4; j++) bv[j] = bias ? bias[n0 + tc + j] : 0.f;
    #pragma unroll
    for (int i = 0; i < 8; i++) {
        int row = m0 + tr + i;
        float o[4];
        #pragma unroll
        for (int j = 0; j < 4; j++) {
            float v = acc[i][j] + bv[j];
            o[j] = RELU ? fmaxf(v, 0.f) : v;
        }
        *(float4*)&out[(size_t)row*Nd + n0 + tc] = make_float4(o[0], o[1], o[2], o[3]);
    }
}

// ---------- stats of relu(u_p + v_q) over all edges ----------
__global__ __launch_bounds__(256) void k_e1stats(const float* __restrict__ u,
                                                 const float* __restrict__ v,
                                                 const int* __restrict__ idx,
                                                 float* __restrict__ psum, float* __restrict__ psq) {
    int t = threadIdx.x;
    float s = 0.f, sq = 0.f;
    const int stride = 4096*256;
    int i = blockIdx.x*256 + t;
    #pragma unroll 1
    for (int j = 0; j < 30; j++, i += stride) {
        int edge = i >> 6, c = i & 63;
        int p = edge / KNN;
        int q = idx[edge];
        int b = p >> 11;
        float h = u[(size_t)p*64 + c] + v[(size_t)(b*PNUM + q)*64 + c];
        h = fmaxf(h, 0.f);
        s += h; sq += h*h;
    }
    __shared__ float rs[256], rq[256];
    rs[t] = s; rq[t] = sq;
    __syncthreads();
    if (t < 128) { rs[t] += rs[t+128]; rq[t] += rq[t+128]; }
    __syncthreads();
    if (t < 64) {
        rs[t] += rs[t+64]; rq[t] += rq[t+64];
        psum[(size_t)blockIdx.x*64 + t] = rs[t];
        psq [(size_t)blockIdx.x*64 + t] = rq[t];
    }
}

// ---------- finalize BN stats ----------
__global__ void k_statsfin(const float* __restrict__ psum, const float* __restrict__ psq,
                           int npart, int C, float invM,
                           const float* __restrict__ g, const float* __restrict__ be,
                           float* __restrict__ scale, float* __restrict__ shift) {
    int c = blockIdx.x, t = threadIdx.x;
    float s = 0.f, q = 0.f;
    for (int i = t; i < npart; i += 256) {
        s += psum[(size_t)i*C + c];
        q += psq [(size_t)i*C + c];
    }
    __shared__ float rs[256], rq[256];
    rs[t] = s; rq[t] = q; __syncthreads();
    for (int off = 128; off >= 1; off >>= 1) {
        if (t < off) { rs[t] += rs[t+off]; rq[t] += rq[t+off]; }
        __syncthreads();
    }
    if (t == 0) {
        float m   = rs[0]*invM;
        float var = rq[0]*invM - m*m;
        float inv = rsqrtf(var + EPSF);
        float sc  = g[c]*inv;
        scale[c] = sc;
        shift[c] = be[c] - m*sc;
    }
}

// ---------- fold BN affine into next linear ----------
__global__ void k_fold(const float* __restrict__ W, const float* __restrict__ b,
                       const float* __restrict__ scale, const float* __restrict__ shift,
                       float* __restrict__ Wp, float* __restrict__ bp, int Cin, int Cout) {
    int co = blockIdx.x, t = threadIdx.x;
    float acc = 0.f;
    for (int ci = t; ci < Cin; ci += 256) {
        float w = W[(size_t)ci*Cout + co];
        Wp[(size_t)ci*Cout + co] = scale[ci]*w;
        acc += shift[ci]*w;
    }
    __shared__ float r[256];
    r[t] = acc; __syncthreads();
    for (int off = 128; off >= 1; off >>= 1) { if (t < off) r[t] += r[t+off]; __syncthreads(); }
    if (t == 0) bp[co] = b[co] + r[0];
}

// ---------- edge layer 1: wave-per-point register GEMM + pool + stats ----------
__global__ __launch_bounds__(256, 4) void k_e2(const float* __restrict__ u, const float* __restrict__ v,
                                               const int* __restrict__ idx,
                                               const float* __restrict__ W1p, const float* __restrict__ b1p,
                                               float* __restrict__ pmax, float* __restrict__ pmin,
                                               float* __restrict__ psum, float* __restrict__ psq) {
    __shared__ float W1s[64][64];   // 16 KB: W1s[c][co]
    int t = threadIdx.x, lane = t & 63, w = t >> 6;
    int p = blockIdx.x*4 + w;
    int b = p >> 11;
    for (int e = t; e < 4096; e += 256) W1s[e >> 6][e & 63] = W1p[e];
    __syncthreads();
    float wcol[64];
    #pragma unroll
    for (int c = 0; c < 64; c++) wcol[c] = W1s[c][lane];   // conflict-free column read
    float ureg = u[(size_t)p*64 + lane];
    float bias = b1p[lane];
    const int* myidx = idx + (size_t)p*KNN;
    const float* vb = v + (size_t)b*PNUM*64;
    float mx = -1e30f, mn = 1e30f, sm = 0.f, sq = 0.f;
    int q = myidx[0];
    float vk = vb[(size_t)q*64 + lane];
    #pragma unroll 1
    for (int k = 0; k < KNN; k++) {
        float h = fmaxf(ureg + vk, 0.f);
        if (k + 1 < KNN) {               // prefetch next neighbor row
            int qn = myidx[k + 1];
            vk = vb[(size_t)qn*64 + lane];
        }
        float a0 = 0.f, a1 = 0.f, a2 = 0.f, a3 = 0.f;
        #pragma unroll
        for (int c = 0; c < 64; c += 4) {
            a0 = fmaf(lane_bcast(h, c    ), wcol[c    ], a0);
            a1 = fmaf(lane_bcast(h, c + 1), wcol[c + 1], a1);
            a2 = fmaf(lane_bcast(h, c + 2), wcol[c + 2], a2);
            a3 = fmaf(lane_bcast(h, c + 3), wcol[c + 3], a3);
        }
        float o = fmaxf((a0 + a1) + (a2 + a3) + bias, 0.f);
        mx = fmaxf(mx, o);
        mn = fminf(mn, o);
        sm += o;
        sq += o*o;
    }
    pmax[(size_t)p*64 + lane] = mx;
    pmin[(size_t)p*64 + lane] = mn;
    psum[(size_t)p*64 + lane] = sm;
    psq [(size_t)p*64 + lane] = sq;
}

// ---------- BN1 applied after pooling (max if scale>=0 else min) ----------
__global__ void k_applypool(const float* __restrict__ pmax, const float* __restrict__ pmin,
                            const float* __restrict__ scale, const float* __restrict__ shift,
                            float* __restrict__ out) {
    int i = blockIdx.x*256 + threadIdx.x;
    int c = i & 63;
    float sc = scale[c];
    float pooled = (sc >= 0.f) ? pmax[i] : pmin[i];
    out[i] = sc*pooled + shift[c];
}

// ---------- per-column partial sums over 64-row blocks ----------
__global__ void k_colstats(const float* __restrict__ Hbuf, float* __restrict__ psum,
                           float* __restrict__ psq, int Cout) {
    int m0 = blockIdx.x*64, c0 = blockIdx.y*64;
    int t = threadIdx.x;
    int c = t & 63, rg = t >> 6;
    float s = 0.f, q = 0.f;
    #pragma unroll 4
    for (int r = 0; r < 16; r++) {
        float hv = Hbuf[(size_t)(m0 + rg*16 + r)*Cout + c0 + c];
        s += hv; q += hv*hv;
    }
    __shared__ float rs[256], rq[256];
    rs[t] = s; rq[t] = q; __syncthreads();
    if (t < 128) { rs[t] += rs[t+128]; rq[t] += rq[t+128]; }
    __syncthreads();
    if (t < 64) {
        rs[t] += rs[t+64]; rq[t] += rq[t+64];
        psum[(size_t)blockIdx.x*Cout + c0 + t] = rs[t];
        psq [(size_t)blockIdx.x*Cout + c0 + t] = rq[t];
    }
}

// ---------- log_softmax over 50 cols, one wave per row ----------
__global__ void k_logsoftmax(const float* __restrict__ logits, float* __restrict__ out) {
    int t = threadIdx.x;
    int n = blockIdx.x*4 + (t >> 6);
    int l = t & 63;
    float z = (l < 50) ? logits[(size_t)n*50 + l] : -INFINITY;
    float mx = z;
    #pragma unroll
    for (int off = 32; off >= 1; off >>= 1) mx = fmaxf(mx, __shfl_xor(mx, off, 64));
    float ex = (l < 50) ? expf(z - mx) : 0.f;
    float sm = ex;
    #pragma unroll
    for (int off = 32; off >= 1; off >>= 1) sm += __shfl_xor(sm, off, 64);
    float lse = mx + logf(sm);
    if (l < 50) out[(size_t)n*50 + l] = z - lse;
}

extern "C" void kernel_launch(void* const* d_in, const int* in_sizes, int n_in,
                              void* d_out, int out_size, void* d_ws, size_t ws_size,
                              hipStream_t stream) {
    (void)in_sizes; (void)n_in; (void)out_size;
    const float* x   = (const float*)d_in[0];
    const float* pos = (const float*)d_in[1];
    const float* prm[38];
    for (int i = 0; i < 38; i++) prm[i] = (const float*)d_in[3 + i];
    // prm: c1[0..7] c2[8..15] c3[16..23] l1[24..27] h0[28..31] h1[32..35] ho[36..37]

    float* ws = (float*)d_ws;
    size_t off = 0;
    auto alloc = [&](size_t cnt) { float* p = ws + off; off += (cnt + 63) & ~((size_t)63); return p; };
    float* f0   = alloc((size_t)NPT*6);
    float* x1   = alloc((size_t)NPT*64);
    float* x2   = alloc((size_t)NPT*64);
    float* x3   = alloc((size_t)NPT*64);
    float* u    = alloc((size_t)NPT*64);
    float* v    = alloc((size_t)NPT*64);
    float* pmax = alloc((size_t)NPT*64);
    float* pmin = alloc((size_t)NPT*64);
    int*   idx  = (int*)alloc((size_t)NPT*KNN);
    int*   ccnt = (int*)alloc(NPT);
    float* W1p  = alloc(64*64);
    float* b1p  = alloc(64);
    float* scaleA = alloc(1024);
    float* shiftA = alloc(1024);
    float* Wp   = alloc(1024*256);
    float* bp   = alloc(1024);
    float* psum = alloc((size_t)NPT*64);
    float* psq  = alloc((size_t)NPT*64);
    float* big  = alloc((size_t)BNUM*PNUM*PNUM);   // shared: Dk (u16), then head activations
    if (off*sizeof(float) > ws_size) return;       // insufficient workspace -> leave poisoned

    // cand (NPT*KCAP ints = 4 MB) aliases psum (4 MB): dead ranges don't overlap in time
    int* cand = (int*)psum;
    ushort_t* Dk = (ushort_t*)big;

    auto conv = [&](const float* F, int C, const float* const* pp, float* xout) {
        if (C == 6) k_dist<6><<<dim3(16,16,8), 256, 0, stream>>>(F, Dk);
        else        k_dist<64><<<dim3(16,16,8), 256, 0, stream>>>(F, Dk);
        k_topk<<<NPT, 256, 0, stream>>>(Dk, cand, ccnt);
        if (C == 6) k_refine<6><<<NPT/4, 256, 0, stream>>>(F, cand, ccnt, idx);
        else        k_refine<64><<<NPT/4, 256, 0, stream>>>(F, cand, ccnt, idx);
        if (C == 6) k_uv<6><<<NPT/64, 256, 0, stream>>>(F, pp[0], pp[1], u, v);
        else        k_uv<64><<<NPT/64, 256, 0, stream>>>(F, pp[0], pp[1], u, v);
        k_e1stats<<<4096, 256, 0, stream>>>(u, v, idx, psum, psq);
        k_statsfin<<<64, 256, 0, stream>>>(psum, psq, 4096, 64, 1.f/((float)NPT*KNN),
                                           pp[2], pp[3], scaleA, shiftA);
        k_fold<<<64, 256, 0, stream>>>(pp[4], pp[5], scaleA, shiftA, W1p, b1p, 64, 64);
        k_e2<<<NPT/4, 256, 0, stream>>>(u, v, idx, W1p, b1p, pmax, pmin, psum, psq);
        k_statsfin<<<64, 256, 0, stream>>>(psum, psq, NPT, 64, 1.f/((float)NPT*KNN),
                                           pp[6], pp[7], scaleA, shiftA);
        k_applypool<<<NPT*64/256, 256, 0, stream>>>(pmax, pmin, scaleA, shiftA, xout);
    };

    k_concat6<<<NPT*6/256, 256, 0, stream>>>(x, pos, f0);
    conv(f0, 6,  &prm[0],  x1);
    conv(x1, 64, &prm[8],  x2);
    conv(x2, 64, &prm[16], x3);

    float* Hb1    = big + 3145728;
    float* Hb2    = big + 19922944;
    float* Hb3    = big + 24117248;
    float* logits = big + 26214400;

    k_gemm128_l1<<<dim3(NPT/128, 8), 256, 0, stream>>>(x1, x2, x3, prm[24], prm[25], Hb1);
    k_colstats<<<dim3(NPT/64, 16), 256, 0, stream>>>(Hb1, psum, psq, 1024);
    k_statsfin<<<1024, 256, 0, stream>>>(psum, psq, NPT/64, 1024, 1.f/(float)NPT,
                                         prm[26], prm[27], scaleA, shiftA);
    k_fold<<<256, 256, 0, stream>>>(prm[28], prm[29], scaleA, shiftA, Wp, bp, 1024, 256);
    k_gemm12864<1><<<dim3(NPT/128, 4), 256, 0, stream>>>(Hb1, Wp, bp, Hb2, NPT, 1024, 256);
    k_colstats<<<dim3(NPT/64, 4), 256, 0, stream>>>(Hb2, psum, psq, 256);
    k_statsfin<<<256, 256, 0, stream>>>(psum, psq, NPT/64, 256, 1.f/(float)NPT,
                                        prm[30], prm[31], scaleA, shiftA);
    k_fold<<<128, 256, 0, stream>>>(prm[32], prm[33], scaleA, shiftA, Wp, bp, 256, 128);
    k_gemm12864<1><<<dim3(NPT/128, 2), 256, 0, stream>>>(Hb2, Wp, bp, Hb3, NPT, 256, 128);
    k_colstats<<<dim3(NPT/64, 2), 256, 0, stream>>>(Hb3, psum, psq, 128);
    k_statsfin<<<128, 256, 0, stream>>>(psum, psq, NPT/64, 128, 1.f/(float)NPT,
                                        prm[34], prm[35], scaleA, shiftA);
    k_fold<<<50, 256, 0, stream>>>(prm[36], prm[37], scaleA, shiftA, Wp, bp, 128, 50);
    k_gemm<0><<<dim3(NPT/64, 1), 256, 0, stream>>>(Hb3, Wp, bp, logits, NPT, 128, 50);
    k_logsoftmax<<<NPT/4, 256, 0, stream>>>(logits, (float*)d_out);
}

// Round 7
// 1486.627 us; speedup vs baseline: 2.6467x; 1.0924x over previous
//
#include <hip/hip_runtime.h>
#include <hip/hip_bf16.h>
#include <stdint.h>

#define BNUM 8
#define PNUM 2048
#define KNN  30
#define KSEL 40      // rank threshold for candidate selection
#define KCAP 64      // max candidates per row (one wave in refine)
#define NPT  (BNUM*PNUM)   // 16384
#define EPSF 1e-5f

typedef unsigned long long u64;
typedef unsigned short ushort_t;
typedef __attribute__((ext_vector_type(8))) short short8v;   // 8 bf16 (4 VGPRs)
typedef __attribute__((ext_vector_type(4))) float f32x4;

__device__ __forceinline__ float lane_bcast(float x, int l) {
    return __int_as_float(__builtin_amdgcn_readlane(__float_as_int(x), l));
}

__device__ __forceinline__ unsigned mono_key(float d) {
    unsigned u = __float_as_uint(d);
    return (u & 0x80000000u) ? ~u : (u | 0x80000000u);   // monotone float->uint
}

__device__ __forceinline__ unsigned f2bf(float f) {      // f32 -> bf16 bits, RNE
    unsigned u = __float_as_uint(f);
    u += 0x7fffu + ((u >> 16) & 1u);
    return u >> 16;
}

// ---------- f0 = concat(x, pos) ----------
__global__ void k_concat6(const float* __restrict__ x, const float* __restrict__ pos,
                          float* __restrict__ f0) {
    int i = blockIdx.x*256 + threadIdx.x;        // < N*6
    int n = i/6, c = i%6;
    f0[i] = (c < 3) ? x[n*3 + c] : pos[n*3 + c - 3];
}

// ---------- dist 128x128 tile (snorm fused): Dk = top16(monokey(s_p+s_q-2 f_p.f_q)) ----------
template<int C>
__global__ __launch_bounds__(256) void k_dist(const float* __restrict__ F,
                                              ushort_t* __restrict__ Dk) {
    __shared__ float FpT[C][132];
    __shared__ float FqT[C][132];
    __shared__ float sp[128], sq[128];
    int b = blockIdx.z;
    int p0 = blockIdx.x*128, q0 = blockIdx.y*128;
    int t = threadIdx.x;
    for (int e = t; e < 128*C; e += 256) {
        int r = e / C, c = e % C;
        FpT[c][r] = F[(size_t)(b*PNUM + p0 + r)*C + c];
        FqT[c][r] = F[(size_t)(b*PNUM + q0 + r)*C + c];
    }
    __syncthreads();
    if (t < 128) {
        float a = 0.f;
        for (int c = 0; c < C; c++) { float xv = FpT[c][t]; a = fmaf(xv, xv, a); }
        sp[t] = a;
    } else {
        int r = t - 128;
        float a = 0.f;
        for (int c = 0; c < C; c++) { float xv = FqT[c][r]; a = fmaf(xv, xv, a); }
        sq[r] = a;
    }
    __syncthreads();
    int tc = (t & 15)*8, tr = (t >> 4)*8;
    float acc[8][8] = {};
    #pragma unroll 4
    for (int c = 0; c < C; c++) {
        float4 p0v = *(const float4*)&FpT[c][tr];
        float4 p1v = *(const float4*)&FpT[c][tr+4];
        float4 q0v = *(const float4*)&FqT[c][tc];
        float4 q1v = *(const float4*)&FqT[c][tc+4];
        float av[8] = {p0v.x,p0v.y,p0v.z,p0v.w,p1v.x,p1v.y,p1v.z,p1v.w};
        float bv[8] = {q0v.x,q0v.y,q0v.z,q0v.w,q1v.x,q1v.y,q1v.z,q1v.w};
        #pragma unroll
        for (int i = 0; i < 8; i++)
            #pragma unroll
            for (int j = 0; j < 8; j++) acc[i][j] = fmaf(av[i], bv[j], acc[i][j]);
    }
    #pragma unroll
    for (int i = 0; i < 8; i++) {
        unsigned ks[8];
        #pragma unroll
        for (int j = 0; j < 8; j++) {
            float d = sp[tr + i] + sq[tc + j] - 2.0f*acc[i][j];
            ks[j] = mono_key(d) >> 16;
        }
        uint4 w;
        w.x = ks[0] | (ks[1] << 16);
        w.y = ks[2] | (ks[3] << 16);
        w.z = ks[4] | (ks[5] << 16);
        w.w = ks[6] | (ks[7] << 16);
        *(uint4*)&Dk[(size_t)(b*PNUM + p0 + tr + i)*PNUM + q0 + tc] = w;
    }
}

// ---------- candidate select: binary search threshold on u16 keys; no atomics ----------
__global__ __launch_bounds__(256) void k_topk(const ushort_t* __restrict__ Dk,
                                              int* __restrict__ cand, int* __restrict__ ccnt) {
    __shared__ int red[4];
    __shared__ int wbase[4];
    int n = blockIdx.x, t = threadIdx.x, lane = t & 63, w = t >> 6;
    uint4 wv = *(const uint4*)(Dk + (size_t)n*PNUM + t*8);
    int ks[8];
    ks[0] = wv.x & 0xffff; ks[1] = wv.x >> 16;
    ks[2] = wv.y & 0xffff; ks[3] = wv.y >> 16;
    ks[4] = wv.z & 0xffff; ks[5] = wv.z >> 16;
    ks[6] = wv.w & 0xffff; ks[7] = wv.w >> 16;
    int lo = 0, hi = 65535;
    while (lo < hi) {                      // 16 iterations, block-uniform
        int mid = (lo + hi) >> 1;
        int c = 0;
        #pragma unroll
        for (int e = 0; e < 8; e++) c += (ks[e] <= mid);
        #pragma unroll
        for (int o = 32; o >= 1; o >>= 1) c += __shfl_xor(c, o, 64);
        if (lane == 0) red[w] = c;
        __syncthreads();
        int tot = red[0] + red[1] + red[2] + red[3];
        __syncthreads();
        if (tot >= KSEL) hi = mid; else lo = mid + 1;
    }
    int P = lo;
    int lc = 0;
    #pragma unroll
    for (int e = 0; e < 8; e++) lc += (ks[e] <= P);
    int pre = lc;                          // inclusive prefix within wave
    #pragma unroll
    for (int o = 1; o < 64; o <<= 1) { int vv = __shfl_up(pre, o, 64); if (lane >= o) pre += vv; }
    int excl = pre - lc;
    if (lane == 63) red[w] = pre;          // wave totals
    __syncthreads();
    if (t == 0) {
        int s0 = 0;
        #pragma unroll
        for (int i = 0; i < 4; i++) { wbase[i] = s0; s0 += red[i]; }
        ccnt[n] = (s0 < KCAP) ? s0 : KCAP;
    }
    __syncthreads();
    int base = wbase[w] + excl;
    #pragma unroll
    for (int e = 0; e < 8; e++) {
        if (ks[e] <= P) {
            if (base < KCAP) cand[(size_t)n*KCAP + base] = t*8 + e;
            base++;
        }
    }
}

// ---------- refine: f64 direct squared distance over candidates, exact top-30 ----------
template<int C>
__global__ __launch_bounds__(256) void k_refine(const float* __restrict__ F,
                                                const int* __restrict__ cand,
                                                const int* __restrict__ ccnt,
                                                int* __restrict__ idx) {
    int t = threadIdx.x;
    int lane = t & 63;
    int row = blockIdx.x*4 + (t >> 6);
    int b = row >> 11;
    const float* fp = F + (size_t)row*C;
    int cnt = ccnt[row];
    bool act = lane < cnt;
    int q = act ? cand[(size_t)row*KCAP + lane] : 0;
    const float* fq = F + (size_t)(b*PNUM + q)*C;
    double d = 1e300;
    if (act) {
        d = 0.0;
        if (C == 64) {
            #pragma unroll
            for (int c4 = 0; c4 < C/4; c4++) {
                float4 a = ((const float4*)fp)[c4];
                float4 bb = ((const float4*)fq)[c4];
                double d0 = (double)a.x - (double)bb.x;
                double d1 = (double)a.y - (double)bb.y;
                double d2 = (double)a.z - (double)bb.z;
                double d3 = (double)a.w - (double)bb.w;
                d += d0*d0 + d1*d1 + d2*d2 + d3*d3;
            }
        } else {
            #pragma unroll
            for (int c = 0; c < C; c++) {
                double df = (double)fp[c] - (double)fq[c];
                d += df*df;
            }
        }
    }
    for (int it = 0; it < KNN; it++) {
        double m = d;
        #pragma unroll
        for (int off = 32; off >= 1; off >>= 1) {
            double o = __shfl_xor(m, off, 64);
            m = (o < m) ? o : m;
        }
        int cid = (d == m) ? q : 0x7fffffff;
        int cm = cid;
        #pragma unroll
        for (int off = 32; off >= 1; off >>= 1) {
            int o = __shfl_xor(cm, off, 64);
            cm = (o < cm) ? o : cm;
        }
        if (d == m && q == cm) {
            idx[(size_t)row*KNN + it] = q;
            d = 1e300;
        }
    }
}

// ---------- fused u/v GEMM: u = F@(W0a-W0b)+b0, v = F@W0b ----------
template<int C>
__global__ __launch_bounds__(256) void k_uv(const float* __restrict__ F,
                                            const float* __restrict__ W0,
                                            const float* __restrict__ b0,
                                            float* __restrict__ u, float* __restrict__ v) {
    __shared__ float As[64][17];
    __shared__ float Wa[16][64];
    __shared__ float Wb[16][64];
    int m0 = blockIdx.x*64;
    int t = threadIdx.x;
    int cb = (t & 15)*4, rb = (t >> 4)*4;
    float aU[4][4] = {}, aV[4][4] = {};
    for (int k0 = 0; k0 < C; k0 += 16) {
        #pragma unroll
        for (int j = 0; j < 4; j++) {
            int e = t + 256*j;
            int r = e >> 4, c = e & 15;
            As[r][c] = (k0 + c < C) ? F[(size_t)(m0 + r)*C + k0 + c] : 0.f;
        }
        {
            int r = t >> 4, c4 = (t & 15)*4;
            bool ok = (k0 + r < C);
            float4 wa = ok ? *(const float4*)&W0[(size_t)(k0 + r)*64 + c4] : make_float4(0,0,0,0);
            float4 wb = ok ? *(const float4*)&W0[(size_t)(C + k0 + r)*64 + c4] : make_float4(0,0,0,0);
            *(float4*)&Wa[r][c4] = wa;
            *(float4*)&Wb[r][c4] = wb;
        }
        __syncthreads();
        #pragma unroll
        for (int kk = 0; kk < 16; kk++) {
            float a[4];
            #pragma unroll
            for (int i = 0; i < 4; i++) a[i] = As[rb + i][kk];
            float4 wa4 = *(const float4*)&Wa[kk][cb];
            float4 wb4 = *(const float4*)&Wb[kk][cb];
            float wa[4] = {wa4.x, wa4.y, wa4.z, wa4.w};
            float wb[4] = {wb4.x, wb4.y, wb4.z, wb4.w};
            #pragma unroll
            for (int i = 0; i < 4; i++)
                #pragma unroll
                for (int j = 0; j < 4; j++) {
                    aU[i][j] = fmaf(a[i], wa[j] - wb[j], aU[i][j]);
                    aV[i][j] = fmaf(a[i], wb[j], aV[i][j]);
                }
        }
        __syncthreads();
    }
    #pragma unroll
    for (int i = 0; i < 4; i++) {
        int row = m0 + rb + i;
        #pragma unroll
        for (int j = 0; j < 4; j++) {
            int col = cb + j;
            u[(size_t)row*64 + col] = aU[i][j] + b0[col];
            v[(size_t)row*64 + col] = aV[i][j];
        }
    }
}

// ---------- 64-wide tiled f32 GEMM (final ho layer) ----------
template<int RELU>
__global__ __launch_bounds__(256) void k_gemm(const float* __restrict__ A,
                                              const float* __restrict__ W,
                                              const float* __restrict__ bias,
                                              float* __restrict__ out,
                                              int M, int Kd, int Nd) {
    __shared__ float As[64][17];
    __shared__ float Bs[16][64];
    int m0 = blockIdx.x*64, n0 = blockIdx.y*64;
    int t = threadIdx.x;
    int cb = (t & 15)*4, rb = (t >> 4)*4;
    float acc[4][4] = {};
    for (int k0 = 0; k0 < Kd; k0 += 16) {
        #pragma unroll
        for (int j = 0; j < 4; j++) {
            int e = t + 256*j;
            int r = e >> 4, c = e & 15;
            As[r][c] = (k0 + c < Kd) ? A[(size_t)(m0 + r)*Kd + k0 + c] : 0.f;
        }
        #pragma unroll
        for (int j = 0; j < 4; j++) {
            int e = t + 256*j;
            int r = e >> 6, c = e & 63;
            Bs[r][c] = (k0 + r < Kd && n0 + c < Nd) ? W[(size_t)(k0 + r)*Nd + n0 + c] : 0.f;
        }
        __syncthreads();
        #pragma unroll
        for (int kk = 0; kk < 16; kk++) {
            float a[4];
            #pragma unroll
            for (int i = 0; i < 4; i++) a[i] = As[rb + i][kk];
            float4 w4 = *(const float4*)&Bs[kk][cb];
            float w[4] = {w4.x, w4.y, w4.z, w4.w};
            #pragma unroll
            for (int i = 0; i < 4; i++)
                #pragma unroll
                for (int j = 0; j < 4; j++) acc[i][j] += a[i]*w[j];
        }
        __syncthreads();
    }
    #pragma unroll
    for (int i = 0; i < 4; i++) {
        int row = m0 + rb + i;
        #pragma unroll
        for (int j = 0; j < 4; j++) {
            int col = n0 + cb + j;
            if (col < Nd) {
                float v = acc[i][j] + (bias ? bias[col] : 0.f);
                if (RELU) v = fmaxf(v, 0.f);
                out[(size_t)row*Nd + col] = v;
            }
        }
    }
}

// ---------- pack f32 weights [Kd][Nd] -> bf16 fragment layout [(Kd/8)][Nd][8] ----------
__global__ void k_pack(const float* __restrict__ W, ushort_t* __restrict__ Wpk,
                       int Kd, int Nd) {
    int cell = blockIdx.x*256 + threadIdx.x;
    int ncell = (Kd >> 3)*Nd;
    if (cell >= ncell) return;
    int kg = cell / Nd, n = cell - kg*Nd;
    unsigned b[8];
    #pragma unroll
    for (int j = 0; j < 8; j++) b[j] = f2bf(W[(size_t)(kg*8 + j)*Nd + n]);
    uint4 wv;
    wv.x = b[0] | (b[1] << 16); wv.y = b[2] | (b[3] << 16);
    wv.z = b[4] | (b[5] << 16); wv.w = b[6] | (b[7] << 16);
    *(uint4*)&Wpk[(size_t)cell*8] = wv;
}

// ---------- bf16 MFMA GEMM: 128x128 tile, 4 waves (2x2 of 64x64), f32 out ----------
// A: f32 activations (CONCAT: three 64-wide sources), converted to bf16 during staging.
// Wpk: pre-packed bf16 weights in fragment layout [(Kd/8)][Nd][8].
template<int CONCAT, int RELU>
__global__ __launch_bounds__(256) void k_mgemm(const float* __restrict__ A,
                                               const float* __restrict__ A2,
                                               const float* __restrict__ A3,
                                               const ushort_t* __restrict__ Wpk,
                                               const float* __restrict__ bias,
                                               float* __restrict__ out,
                                               int Kd, int Nd) {
    __shared__ ushort_t Al[4][128][8];   // [kgroup][row][8 bf16] = 8 KB
    __shared__ ushort_t Bl[4][128][8];   // [kgroup][col][8 bf16] = 8 KB
    int m0 = blockIdx.x*128, n0 = blockIdx.y*128;
    int t = threadIdx.x, lane = t & 63, w = t >> 6;
    int wm = (w >> 1)*64, wn = (w & 1)*64;
    f32x4 acc[4][4] = {};
    int arow = t >> 2, akg = t & 3;
    for (int k0 = 0; k0 < Kd; k0 += 32) {
        #pragma unroll
        for (int i = 0; i < 2; i++) {          // A: 512 cells, 2 per thread
            int row = arow + 64*i;
            int kb = k0 + akg*8;
            const float* src;
            if (CONCAT) {
                const float* s0 = (kb < 64) ? A : (kb < 128) ? A2 : A3;
                src = s0 + (size_t)(m0 + row)*64 + (kb & 63);
            } else {
                src = A + (size_t)(m0 + row)*Kd + kb;
            }
            float4 fa = *(const float4*)src;
            float4 fb = *(const float4*)(src + 4);
            uint4 wv;
            wv.x = f2bf(fa.x) | (f2bf(fa.y) << 16);
            wv.y = f2bf(fa.z) | (f2bf(fa.w) << 16);
            wv.z = f2bf(fb.x) | (f2bf(fb.y) << 16);
            wv.w = f2bf(fb.z) | (f2bf(fb.w) << 16);
            *(uint4*)&Al[akg][row][0] = wv;
        }
        #pragma unroll
        for (int i = 0; i < 2; i++) {          // B: 512 cells, contiguous copy
            int cell = t + 256*i;
            int kg = cell >> 7, col = cell & 127;
            *(uint4*)&Bl[kg][col][0] =
                *(const uint4*)&Wpk[((size_t)(k0/8 + kg)*Nd + n0 + col)*8];
        }
        __syncthreads();
        short8v af[4], bf[4];
        #pragma unroll
        for (int mf = 0; mf < 4; mf++)
            af[mf] = *(const short8v*)&Al[lane >> 4][wm + mf*16 + (lane & 15)][0];
        #pragma unroll
        for (int nf = 0; nf < 4; nf++)
            bf[nf] = *(const short8v*)&Bl[lane >> 4][wn + nf*16 + (lane & 15)][0];
        #pragma unroll
        for (int mf = 0; mf < 4; mf++)
            #pragma unroll
            for (int nf = 0; nf < 4; nf++)
                acc[mf][nf] = __builtin_amdgcn_mfma_f32_16x16x32_bf16(af[mf], bf[nf], acc[mf][nf], 0, 0, 0);
        __syncthreads();
    }
    int crow = (lane >> 4)*4;
    int ccol = lane & 15;
    #pragma unroll
    for (int nf = 0; nf < 4; nf++) {
        int col = n0 + wn + nf*16 + ccol;
        float bv = bias[col];
        #pragma unroll
        for (int mf = 0; mf < 4; mf++) {
            #pragma unroll
            for (int r = 0; r < 4; r++) {
                int row = m0 + wm + mf*16 + crow + r;
                float vv = acc[mf][nf][r] + bv;
                if (RELU) vv = fmaxf(vv, 0.f);
                out[(size_t)row*Nd + col] = vv;
            }
        }
    }
}

// ---------- stats of relu(u_p + v_q) over all edges ----------
__global__ __launch_bounds__(256) void k_e1stats(const float* __restrict__ u,
                                                 const float* __restrict__ v,
                                                 const int* __restrict__ idx,
                                                 float* __restrict__ psum, float* __restrict__ psq) {
    int t = threadIdx.x;
    float s = 0.f, sq = 0.f;
    const int stride = 4096*256;
    int i = blockIdx.x*256 + t;
    #pragma unroll 1
    for (int j = 0; j < 30; j++, i += stride) {
        int edge = i >> 6, c = i & 63;
        int p = edge / KNN;
        int q = idx[edge];
        int b = p >> 11;
        float h = u[(size_t)p*64 + c] + v[(size_t)(b*PNUM + q)*64 + c];
        h = fmaxf(h, 0.f);
        s += h; sq += h*h;
    }
    __shared__ float rs[256], rq[256];
    rs[t] = s; rq[t] = sq;
    __syncthreads();
    if (t < 128) { rs[t] += rs[t+128]; rq[t] += rq[t+128]; }
    __syncthreads();
    if (t < 64) {
        rs[t] += rs[t+64]; rq[t] += rq[t+64];
        psum[(size_t)blockIdx.x*64 + t] = rs[t];
        psq [(size_t)blockIdx.x*64 + t] = rq[t];
    }
}

// ---------- finalize BN stats ----------
__global__ void k_statsfin(const float* __restrict__ psum, const float* __restrict__ psq,
                           int npart, int C, float invM,
                           const float* __restrict__ g, const float* __restrict__ be,
                           float* __restrict__ scale, float* __restrict__ shift) {
    int c = blockIdx.x, t = threadIdx.x;
    float s = 0.f, q = 0.f;
    for (int i = t; i < npart; i += 256) {
        s += psum[(size_t)i*C + c];
        q += psq [(size_t)i*C + c];
    }
    __shared__ float rs[256], rq[256];
    rs[t] = s; rq[t] = q; __syncthreads();
    for (int off = 128; off >= 1; off >>= 1) {
        if (t < off) { rs[t] += rs[t+off]; rq[t] += rq[t+off]; }
        __syncthreads();
    }
    if (t == 0) {
        float m   = rs[0]*invM;
        float var = rq[0]*invM - m*m;
        float inv = rsqrtf(var + EPSF);
        float sc  = g[c]*inv;
        scale[c] = sc;
        shift[c] = be[c] - m*sc;
    }
}

// ---------- fold BN affine into next linear ----------
__global__ void k_fold(const float* __restrict__ W, const float* __restrict__ b,
                       const float* __restrict__ scale, const float* __restrict__ shift,
                       float* __restrict__ Wp, float* __restrict__ bp, int Cin, int Cout) {
    int co = blockIdx.x, t = threadIdx.x;
    float acc = 0.f;
    for (int ci = t; ci < Cin; ci += 256) {
        float w = W[(size_t)ci*Cout + co];
        Wp[(size_t)ci*Cout + co] = scale[ci]*w;
        acc += shift[ci]*w;
    }
    __shared__ float r[256];
    r[t] = acc; __syncthreads();
    for (int off = 128; off >= 1; off >>= 1) { if (t < off) r[t] += r[t+off]; __syncthreads(); }
    if (t == 0) bp[co] = b[co] + r[0];
}

// ---------- edge layer 1: wave-per-point register GEMM + pool + stats ----------
__global__ __launch_bounds__(256, 4) void k_e2(const float* __restrict__ u, const float* __restrict__ v,
                                               const int* __restrict__ idx,
                                               const float* __restrict__ W1p, const float* __restrict__ b1p,
                                               float* __restrict__ pmax, float* __restrict__ pmin,
                                               float* __restrict__ psum, float* __restrict__ psq) {
    __shared__ float W1s[64][64];   // 16 KB: W1s[c][co]
    int t = threadIdx.x, lane = t & 63, w = t >> 6;
    int p = blockIdx.x*4 + w;
    int b = p >> 11;
    for (int e = t; e < 4096; e += 256) W1s[e >> 6][e & 63] = W1p[e];
    __syncthreads();
    float wcol[64];
    #pragma unroll
    for (int c = 0; c < 64; c++) wcol[c] = W1s[c][lane];   // conflict-free column read
    float ureg = u[(size_t)p*64 + lane];
    float bias = b1p[lane];
    const int* myidx = idx + (size_t)p*KNN;
    const float* vb = v + (size_t)b*PNUM*64;
    float mx = -1e30f, mn = 1e30f, sm = 0.f, sq = 0.f;
    int q = myidx[0];
    float vk = vb[(size_t)q*64 + lane];
    #pragma unroll 1
    for (int k = 0; k < KNN; k++) {
        float h = fmaxf(ureg + vk, 0.f);
        if (k + 1 < KNN) {               // prefetch next neighbor row
            int qn = myidx[k + 1];
            vk = vb[(size_t)qn*64 + lane];
        }
        float a0 = 0.f, a1 = 0.f, a2 = 0.f, a3 = 0.f;
        #pragma unroll
        for (int c = 0; c < 64; c += 4) {
            a0 = fmaf(lane_bcast(h, c    ), wcol[c    ], a0);
            a1 = fmaf(lane_bcast(h, c + 1), wcol[c + 1], a1);
            a2 = fmaf(lane_bcast(h, c + 2), wcol[c + 2], a2);
            a3 = fmaf(lane_bcast(h, c + 3), wcol[c + 3], a3);
        }
        float o = fmaxf((a0 + a1) + (a2 + a3) + bias, 0.f);
        mx = fmaxf(mx, o);
        mn = fminf(mn, o);
        sm += o;
        sq += o*o;
    }
    pmax[(size_t)p*64 + lane] = mx;
    pmin[(size_t)p*64 + lane] = mn;
    psum[(size_t)p*64 + lane] = sm;
    psq [(size_t)p*64 + lane] = sq;
}

// ---------- BN1 applied after pooling (max if scale>=0 else min) ----------
__global__ void k_applypool(const float* __restrict__ pmax, const float* __restrict__ pmin,
                            const float* __restrict__ scale, const float* __restrict__ shift,
                            float* __restrict__ out) {
    int i = blockIdx.x*256 + threadIdx.x;
    int c = i & 63;
    float sc = scale[c];
    float pooled = (sc >= 0.f) ? pmax[i] : pmin[i];
    out[i] = sc*pooled + shift[c];
}

// ---------- per-column partial sums over 64-row blocks ----------
__global__ void k_colstats(const float* __restrict__ Hbuf, float* __restrict__ psum,
                           float* __restrict__ psq, int Cout) {
    int m0 = blockIdx.x*64, c0 = blockIdx.y*64;
    int t = threadIdx.x;
    int c = t & 63, rg = t >> 6;
    float s = 0.f, q = 0.f;
    #pragma unroll 4
    for (int r = 0; r < 16; r++) {
        float hv = Hbuf[(size_t)(m0 + rg*16 + r)*Cout + c0 + c];
        s += hv; q += hv*hv;
    }
    __shared__ float rs[256], rq[256];
    rs[t] = s; rq[t] = q; __syncthreads();
    if (t < 128) { rs[t] += rs[t+128]; rq[t] += rq[t+128]; }
    __syncthreads();
    if (t < 64) {
        rs[t] += rs[t+64]; rq[t] += rq[t+64];
        psum[(size_t)blockIdx.x*Cout + c0 + t] = rs[t];
        psq [(size_t)blockIdx.x*Cout + c0 + t] = rq[t];
    }
}

// ---------- log_softmax over 50 cols, one wave per row ----------
__global__ void k_logsoftmax(const float* __restrict__ logits, float* __restrict__ out) {
    int t = threadIdx.x;
    int n = blockIdx.x*4 + (t >> 6);
    int l = t & 63;
    float z = (l < 50) ? logits[(size_t)n*50 + l] : -INFINITY;
    float mx = z;
    #pragma unroll
    for (int off = 32; off >= 1; off >>= 1) mx = fmaxf(mx, __shfl_xor(mx, off, 64));
    float ex = (l < 50) ? expf(z - mx) : 0.f;
    float sm = ex;
    #pragma unroll
    for (int off = 32; off >= 1; off >>= 1) sm += __shfl_xor(sm, off, 64);
    float lse = mx + logf(sm);
    if (l < 50) out[(size_t)n*50 + l] = z - lse;
}

extern "C" void kernel_launch(void* const* d_in, const int* in_sizes, int n_in,
                              void* d_out, int out_size, void* d_ws, size_t ws_size,
                              hipStream_t stream) {
    (void)in_sizes; (void)n_in; (void)out_size;
    const float* x   = (const float*)d_in[0];
    const float* pos = (const float*)d_in[1];
    const float* prm[38];
    for (int i = 0; i < 38; i++) prm[i] = (const float*)d_in[3 + i];
    // prm: c1[0..7] c2[8..15] c3[16..23] l1[24..27] h0[28..31] h1[32..35] ho[36..37]

    float* ws = (float*)d_ws;
    size_t off = 0;
    auto alloc = [&](size_t cnt) { float* p = ws + off; off += (cnt + 63) & ~((size_t)63); return p; };
    float* f0   = alloc((size_t)NPT*6);
    float* x1   = alloc((size_t)NPT*64);
    float* x2   = alloc((size_t)NPT*64);
    float* x3   = alloc((size_t)NPT*64);
    float* u    = alloc((size_t)NPT*64);
    float* v    = alloc((size_t)NPT*64);
    float* pmax = alloc((size_t)NPT*64);
    float* pmin = alloc((size_t)NPT*64);
    int*   idx  = (int*)alloc((size_t)NPT*KNN);
    int*   ccnt = (int*)alloc(NPT);
    float* W1p  = alloc(64*64);
    float* b1p  = alloc(64);
    float* scaleA = alloc(1024);
    float* shiftA = alloc(1024);
    float* Wp   = alloc(1024*256);
    float* bp   = alloc(1024);
    ushort_t* Wpk1 = (ushort_t*)alloc(98304);    // l1 packed weights (192*1024 bf16)
    ushort_t* Wpk2 = (ushort_t*)alloc(131072);   // h0/h1 packed weights (max 1024*256 bf16)
    float* psum = alloc((size_t)NPT*64);
    float* psq  = alloc((size_t)NPT*64);
    float* big  = alloc((size_t)BNUM*PNUM*PNUM);   // shared: Dk (u16), then head activations
    if (off*sizeof(float) > ws_size) return;       // insufficient workspace -> leave poisoned

    // cand (NPT*KCAP ints = 4 MB) aliases psum (4 MB): dead ranges don't overlap in time
    int* cand = (int*)psum;
    ushort_t* Dk = (ushort_t*)big;

    auto conv = [&](const float* F, int C, const float* const* pp, float* xout) {
        if (C == 6) k_dist<6><<<dim3(16,16,8), 256, 0, stream>>>(F, Dk);
        else        k_dist<64><<<dim3(16,16,8), 256, 0, stream>>>(F, Dk);
        k_topk<<<NPT, 256, 0, stream>>>(Dk, cand, ccnt);
        if (C == 6) k_refine<6><<<NPT/4, 256, 0, stream>>>(F, cand, ccnt, idx);
        else        k_refine<64><<<NPT/4, 256, 0, stream>>>(F, cand, ccnt, idx);
        if (C == 6) k_uv<6><<<NPT/64, 256, 0, stream>>>(F, pp[0], pp[1], u, v);
        else        k_uv<64><<<NPT/64, 256, 0, stream>>>(F, pp[0], pp[1], u, v);
        k_e1stats<<<4096, 256, 0, stream>>>(u, v, idx, psum, psq);
        k_statsfin<<<64, 256, 0, stream>>>(psum, psq, 4096, 64, 1.f/((float)NPT*KNN),
                                           pp[2], pp[3], scaleA, shiftA);
        k_fold<<<64, 256, 0, stream>>>(pp[4], pp[5], scaleA, shiftA, W1p, b1p, 64, 64);
        k_e2<<<NPT/4, 256, 0, stream>>>(u, v, idx, W1p, b1p, pmax, pmin, psum, psq);
        k_statsfin<<<64, 256, 0, stream>>>(psum, psq, NPT, 64, 1.f/((float)NPT*KNN),
                                           pp[6], pp[7], scaleA, shiftA);
        k_applypool<<<NPT*64/256, 256, 0, stream>>>(pmax, pmin, scaleA, shiftA, xout);
    };

    k_concat6<<<NPT*6/256, 256, 0, stream>>>(x, pos, f0);
    k_pack<<<96, 256, 0, stream>>>(prm[24], Wpk1, 192, 1024);   // l1 weights (no fold needed)
    conv(f0, 6,  &prm[0],  x1);
    conv(x1, 64, &prm[8],  x2);
    conv(x2, 64, &prm[16], x3);

    float* Hb1    = big + 3145728;
    float* Hb2    = big + 19922944;
    float* Hb3    = big + 24117248;
    float* logits = big + 26214400;

    // l1: [x1|x2|x3] (16384x192) @ W (192x1024) + bias, ReLU — bf16 MFMA
    k_mgemm<1,1><<<dim3(NPT/128, 8), 256, 0, stream>>>(x1, x2, x3, Wpk1, prm[25], Hb1, 192, 1024);
    k_colstats<<<dim3(NPT/64, 16), 256, 0, stream>>>(Hb1, psum, psq, 1024);
    k_statsfin<<<1024, 256, 0, stream>>>(psum, psq, NPT/64, 1024, 1.f/(float)NPT,
                                         prm[26], prm[27], scaleA, shiftA);
    k_fold<<<256, 256, 0, stream>>>(prm[28], prm[29], scaleA, shiftA, Wp, bp, 1024, 256);
    k_pack<<<128, 256, 0, stream>>>(Wp, Wpk2, 1024, 256);
    k_mgemm<0,1><<<dim3(NPT/128, 2), 256, 0, stream>>>(Hb1, nullptr, nullptr, Wpk2, bp, Hb2, 1024, 256);
    k_colstats<<<dim3(NPT/64, 4), 256, 0, stream>>>(Hb2, psum, psq, 256);
    k_statsfin<<<256, 256, 0, stream>>>(psum, psq, NPT/64, 256, 1.f/(float)NPT,
                                        prm[30], prm[31], scaleA, shiftA);
    k_fold<<<128, 256, 0, stream>>>(prm[32], prm[33], scaleA, shiftA, Wp, bp, 256, 128);
    k_pack<<<16, 256, 0, stream>>>(Wp, Wpk2, 256, 128);
    k_mgemm<0,1><<<dim3(NPT/128, 1), 256, 0, stream>>>(Hb2, nullptr, nullptr, Wpk2, bp, Hb3, 256, 128);
    k_colstats<<<dim3(NPT/64, 2), 256, 0, stream>>>(Hb3, psum, psq, 128);
    k_statsfin<<<128, 256, 0, stream>>>(psum, psq, NPT/64, 128, 1.f/(float)NPT,
                                        prm[34], prm[35], scaleA, shiftA);
    k_fold<<<50, 256, 0, stream>>>(prm[36], prm[37], scaleA, shiftA, Wp, bp, 128, 50);
    k_gemm<0><<<dim3(NPT/64, 1), 256, 0, stream>>>(Hb3, Wp, bp, logits, NPT, 128, 50);
    k_logsoftmax<<<NPT/4, 256, 0, stream>>>(logits, (float*)d_out);
}

// Round 8
// 1352.231 us; speedup vs baseline: 2.9097x; 1.0994x over previous
//
#include <hip/hip_runtime.h>
#include <hip/hip_bf16.h>
#include <stdint.h>

#define BNUM 8
#define PNUM 2048
#define KNN  30
#define KSEL 40      // rank threshold for candidate selection
#define KCAP 64      // max candidates per row (one wave in refine)
#define NPT  (BNUM*PNUM)   // 16384
#define EPSF 1e-5f

typedef unsigned long long u64;
typedef unsigned short ushort_t;
typedef __attribute__((ext_vector_type(8))) short short8v;   // 8 bf16 (4 VGPRs)
typedef __attribute__((ext_vector_type(4))) float f32x4;

__device__ __forceinline__ unsigned mono_key(float d) {
    unsigned u = __float_as_uint(d);
    return (u & 0x80000000u) ? ~u : (u | 0x80000000u);   // monotone float->uint
}

__device__ __forceinline__ unsigned f2bf(float f) {      // f32 -> bf16 bits, RNE
    unsigned u = __float_as_uint(f);
    u += 0x7fffu + ((u >> 16) & 1u);
    return u >> 16;
}

// ---------- f0 = concat(x, pos) ----------
__global__ void k_concat6(const float* __restrict__ x, const float* __restrict__ pos,
                          float* __restrict__ f0) {
    int i = blockIdx.x*256 + threadIdx.x;        // < N*6
    int n = i/6, c = i%6;
    f0[i] = (c < 3) ? x[n*3 + c] : pos[n*3 + c - 3];
}

// ---------- dist 128x128 tile (snorm fused): Dk = top16(monokey(s_p+s_q-2 f_p.f_q)) ----------
template<int C>
__global__ __launch_bounds__(256) void k_dist(const float* __restrict__ F,
                                              ushort_t* __restrict__ Dk) {
    __shared__ float FpT[C][132];
    __shared__ float FqT[C][132];
    __shared__ float sp[128], sq[128];
    int b = blockIdx.z;
    int p0 = blockIdx.x*128, q0 = blockIdx.y*128;
    int t = threadIdx.x;
    for (int e = t; e < 128*C; e += 256) {
        int r = e / C, c = e % C;
        FpT[c][r] = F[(size_t)(b*PNUM + p0 + r)*C + c];
        FqT[c][r] = F[(size_t)(b*PNUM + q0 + r)*C + c];
    }
    __syncthreads();
    if (t < 128) {
        float a = 0.f;
        for (int c = 0; c < C; c++) { float xv = FpT[c][t]; a = fmaf(xv, xv, a); }
        sp[t] = a;
    } else {
        int r = t - 128;
        float a = 0.f;
        for (int c = 0; c < C; c++) { float xv = FqT[c][r]; a = fmaf(xv, xv, a); }
        sq[r] = a;
    }
    __syncthreads();
    int tc = (t & 15)*8, tr = (t >> 4)*8;
    float acc[8][8] = {};
    #pragma unroll 4
    for (int c = 0; c < C; c++) {
        float4 p0v = *(const float4*)&FpT[c][tr];
        float4 p1v = *(const float4*)&FpT[c][tr+4];
        float4 q0v = *(const float4*)&FqT[c][tc];
        float4 q1v = *(const float4*)&FqT[c][tc+4];
        float av[8] = {p0v.x,p0v.y,p0v.z,p0v.w,p1v.x,p1v.y,p1v.z,p1v.w};
        float bv[8] = {q0v.x,q0v.y,q0v.z,q0v.w,q1v.x,q1v.y,q1v.z,q1v.w};
        #pragma unroll
        for (int i = 0; i < 8; i++)
            #pragma unroll
            for (int j = 0; j < 8; j++) acc[i][j] = fmaf(av[i], bv[j], acc[i][j]);
    }
    #pragma unroll
    for (int i = 0; i < 8; i++) {
        unsigned ks[8];
        #pragma unroll
        for (int j = 0; j < 8; j++) {
            float d = sp[tr + i] + sq[tc + j] - 2.0f*acc[i][j];
            ks[j] = mono_key(d) >> 16;
        }
        uint4 w;
        w.x = ks[0] | (ks[1] << 16);
        w.y = ks[2] | (ks[3] << 16);
        w.z = ks[4] | (ks[5] << 16);
        w.w = ks[6] | (ks[7] << 16);
        *(uint4*)&Dk[(size_t)(b*PNUM + p0 + tr + i)*PNUM + q0 + tc] = w;
    }
}

// ---------- candidate select: binary search threshold on u16 keys; no atomics ----------
__global__ __launch_bounds__(256) void k_topk(const ushort_t* __restrict__ Dk,
                                              int* __restrict__ cand, int* __restrict__ ccnt) {
    __shared__ int red[4];
    __shared__ int wbase[4];
    int n = blockIdx.x, t = threadIdx.x, lane = t & 63, w = t >> 6;
    uint4 wv = *(const uint4*)(Dk + (size_t)n*PNUM + t*8);
    int ks[8];
    ks[0] = wv.x & 0xffff; ks[1] = wv.x >> 16;
    ks[2] = wv.y & 0xffff; ks[3] = wv.y >> 16;
    ks[4] = wv.z & 0xffff; ks[5] = wv.z >> 16;
    ks[6] = wv.w & 0xffff; ks[7] = wv.w >> 16;
    int lo = 0, hi = 65535;
    while (lo < hi) {                      // 16 iterations, block-uniform
        int mid = (lo + hi) >> 1;
        int c = 0;
        #pragma unroll
        for (int e = 0; e < 8; e++) c += (ks[e] <= mid);
        #pragma unroll
        for (int o = 32; o >= 1; o >>= 1) c += __shfl_xor(c, o, 64);
        if (lane == 0) red[w] = c;
        __syncthreads();
        int tot = red[0] + red[1] + red[2] + red[3];
        __syncthreads();
        if (tot >= KSEL) hi = mid; else lo = mid + 1;
    }
    int P = lo;
    int lc = 0;
    #pragma unroll
    for (int e = 0; e < 8; e++) lc += (ks[e] <= P);
    int pre = lc;                          // inclusive prefix within wave
    #pragma unroll
    for (int o = 1; o < 64; o <<= 1) { int vv = __shfl_up(pre, o, 64); if (lane >= o) pre += vv; }
    int excl = pre - lc;
    if (lane == 63) red[w] = pre;          // wave totals
    __syncthreads();
    if (t == 0) {
        int s0 = 0;
        #pragma unroll
        for (int i = 0; i < 4; i++) { wbase[i] = s0; s0 += red[i]; }
        ccnt[n] = (s0 < KCAP) ? s0 : KCAP;
    }
    __syncthreads();
    int base = wbase[w] + excl;
    #pragma unroll
    for (int e = 0; e < 8; e++) {
        if (ks[e] <= P) {
            if (base < KCAP) cand[(size_t)n*KCAP + base] = t*8 + e;
            base++;
        }
    }
}

// ---------- refine: f64 direct squared distance over candidates, exact top-30 ----------
template<int C>
__global__ __launch_bounds__(256) void k_refine(const float* __restrict__ F,
                                                const int* __restrict__ cand,
                                                const int* __restrict__ ccnt,
                                                int* __restrict__ idx) {
    int t = threadIdx.x;
    int lane = t & 63;
    int row = blockIdx.x*4 + (t >> 6);
    int b = row >> 11;
    const float* fp = F + (size_t)row*C;
    int cnt = ccnt[row];
    bool act = lane < cnt;
    int q = act ? cand[(size_t)row*KCAP + lane] : 0;
    const float* fq = F + (size_t)(b*PNUM + q)*C;
    double d = 1e300;
    if (act) {
        d = 0.0;
        if (C == 64) {
            #pragma unroll
            for (int c4 = 0; c4 < C/4; c4++) {
                float4 a = ((const float4*)fp)[c4];
                float4 bb = ((const float4*)fq)[c4];
                double d0 = (double)a.x - (double)bb.x;
                double d1 = (double)a.y - (double)bb.y;
                double d2 = (double)a.z - (double)bb.z;
                double d3 = (double)a.w - (double)bb.w;
                d += d0*d0 + d1*d1 + d2*d2 + d3*d3;
            }
        } else {
            #pragma unroll
            for (int c = 0; c < C; c++) {
                double df = (double)fp[c] - (double)fq[c];
                d += df*df;
            }
        }
    }
    for (int it = 0; it < KNN; it++) {
        double m = d;
        #pragma unroll
        for (int off = 32; off >= 1; off >>= 1) {
            double o = __shfl_xor(m, off, 64);
            m = (o < m) ? o : m;
        }
        int cid = (d == m) ? q : 0x7fffffff;
        int cm = cid;
        #pragma unroll
        for (int off = 32; off >= 1; off >>= 1) {
            int o = __shfl_xor(cm, off, 64);
            cm = (o < cm) ? o : cm;
        }
        if (d == m && q == cm) {
            idx[(size_t)row*KNN + it] = q;
            d = 1e300;
        }
    }
}

// ---------- fused u/v GEMM: u = F@(W0a-W0b)+b0, v = F@W0b ----------
template<int C>
__global__ __launch_bounds__(256) void k_uv(const float* __restrict__ F,
                                            const float* __restrict__ W0,
                                            const float* __restrict__ b0,
                                            float* __restrict__ u, float* __restrict__ v) {
    __shared__ float As[64][17];
    __shared__ float Wa[16][64];
    __shared__ float Wb[16][64];
    int m0 = blockIdx.x*64;
    int t = threadIdx.x;
    int cb = (t & 15)*4, rb = (t >> 4)*4;
    float aU[4][4] = {}, aV[4][4] = {};
    for (int k0 = 0; k0 < C; k0 += 16) {
        #pragma unroll
        for (int j = 0; j < 4; j++) {
            int e = t + 256*j;
            int r = e >> 4, c = e & 15;
            As[r][c] = (k0 + c < C) ? F[(size_t)(m0 + r)*C + k0 + c] : 0.f;
        }
        {
            int r = t >> 4, c4 = (t & 15)*4;
            bool ok = (k0 + r < C);
            float4 wa = ok ? *(const float4*)&W0[(size_t)(k0 + r)*64 + c4] : make_float4(0,0,0,0);
            float4 wb = ok ? *(const float4*)&W0[(size_t)(C + k0 + r)*64 + c4] : make_float4(0,0,0,0);
            *(float4*)&Wa[r][c4] = wa;
            *(float4*)&Wb[r][c4] = wb;
        }
        __syncthreads();
        #pragma unroll
        for (int kk = 0; kk < 16; kk++) {
            float a[4];
            #pragma unroll
            for (int i = 0; i < 4; i++) a[i] = As[rb + i][kk];
            float4 wa4 = *(const float4*)&Wa[kk][cb];
            float4 wb4 = *(const float4*)&Wb[kk][cb];
            float wa[4] = {wa4.x, wa4.y, wa4.z, wa4.w};
            float wb[4] = {wb4.x, wb4.y, wb4.z, wb4.w};
            #pragma unroll
            for (int i = 0; i < 4; i++)
                #pragma unroll
                for (int j = 0; j < 4; j++) {
                    aU[i][j] = fmaf(a[i], wa[j] - wb[j], aU[i][j]);
                    aV[i][j] = fmaf(a[i], wb[j], aV[i][j]);
                }
        }
        __syncthreads();
    }
    #pragma unroll
    for (int i = 0; i < 4; i++) {
        int row = m0 + rb + i;
        #pragma unroll
        for (int j = 0; j < 4; j++) {
            int col = cb + j;
            u[(size_t)row*64 + col] = aU[i][j] + b0[col];
            v[(size_t)row*64 + col] = aV[i][j];
        }
    }
}

// ---------- 64-wide tiled f32 GEMM (final ho layer) ----------
template<int RELU>
__global__ __launch_bounds__(256) void k_gemm(const float* __restrict__ A,
                                              const float* __restrict__ W,
                                              const float* __restrict__ bias,
                                              float* __restrict__ out,
                                              int M, int Kd, int Nd) {
    __shared__ float As[64][17];
    __shared__ float Bs[16][64];
    int m0 = blockIdx.x*64, n0 = blockIdx.y*64;
    int t = threadIdx.x;
    int cb = (t & 15)*4, rb = (t >> 4)*4;
    float acc[4][4] = {};
    for (int k0 = 0; k0 < Kd; k0 += 16) {
        #pragma unroll
        for (int j = 0; j < 4; j++) {
            int e = t + 256*j;
            int r = e >> 4, c = e & 15;
            As[r][c] = (k0 + c < Kd) ? A[(size_t)(m0 + r)*Kd + k0 + c] : 0.f;
        }
        #pragma unroll
        for (int j = 0; j < 4; j++) {
            int e = t + 256*j;
            int r = e >> 6, c = e & 63;
            Bs[r][c] = (k0 + r < Kd && n0 + c < Nd) ? W[(size_t)(k0 + r)*Nd + n0 + c] : 0.f;
        }
        __syncthreads();
        #pragma unroll
        for (int kk = 0; kk < 16; kk++) {
            float a[4];
            #pragma unroll
            for (int i = 0; i < 4; i++) a[i] = As[rb + i][kk];
            float4 w4 = *(const float4*)&Bs[kk][cb];
            float w[4] = {w4.x, w4.y, w4.z, w4.w};
            #pragma unroll
            for (int i = 0; i < 4; i++)
                #pragma unroll
                for (int j = 0; j < 4; j++) acc[i][j] += a[i]*w[j];
        }
        __syncthreads();
    }
    #pragma unroll
    for (int i = 0; i < 4; i++) {
        int row = m0 + rb + i;
        #pragma unroll
        for (int j = 0; j < 4; j++) {
            int col = n0 + cb + j;
            if (col < Nd) {
                float v = acc[i][j] + (bias ? bias[col] : 0.f);
                if (RELU) v = fmaxf(v, 0.f);
                out[(size_t)row*Nd + col] = v;
            }
        }
    }
}

// ---------- pack f32 weights [Kd][Nd] -> bf16 fragment layout [(Kd/8)][Nd][8] ----------
__global__ void k_pack(const float* __restrict__ W, ushort_t* __restrict__ Wpk,
                       int Kd, int Nd) {
    int cell = blockIdx.x*256 + threadIdx.x;
    int ncell = (Kd >> 3)*Nd;
    if (cell >= ncell) return;
    int kg = cell / Nd, n = cell - kg*Nd;
    unsigned b[8];
    #pragma unroll
    for (int j = 0; j < 8; j++) b[j] = f2bf(W[(size_t)(kg*8 + j)*Nd + n]);
    uint4 wv;
    wv.x = b[0] | (b[1] << 16); wv.y = b[2] | (b[3] << 16);
    wv.z = b[4] | (b[5] << 16); wv.w = b[6] | (b[7] << 16);
    *(uint4*)&Wpk[(size_t)cell*8] = wv;
}

// ---------- bf16 MFMA GEMM: 128x128 tile, 4 waves (2x2 of 64x64), f32 out ----------
template<int CONCAT, int RELU>
__global__ __launch_bounds__(256) void k_mgemm(const float* __restrict__ A,
                                               const float* __restrict__ A2,
                                               const float* __restrict__ A3,
                                               const ushort_t* __restrict__ Wpk,
                                               const float* __restrict__ bias,
                                               float* __restrict__ out,
                                               int Kd, int Nd) {
    __shared__ ushort_t Al[4][128][8];   // [kgroup][row][8 bf16] = 8 KB
    __shared__ ushort_t Bl[4][128][8];   // [kgroup][col][8 bf16] = 8 KB
    int m0 = blockIdx.x*128, n0 = blockIdx.y*128;
    int t = threadIdx.x, lane = t & 63, w = t >> 6;
    int wm = (w >> 1)*64, wn = (w & 1)*64;
    f32x4 acc[4][4] = {};
    int arow = t >> 2, akg = t & 3;
    for (int k0 = 0; k0 < Kd; k0 += 32) {
        #pragma unroll
        for (int i = 0; i < 2; i++) {          // A: 512 cells, 2 per thread
            int row = arow + 64*i;
            int kb = k0 + akg*8;
            const float* src;
            if (CONCAT) {
                const float* s0 = (kb < 64) ? A : (kb < 128) ? A2 : A3;
                src = s0 + (size_t)(m0 + row)*64 + (kb & 63);
            } else {
                src = A + (size_t)(m0 + row)*Kd + kb;
            }
            float4 fa = *(const float4*)src;
            float4 fb = *(const float4*)(src + 4);
            uint4 wv;
            wv.x = f2bf(fa.x) | (f2bf(fa.y) << 16);
            wv.y = f2bf(fa.z) | (f2bf(fa.w) << 16);
            wv.z = f2bf(fb.x) | (f2bf(fb.y) << 16);
            wv.w = f2bf(fb.z) | (f2bf(fb.w) << 16);
            *(uint4*)&Al[akg][row][0] = wv;
        }
        #pragma unroll
        for (int i = 0; i < 2; i++) {          // B: 512 cells, contiguous copy
            int cell = t + 256*i;
            int kg = cell >> 7, col = cell & 127;
            *(uint4*)&Bl[kg][col][0] =
                *(const uint4*)&Wpk[((size_t)(k0/8 + kg)*Nd + n0 + col)*8];
        }
        __syncthreads();
        short8v af[4], bf[4];
        #pragma unroll
        for (int mf = 0; mf < 4; mf++)
            af[mf] = *(const short8v*)&Al[lane >> 4][wm + mf*16 + (lane & 15)][0];
        #pragma unroll
        for (int nf = 0; nf < 4; nf++)
            bf[nf] = *(const short8v*)&Bl[lane >> 4][wn + nf*16 + (lane & 15)][0];
        #pragma unroll
        for (int mf = 0; mf < 4; mf++)
            #pragma unroll
            for (int nf = 0; nf < 4; nf++)
                acc[mf][nf] = __builtin_amdgcn_mfma_f32_16x16x32_bf16(af[mf], bf[nf], acc[mf][nf], 0, 0, 0);
        __syncthreads();
    }
    int crow = (lane >> 4)*4;
    int ccol = lane & 15;
    #pragma unroll
    for (int nf = 0; nf < 4; nf++) {
        int col = n0 + wn + nf*16 + ccol;
        float bv = bias[col];
        #pragma unroll
        for (int mf = 0; mf < 4; mf++) {
            #pragma unroll
            for (int r = 0; r < 4; r++) {
                int row = m0 + wm + mf*16 + crow + r;
                float vv = acc[mf][nf][r] + bv;
                if (RELU) vv = fmaxf(vv, 0.f);
                out[(size_t)row*Nd + col] = vv;
            }
        }
    }
}

// ---------- stats of relu(u_p + v_q) over all edges (float4 vectorized) ----------
// grid 3840 x 256; element space: edge (19 bits) x c4 (4 groups of 4 channels)
__global__ __launch_bounds__(256) void k_e1stats(const float* __restrict__ u,
                                                 const float* __restrict__ v,
                                                 const int* __restrict__ idx,
                                                 float* __restrict__ psum, float* __restrict__ psq) {
    int t = threadIdx.x;
    float s0 = 0.f, s1 = 0.f, s2 = 0.f, s3 = 0.f;
    float q0 = 0.f, q1 = 0.f, q2 = 0.f, q3 = 0.f;
    const int stride = 3840*256;
    int i = blockIdx.x*256 + t;
    int c4 = (i & 15)*4;                    // invariant across iterations
    #pragma unroll 1
    for (int j = 0; j < 8; j++, i += stride) {   // 30*16384*16 / (3840*256) = 8
        int edge = i >> 4;
        int p = edge / KNN;
        int q = idx[edge];
        int b = p >> 11;
        float4 uv = *(const float4*)&u[(size_t)p*64 + c4];
        float4 vv = *(const float4*)&v[(size_t)(b*PNUM + q)*64 + c4];
        float h0 = fmaxf(uv.x + vv.x, 0.f);
        float h1 = fmaxf(uv.y + vv.y, 0.f);
        float h2 = fmaxf(uv.z + vv.z, 0.f);
        float h3 = fmaxf(uv.w + vv.w, 0.f);
        s0 += h0; s1 += h1; s2 += h2; s3 += h3;
        q0 = fmaf(h0, h0, q0); q1 = fmaf(h1, h1, q1);
        q2 = fmaf(h2, h2, q2); q3 = fmaf(h3, h3, q3);
    }
    __shared__ float rs[16][16][4];   // [edge-slot][chan-group][comp]
    __shared__ float rq[16][16][4];
    int slot = t >> 4, g = t & 15;
    rs[slot][g][0] = s0; rs[slot][g][1] = s1; rs[slot][g][2] = s2; rs[slot][g][3] = s3;
    rq[slot][g][0] = q0; rq[slot][g][1] = q1; rq[slot][g][2] = q2; rq[slot][g][3] = q3;
    __syncthreads();
    if (t < 64) {
        int gg = t >> 2, comp = t & 3;
        float ss = 0.f, qq = 0.f;
        #pragma unroll
        for (int sl = 0; sl < 16; sl++) { ss += rs[sl][gg][comp]; qq += rq[sl][gg][comp]; }
        psum[(size_t)blockIdx.x*64 + t] = ss;
        psq [(size_t)blockIdx.x*64 + t] = qq;
    }
}

// ---------- finalize BN stats ----------
__global__ void k_statsfin(const float* __restrict__ psum, const float* __restrict__ psq,
                           int npart, int C, float invM,
                           const float* __restrict__ g, const float* __restrict__ be,
                           float* __restrict__ scale, float* __restrict__ shift) {
    int c = blockIdx.x, t = threadIdx.x;
    float s = 0.f, q = 0.f;
    for (int i = t; i < npart; i += 256) {
        s += psum[(size_t)i*C + c];
        q += psq [(size_t)i*C + c];
    }
    __shared__ float rs[256], rq[256];
    rs[t] = s; rq[t] = q; __syncthreads();
    for (int off = 128; off >= 1; off >>= 1) {
        if (t < off) { rs[t] += rs[t+off]; rq[t] += rq[t+off]; }
        __syncthreads();
    }
    if (t == 0) {
        float m   = rs[0]*invM;
        float var = rq[0]*invM - m*m;
        float inv = rsqrtf(var + EPSF);
        float sc  = g[c]*inv;
        scale[c] = sc;
        shift[c] = be[c] - m*sc;
    }
}

// ---------- fold BN affine into next linear ----------
__global__ void k_fold(const float* __restrict__ W, const float* __restrict__ b,
                       const float* __restrict__ scale, const float* __restrict__ shift,
                       float* __restrict__ Wp, float* __restrict__ bp, int Cin, int Cout) {
    int co = blockIdx.x, t = threadIdx.x;
    float acc = 0.f;
    for (int ci = t; ci < Cin; ci += 256) {
        float w = W[(size_t)ci*Cout + co];
        Wp[(size_t)ci*Cout + co] = scale[ci]*w;
        acc += shift[ci]*w;
    }
    __shared__ float r[256];
    r[t] = acc; __syncthreads();
    for (int off = 128; off >= 1; off >>= 1) { if (t < off) r[t] += r[t+off]; __syncthreads(); }
    if (t == 0) bp[co] = b[co] + r[0];
}

// ---------- edge layer 1: wave-per-point, LDS-broadcast dot (no readlane) ----------
__global__ __launch_bounds__(256, 4) void k_e2(const float* __restrict__ u, const float* __restrict__ v,
                                               const int* __restrict__ idx,
                                               const float* __restrict__ W1p, const float* __restrict__ b1p,
                                               float* __restrict__ pmax, float* __restrict__ pmin,
                                               float* __restrict__ psum, float* __restrict__ psq) {
    __shared__ float W1s[64][64];      // 16 KB: W1s[c][co]
    __shared__ float hbuf[4][64];      // wave-private h vectors
    int t = threadIdx.x, lane = t & 63, w = t >> 6;
    int p = blockIdx.x*4 + w;
    int b = p >> 11;
    for (int e = t; e < 4096; e += 256) W1s[e >> 6][e & 63] = W1p[e];
    __syncthreads();
    float wcol[64];
    #pragma unroll
    for (int c = 0; c < 64; c++) wcol[c] = W1s[c][lane];   // conflict-free column read
    float ureg = u[(size_t)p*64 + lane];
    float bias = b1p[lane];
    const int* myidx = idx + (size_t)p*KNN;
    const float* vb = v + (size_t)b*PNUM*64;
    float mx = -1e30f, mn = 1e30f, sm = 0.f, sq = 0.f;
    int q = myidx[0];
    float vk = vb[(size_t)q*64 + lane];
    #pragma unroll 1
    for (int k = 0; k < KNN; k++) {
        float h = fmaxf(ureg + vk, 0.f);
        hbuf[w][lane] = h;               // wave-private; in-order DS pipe -> no barrier
        if (k + 1 < KNN) {               // prefetch next neighbor row
            int qn = myidx[k + 1];
            vk = vb[(size_t)qn*64 + lane];
        }
        float a0 = 0.f, a1 = 0.f, a2 = 0.f, a3 = 0.f;
        #pragma unroll
        for (int c = 0; c < 64; c += 4) {
            float4 h4 = *(const float4*)&hbuf[w][c];   // uniform-address broadcast read
            a0 = fmaf(h4.x, wcol[c    ], a0);
            a1 = fmaf(h4.y, wcol[c + 1], a1);
            a2 = fmaf(h4.z, wcol[c + 2], a2);
            a3 = fmaf(h4.w, wcol[c + 3], a3);
        }
        float o = fmaxf((a0 + a1) + (a2 + a3) + bias, 0.f);
        mx = fmaxf(mx, o);
        mn = fminf(mn, o);
        sm += o;
        sq = fmaf(o, o, sq);
    }
    pmax[(size_t)p*64 + lane] = mx;
    pmin[(size_t)p*64 + lane] = mn;
    psum[(size_t)p*64 + lane] = sm;
    psq [(size_t)p*64 + lane] = sq;
}

// ---------- BN1 applied after pooling (max if scale>=0 else min) ----------
__global__ void k_applypool(const float* __restrict__ pmax, const float* __restrict__ pmin,
                            const float* __restrict__ scale, const float* __restrict__ shift,
                            float* __restrict__ out) {
    int i = blockIdx.x*256 + threadIdx.x;
    int c = i & 63;
    float sc = scale[c];
    float pooled = (sc >= 0.f) ? pmax[i] : pmin[i];
    out[i] = sc*pooled + shift[c];
}

// ---------- per-column partial sums over 64-row blocks ----------
__global__ void k_colstats(const float* __restrict__ Hbuf, float* __restrict__ psum,
                           float* __restrict__ psq, int Cout) {
    int m0 = blockIdx.x*64, c0 = blockIdx.y*64;
    int t = threadIdx.x;
    int c = t & 63, rg = t >> 6;
    float s = 0.f, q = 0.f;
    #pragma unroll 4
    for (int r = 0; r < 16; r++) {
        float hv = Hbuf[(size_t)(m0 + rg*16 + r)*Cout + c0 + c];
        s += hv; q += hv*hv;
    }
    __shared__ float rs[256], rq[256];
    rs[t] = s; rq[t] = q; __syncthreads();
    if (t < 128) { rs[t] += rs[t+128]; rq[t] += rq[t+128]; }
    __syncthreads();
    if (t < 64) {
        rs[t] += rs[t+64]; rq[t] += rq[t+64];
        psum[(size_t)blockIdx.x*Cout + c0 + t] = rs[t];
        psq [(size_t)blockIdx.x*Cout + c0 + t] = rq[t];
    }
}

// ---------- log_softmax over 50 cols, one wave per row ----------
__global__ void k_logsoftmax(const float* __restrict__ logits, float* __restrict__ out) {
    int t = threadIdx.x;
    int n = blockIdx.x*4 + (t >> 6);
    int l = t & 63;
    float z = (l < 50) ? logits[(size_t)n*50 + l] : -INFINITY;
    float mx = z;
    #pragma unroll
    for (int off = 32; off >= 1; off >>= 1) mx = fmaxf(mx, __shfl_xor(mx, off, 64));
    float ex = (l < 50) ? expf(z - mx) : 0.f;
    float sm = ex;
    #pragma unroll
    for (int off = 32; off >= 1; off >>= 1) sm += __shfl_xor(sm, off, 64);
    float lse = mx + logf(sm);
    if (l < 50) out[(size_t)n*50 + l] = z - lse;
}

extern "C" void kernel_launch(void* const* d_in, const int* in_sizes, int n_in,
                              void* d_out, int out_size, void* d_ws, size_t ws_size,
                              hipStream_t stream) {
    (void)in_sizes; (void)n_in; (void)out_size;
    const float* x   = (const float*)d_in[0];
    const float* pos = (const float*)d_in[1];
    const float* prm[38];
    for (int i = 0; i < 38; i++) prm[i] = (const float*)d_in[3 + i];
    // prm: c1[0..7] c2[8..15] c3[16..23] l1[24..27] h0[28..31] h1[32..35] ho[36..37]

    float* ws = (float*)d_ws;
    size_t off = 0;
    auto alloc = [&](size_t cnt) { float* p = ws + off; off += (cnt + 63) & ~((size_t)63); return p; };
    float* f0   = alloc((size_t)NPT*6);
    float* x1   = alloc((size_t)NPT*64);
    float* x2   = alloc((size_t)NPT*64);
    float* x3   = alloc((size_t)NPT*64);
    float* u    = alloc((size_t)NPT*64);
    float* v    = alloc((size_t)NPT*64);
    float* pmax = alloc((size_t)NPT*64);
    float* pmin = alloc((size_t)NPT*64);
    int*   idx  = (int*)alloc((size_t)NPT*KNN);
    int*   ccnt = (int*)alloc(NPT);
    float* W1p  = alloc(64*64);
    float* b1p  = alloc(64);
    float* scaleA = alloc(1024);
    float* shiftA = alloc(1024);
    float* Wp   = alloc(1024*256);
    float* bp   = alloc(1024);
    ushort_t* Wpk1 = (ushort_t*)alloc(98304);    // l1 packed weights (192*1024 bf16)
    ushort_t* Wpk2 = (ushort_t*)alloc(131072);   // h0/h1 packed weights (max 1024*256 bf16)
    float* psum = alloc((size_t)NPT*64);
    float* psq  = alloc((size_t)NPT*64);
    float* big  = alloc((size_t)BNUM*PNUM*PNUM);   // shared: Dk (u16), then head activations
    if (off*sizeof(float) > ws_size) return;       // insufficient workspace -> leave poisoned

    // cand (NPT*KCAP ints = 4 MB) aliases psum (4 MB): dead ranges don't overlap in time
    int* cand = (int*)psum;
    ushort_t* Dk = (ushort_t*)big;

    auto conv = [&](const float* F, int C, const float* const* pp, float* xout) {
        if (C == 6) k_dist<6><<<dim3(16,16,8), 256, 0, stream>>>(F, Dk);
        else        k_dist<64><<<dim3(16,16,8), 256, 0, stream>>>(F, Dk);
        k_topk<<<NPT, 256, 0, stream>>>(Dk, cand, ccnt);
        if (C == 6) k_refine<6><<<NPT/4, 256, 0, stream>>>(F, cand, ccnt, idx);
        else        k_refine<64><<<NPT/4, 256, 0, stream>>>(F, cand, ccnt, idx);
        if (C == 6) k_uv<6><<<NPT/64, 256, 0, stream>>>(F, pp[0], pp[1], u, v);
        else        k_uv<64><<<NPT/64, 256, 0, stream>>>(F, pp[0], pp[1], u, v);
        k_e1stats<<<3840, 256, 0, stream>>>(u, v, idx, psum, psq);
        k_statsfin<<<64, 256, 0, stream>>>(psum, psq, 3840, 64, 1.f/((float)NPT*KNN),
                                           pp[2], pp[3], scaleA, shiftA);
        k_fold<<<64, 256, 0, stream>>>(pp[4], pp[5], scaleA, shiftA, W1p, b1p, 64, 64);
        k_e2<<<NPT/4, 256, 0, stream>>>(u, v, idx, W1p, b1p, pmax, pmin, psum, psq);
        k_statsfin<<<64, 256, 0, stream>>>(psum, psq, NPT, 64, 1.f/((float)NPT*KNN),
                                           pp[6], pp[7], scaleA, shiftA);
        k_applypool<<<NPT*64/256, 256, 0, stream>>>(pmax, pmin, scaleA, shiftA, xout);
    };

    k_concat6<<<NPT*6/256, 256, 0, stream>>>(x, pos, f0);
    k_pack<<<96, 256, 0, stream>>>(prm[24], Wpk1, 192, 1024);   // l1 weights (no fold needed)
    conv(f0, 6,  &prm[0],  x1);
    conv(x1, 64, &prm[8],  x2);
    conv(x2, 64, &prm[16], x3);

    float* Hb1    = big + 3145728;
    float* Hb2    = big + 19922944;
    float* Hb3    = big + 24117248;
    float* logits = big + 26214400;

    // l1: [x1|x2|x3] (16384x192) @ W (192x1024) + bias, ReLU — bf16 MFMA
    k_mgemm<1,1><<<dim3(NPT/128, 8), 256, 0, stream>>>(x1, x2, x3, Wpk1, prm[25], Hb1, 192, 1024);
    k_colstats<<<dim3(NPT/64, 16), 256, 0, stream>>>(Hb1, psum, psq, 1024);
    k_statsfin<<<1024, 256, 0, stream>>>(psum, psq, NPT/64, 1024, 1.f/(float)NPT,
                                         prm[26], prm[27], scaleA, shiftA);
    k_fold<<<256, 256, 0, stream>>>(prm[28], prm[29], scaleA, shiftA, Wp, bp, 1024, 256);
    k_pack<<<128, 256, 0, stream>>>(Wp, Wpk2, 1024, 256);
    k_mgemm<0,1><<<dim3(NPT/128, 2), 256, 0, stream>>>(Hb1, nullptr, nullptr, Wpk2, bp, Hb2, 1024, 256);
    k_colstats<<<dim3(NPT/64, 4), 256, 0, stream>>>(Hb2, psum, psq, 256);
    k_statsfin<<<256, 256, 0, stream>>>(psum, psq, NPT/64, 256, 1.f/(float)NPT,
                                        prm[30], prm[31], scaleA, shiftA);
    k_fold<<<128, 256, 0, stream>>>(prm[32], prm[33], scaleA, shiftA, Wp, bp, 256, 128);
    k_pack<<<16, 256, 0, stream>>>(Wp, Wpk2, 256, 128);
    k_mgemm<0,1><<<dim3(NPT/128, 1), 256, 0, stream>>>(Hb2, nullptr, nullptr, Wpk2, bp, Hb3, 256, 128);
    k_colstats<<<dim3(NPT/64, 2), 256, 0, stream>>>(Hb3, psum, psq, 128);
    k_statsfin<<<128, 256, 0, stream>>>(psum, psq, NPT/64, 128, 1.f/(float)NPT,
                                        prm[34], prm[35], scaleA, shiftA);
    k_fold<<<50, 256, 0, stream>>>(prm[36], prm[37], scaleA, shiftA, Wp, bp, 128, 50);
    k_gemm<0><<<dim3(NPT/64, 1), 256, 0, stream>>>(Hb3, Wp, bp, logits, NPT, 128, 50);
    k_logsoftmax<<<NPT/4, 256, 0, stream>>>(logits, (float*)d_out);
}

// Round 9
// 1156.083 us; speedup vs baseline: 3.4034x; 1.1697x over previous
//
#include <hip/hip_runtime.h>
#include <hip/hip_bf16.h>
#include <stdint.h>

#define BNUM 8
#define PNUM 2048
#define KNN  30
#define KSEL 40      // rank threshold for candidate selection
#define KCAP 64      // max candidates per row (one wave in refine)
#define NPT  (BNUM*PNUM)   // 16384
#define EPSF 1e-5f

typedef unsigned long long u64;
typedef unsigned short ushort_t;
typedef __attribute__((ext_vector_type(8))) short short8v;   // 8 bf16 (4 VGPRs)
typedef __attribute__((ext_vector_type(4))) float f32x4;

__device__ __forceinline__ unsigned mono_key(float d) {
    unsigned u = __float_as_uint(d);
    return (u & 0x80000000u) ? ~u : (u | 0x80000000u);   // monotone float->uint
}

__device__ __forceinline__ unsigned f2bf(float f) {      // f32 -> bf16 bits, RNE
    unsigned u = __float_as_uint(f);
    u += 0x7fffu + ((u >> 16) & 1u);
    return u >> 16;
}

__device__ __forceinline__ double lane_bcast64(double x, int l) {   // uniform l -> v_readlane
    union { double d; int i[2]; } a; a.d = x;
    union { int i[2]; double d; } r;
    r.i[0] = __builtin_amdgcn_readlane(a.i[0], l);
    r.i[1] = __builtin_amdgcn_readlane(a.i[1], l);
    return r.d;
}

// ---------- f0 = concat(x, pos) ----------
__global__ void k_concat6(const float* __restrict__ x, const float* __restrict__ pos,
                          float* __restrict__ f0) {
    int i = blockIdx.x*256 + threadIdx.x;        // < N*6
    int n = i/6, c = i%6;
    f0[i] = (c < 3) ? x[n*3 + c] : pos[n*3 + c - 3];
}

// ---------- dist 128x128 tile (snorm fused): Dk = top16(monokey(s_p+s_q-2 f_p.f_q)) ----------
template<int C>
__global__ __launch_bounds__(256) void k_dist(const float* __restrict__ F,
                                              ushort_t* __restrict__ Dk) {
    __shared__ float FpT[C][132];
    __shared__ float FqT[C][132];
    __shared__ float sp[128], sq[128];
    int b = blockIdx.z;
    int p0 = blockIdx.x*128, q0 = blockIdx.y*128;
    int t = threadIdx.x;
    for (int e = t; e < 128*C; e += 256) {
        int r = e / C, c = e % C;
        FpT[c][r] = F[(size_t)(b*PNUM + p0 + r)*C + c];
        FqT[c][r] = F[(size_t)(b*PNUM + q0 + r)*C + c];
    }
    __syncthreads();
    if (t < 128) {
        float a = 0.f;
        for (int c = 0; c < C; c++) { float xv = FpT[c][t]; a = fmaf(xv, xv, a); }
        sp[t] = a;
    } else {
        int r = t - 128;
        float a = 0.f;
        for (int c = 0; c < C; c++) { float xv = FqT[c][r]; a = fmaf(xv, xv, a); }
        sq[r] = a;
    }
    __syncthreads();
    int tc = (t & 15)*8, tr = (t >> 4)*8;
    float acc[8][8] = {};
    #pragma unroll 4
    for (int c = 0; c < C; c++) {
        float4 p0v = *(const float4*)&FpT[c][tr];
        float4 p1v = *(const float4*)&FpT[c][tr+4];
        float4 q0v = *(const float4*)&FqT[c][tc];
        float4 q1v = *(const float4*)&FqT[c][tc+4];
        float av[8] = {p0v.x,p0v.y,p0v.z,p0v.w,p1v.x,p1v.y,p1v.z,p1v.w};
        float bv[8] = {q0v.x,q0v.y,q0v.z,q0v.w,q1v.x,q1v.y,q1v.z,q1v.w};
        #pragma unroll
        for (int i = 0; i < 8; i++)
            #pragma unroll
            for (int j = 0; j < 8; j++) acc[i][j] = fmaf(av[i], bv[j], acc[i][j]);
    }
    #pragma unroll
    for (int i = 0; i < 8; i++) {
        unsigned ks[8];
        #pragma unroll
        for (int j = 0; j < 8; j++) {
            float d = sp[tr + i] + sq[tc + j] - 2.0f*acc[i][j];
            ks[j] = mono_key(d) >> 16;
        }
        uint4 w;
        w.x = ks[0] | (ks[1] << 16);
        w.y = ks[2] | (ks[3] << 16);
        w.z = ks[4] | (ks[5] << 16);
        w.w = ks[6] | (ks[7] << 16);
        *(uint4*)&Dk[(size_t)(b*PNUM + p0 + tr + i)*PNUM + q0 + tc] = w;
    }
}

// ---------- candidate select: binary search threshold on u16 keys; no atomics ----------
__global__ __launch_bounds__(256) void k_topk(const ushort_t* __restrict__ Dk,
                                              int* __restrict__ cand, int* __restrict__ ccnt) {
    __shared__ int red[4];
    __shared__ int wbase[4];
    int n = blockIdx.x, t = threadIdx.x, lane = t & 63, w = t >> 6;
    uint4 wv = *(const uint4*)(Dk + (size_t)n*PNUM + t*8);
    int ks[8];
    ks[0] = wv.x & 0xffff; ks[1] = wv.x >> 16;
    ks[2] = wv.y & 0xffff; ks[3] = wv.y >> 16;
    ks[4] = wv.z & 0xffff; ks[5] = wv.z >> 16;
    ks[6] = wv.w & 0xffff; ks[7] = wv.w >> 16;
    int lo = 0, hi = 65535;
    while (lo < hi) {                      // 16 iterations, block-uniform
        int mid = (lo + hi) >> 1;
        int c = 0;
        #pragma unroll
        for (int e = 0; e < 8; e++) c += (ks[e] <= mid);
        #pragma unroll
        for (int o = 32; o >= 1; o >>= 1) c += __shfl_xor(c, o, 64);
        if (lane == 0) red[w] = c;
        __syncthreads();
        int tot = red[0] + red[1] + red[2] + red[3];
        __syncthreads();
        if (tot >= KSEL) hi = mid; else lo = mid + 1;
    }
    int P = lo;
    int lc = 0;
    #pragma unroll
    for (int e = 0; e < 8; e++) lc += (ks[e] <= P);
    int pre = lc;                          // inclusive prefix within wave
    #pragma unroll
    for (int o = 1; o < 64; o <<= 1) { int vv = __shfl_up(pre, o, 64); if (lane >= o) pre += vv; }
    int excl = pre - lc;
    if (lane == 63) red[w] = pre;          // wave totals
    __syncthreads();
    if (t == 0) {
        int s0 = 0;
        #pragma unroll
        for (int i = 0; i < 4; i++) { wbase[i] = s0; s0 += red[i]; }
        ccnt[n] = (s0 < KCAP) ? s0 : KCAP;
    }
    __syncthreads();
    int base = wbase[w] + excl;
    #pragma unroll
    for (int e = 0; e < 8; e++) {
        if (ks[e] <= P) {
            if (base < KCAP) cand[(size_t)n*KCAP + base] = t*8 + e;
            base++;
        }
    }
}

// ---------- refine: f64 distances + all-pairs rank (no serial extraction) ----------
// rank = #{(d_l,q_l) < (d,q)} lexicographic; identical semantics to iterative argmin.
template<int C>
__global__ __launch_bounds__(256) void k_refine(const float* __restrict__ F,
                                                const int* __restrict__ cand,
                                                const int* __restrict__ ccnt,
                                                int* __restrict__ idx) {
    int t = threadIdx.x;
    int lane = t & 63;
    int row = blockIdx.x*4 + (t >> 6);
    int b = row >> 11;
    const float* fp = F + (size_t)row*C;
    int cnt = ccnt[row];
    bool act = lane < cnt;
    int q = act ? cand[(size_t)row*KCAP + lane] : (lane | 0x40000000);
    const float* fq = F + (size_t)(b*PNUM + (act ? q : 0))*C;
    double d = 1e300;
    if (act) {
        d = 0.0;
        if (C == 64) {
            #pragma unroll
            for (int c4 = 0; c4 < C/4; c4++) {
                float4 a = ((const float4*)fp)[c4];
                float4 bb = ((const float4*)fq)[c4];
                double d0 = (double)a.x - (double)bb.x;
                double d1 = (double)a.y - (double)bb.y;
                double d2 = (double)a.z - (double)bb.z;
                double d3 = (double)a.w - (double)bb.w;
                d += d0*d0 + d1*d1 + d2*d2 + d3*d3;
            }
        } else {
            #pragma unroll
            for (int c = 0; c < C; c++) {
                double df = (double)fp[c] - (double)fq[c];
                d += df*df;
            }
        }
    }
    int rank = 0;
    #pragma unroll 16
    for (int l = 0; l < 64; l++) {
        double dl = lane_bcast64(d, l);
        int ql = __builtin_amdgcn_readlane(q, l);
        rank += (dl < d) || (dl == d && ql < q);
    }
    if (act && rank < KNN) idx[(size_t)row*KNN + rank] = q;
}

// ---------- fused u/v GEMM: u = F@(W0a-W0b)+b0, v = F@W0b ----------
template<int C>
__global__ __launch_bounds__(256) void k_uv(const float* __restrict__ F,
                                            const float* __restrict__ W0,
                                            const float* __restrict__ b0,
                                            float* __restrict__ u, float* __restrict__ v) {
    __shared__ float As[64][17];
    __shared__ float Wa[16][64];
    __shared__ float Wb[16][64];
    int m0 = blockIdx.x*64;
    int t = threadIdx.x;
    int cb = (t & 15)*4, rb = (t >> 4)*4;
    float aU[4][4] = {}, aV[4][4] = {};
    for (int k0 = 0; k0 < C; k0 += 16) {
        #pragma unroll
        for (int j = 0; j < 4; j++) {
            int e = t + 256*j;
            int r = e >> 4, c = e & 15;
            As[r][c] = (k0 + c < C) ? F[(size_t)(m0 + r)*C + k0 + c] : 0.f;
        }
        {
            int r = t >> 4, c4 = (t & 15)*4;
            bool ok = (k0 + r < C);
            float4 wa = ok ? *(const float4*)&W0[(size_t)(k0 + r)*64 + c4] : make_float4(0,0,0,0);
            float4 wb = ok ? *(const float4*)&W0[(size_t)(C + k0 + r)*64 + c4] : make_float4(0,0,0,0);
            *(float4*)&Wa[r][c4] = wa;
            *(float4*)&Wb[r][c4] = wb;
        }
        __syncthreads();
        #pragma unroll
        for (int kk = 0; kk < 16; kk++) {
            float a[4];
            #pragma unroll
            for (int i = 0; i < 4; i++) a[i] = As[rb + i][kk];
            float4 wa4 = *(const float4*)&Wa[kk][cb];
            float4 wb4 = *(const float4*)&Wb[kk][cb];
            float wa[4] = {wa4.x, wa4.y, wa4.z, wa4.w};
            float wb[4] = {wb4.x, wb4.y, wb4.z, wb4.w};
            #pragma unroll
            for (int i = 0; i < 4; i++)
                #pragma unroll
                for (int j = 0; j < 4; j++) {
                    aU[i][j] = fmaf(a[i], wa[j] - wb[j], aU[i][j]);
                    aV[i][j] = fmaf(a[i], wb[j], aV[i][j]);
                }
        }
        __syncthreads();
    }
    #pragma unroll
    for (int i = 0; i < 4; i++) {
        int row = m0 + rb + i;
        #pragma unroll
        for (int j = 0; j < 4; j++) {
            int col = cb + j;
            u[(size_t)row*64 + col] = aU[i][j] + b0[col];
            v[(size_t)row*64 + col] = aV[i][j];
        }
    }
}

// ---------- 64-wide tiled f32 GEMM (final ho layer) ----------
template<int RELU>
__global__ __launch_bounds__(256) void k_gemm(const float* __restrict__ A,
                                              const float* __restrict__ W,
                                              const float* __restrict__ bias,
                                              float* __restrict__ out,
                                              int M, int Kd, int Nd) {
    __shared__ float As[64][17];
    __shared__ float Bs[16][64];
    int m0 = blockIdx.x*64, n0 = blockIdx.y*64;
    int t = threadIdx.x;
    int cb = (t & 15)*4, rb = (t >> 4)*4;
    float acc[4][4] = {};
    for (int k0 = 0; k0 < Kd; k0 += 16) {
        #pragma unroll
        for (int j = 0; j < 4; j++) {
            int e = t + 256*j;
            int r = e >> 4, c = e & 15;
            As[r][c] = (k0 + c < Kd) ? A[(size_t)(m0 + r)*Kd + k0 + c] : 0.f;
        }
        #pragma unroll
        for (int j = 0; j < 4; j++) {
            int e = t + 256*j;
            int r = e >> 6, c = e & 63;
            Bs[r][c] = (k0 + r < Kd && n0 + c < Nd) ? W[(size_t)(k0 + r)*Nd + n0 + c] : 0.f;
        }
        __syncthreads();
        #pragma unroll
        for (int kk = 0; kk < 16; kk++) {
            float a[4];
            #pragma unroll
            for (int i = 0; i < 4; i++) a[i] = As[rb + i][kk];
            float4 w4 = *(const float4*)&Bs[kk][cb];
            float w[4] = {w4.x, w4.y, w4.z, w4.w};
            #pragma unroll
            for (int i = 0; i < 4; i++)
                #pragma unroll
                for (int j = 0; j < 4; j++) acc[i][j] += a[i]*w[j];
        }
        __syncthreads();
    }
    #pragma unroll
    for (int i = 0; i < 4; i++) {
        int row = m0 + rb + i;
        #pragma unroll
        for (int j = 0; j < 4; j++) {
            int col = n0 + cb + j;
            if (col < Nd) {
                float v = acc[i][j] + (bias ? bias[col] : 0.f);
                if (RELU) v = fmaxf(v, 0.f);
                out[(size_t)row*Nd + col] = v;
            }
        }
    }
}

// ---------- pack f32 weights [Kd][Nd] -> bf16 fragment layout [(Kd/8)][Nd][8] ----------
__global__ void k_pack(const float* __restrict__ W, ushort_t* __restrict__ Wpk,
                       int Kd, int Nd) {
    int cell = blockIdx.x*256 + threadIdx.x;
    int ncell = (Kd >> 3)*Nd;
    if (cell >= ncell) return;
    int kg = cell / Nd, n = cell - kg*Nd;
    unsigned b[8];
    #pragma unroll
    for (int j = 0; j < 8; j++) b[j] = f2bf(W[(size_t)(kg*8 + j)*Nd + n]);
    uint4 wv;
    wv.x = b[0] | (b[1] << 16); wv.y = b[2] | (b[3] << 16);
    wv.z = b[4] | (b[5] << 16); wv.w = b[6] | (b[7] << 16);
    *(uint4*)&Wpk[(size_t)cell*8] = wv;
}

// ---------- bf16 MFMA GEMM: 128x128 tile, 4 waves (2x2 of 64x64), f32 out ----------
template<int CONCAT, int RELU>
__global__ __launch_bounds__(256) void k_mgemm(const float* __restrict__ A,
                                               const float* __restrict__ A2,
                                               const float* __restrict__ A3,
                                               const ushort_t* __restrict__ Wpk,
                                               const float* __restrict__ bias,
                                               float* __restrict__ out,
                                               int Kd, int Nd) {
    __shared__ ushort_t Al[4][128][8];   // [kgroup][row][8 bf16] = 8 KB
    __shared__ ushort_t Bl[4][128][8];   // [kgroup][col][8 bf16] = 8 KB
    int m0 = blockIdx.x*128, n0 = blockIdx.y*128;
    int t = threadIdx.x, lane = t & 63, w = t >> 6;
    int wm = (w >> 1)*64, wn = (w & 1)*64;
    f32x4 acc[4][4] = {};
    int arow = t >> 2, akg = t & 3;
    for (int k0 = 0; k0 < Kd; k0 += 32) {
        #pragma unroll
        for (int i = 0; i < 2; i++) {          // A: 512 cells, 2 per thread
            int row = arow + 64*i;
            int kb = k0 + akg*8;
            const float* src;
            if (CONCAT) {
                const float* s0 = (kb < 64) ? A : (kb < 128) ? A2 : A3;
                src = s0 + (size_t)(m0 + row)*64 + (kb & 63);
            } else {
                src = A + (size_t)(m0 + row)*Kd + kb;
            }
            float4 fa = *(const float4*)src;
            float4 fb = *(const float4*)(src + 4);
            uint4 wv;
            wv.x = f2bf(fa.x) | (f2bf(fa.y) << 16);
            wv.y = f2bf(fa.z) | (f2bf(fa.w) << 16);
            wv.z = f2bf(fb.x) | (f2bf(fb.y) << 16);
            wv.w = f2bf(fb.z) | (f2bf(fb.w) << 16);
            *(uint4*)&Al[akg][row][0] = wv;
        }
        #pragma unroll
        for (int i = 0; i < 2; i++) {          // B: 512 cells, contiguous copy
            int cell = t + 256*i;
            int kg = cell >> 7, col = cell & 127;
            *(uint4*)&Bl[kg][col][0] =
                *(const uint4*)&Wpk[((size_t)(k0/8 + kg)*Nd + n0 + col)*8];
        }
        __syncthreads();
        short8v af[4], bf[4];
        #pragma unroll
        for (int mf = 0; mf < 4; mf++)
            af[mf] = *(const short8v*)&Al[lane >> 4][wm + mf*16 + (lane & 15)][0];
        #pragma unroll
        for (int nf = 0; nf < 4; nf++)
            bf[nf] = *(const short8v*)&Bl[lane >> 4][wn + nf*16 + (lane & 15)][0];
        #pragma unroll
        for (int mf = 0; mf < 4; mf++)
            #pragma unroll
            for (int nf = 0; nf < 4; nf++)
                acc[mf][nf] = __builtin_amdgcn_mfma_f32_16x16x32_bf16(af[mf], bf[nf], acc[mf][nf], 0, 0, 0);
        __syncthreads();
    }
    int crow = (lane >> 4)*4;
    int ccol = lane & 15;
    #pragma unroll
    for (int nf = 0; nf < 4; nf++) {
        int col = n0 + wn + nf*16 + ccol;
        float bv = bias[col];
        #pragma unroll
        for (int mf = 0; mf < 4; mf++) {
            #pragma unroll
            for (int r = 0; r < 4; r++) {
                int row = m0 + wm + mf*16 + crow + r;
                float vv = acc[mf][nf][r] + bv;
                if (RELU) vv = fmaxf(vv, 0.f);
                out[(size_t)row*Nd + col] = vv;
            }
        }
    }
}

// ---------- stats of relu(u_p + v_q) over all edges (float4 vectorized) ----------
__global__ __launch_bounds__(256) void k_e1stats(const float* __restrict__ u,
                                                 const float* __restrict__ v,
                                                 const int* __restrict__ idx,
                                                 float* __restrict__ psum, float* __restrict__ psq) {
    int t = threadIdx.x;
    float s0 = 0.f, s1 = 0.f, s2 = 0.f, s3 = 0.f;
    float q0 = 0.f, q1 = 0.f, q2 = 0.f, q3 = 0.f;
    const int stride = 3840*256;
    int i = blockIdx.x*256 + t;
    int c4 = (i & 15)*4;                    // invariant across iterations
    #pragma unroll 1
    for (int j = 0; j < 8; j++, i += stride) {   // 30*16384*16 / (3840*256) = 8
        int edge = i >> 4;
        int p = edge / KNN;
        int q = idx[edge];
        int b = p >> 11;
        float4 uv = *(const float4*)&u[(size_t)p*64 + c4];
        float4 vv = *(const float4*)&v[(size_t)(b*PNUM + q)*64 + c4];
        float h0 = fmaxf(uv.x + vv.x, 0.f);
        float h1 = fmaxf(uv.y + vv.y, 0.f);
        float h2 = fmaxf(uv.z + vv.z, 0.f);
        float h3 = fmaxf(uv.w + vv.w, 0.f);
        s0 += h0; s1 += h1; s2 += h2; s3 += h3;
        q0 = fmaf(h0, h0, q0); q1 = fmaf(h1, h1, q1);
        q2 = fmaf(h2, h2, q2); q3 = fmaf(h3, h3, q3);
    }
    __shared__ float rs[16][16][4];   // [edge-slot][chan-group][comp]
    __shared__ float rq[16][16][4];
    int slot = t >> 4, g = t & 15;
    rs[slot][g][0] = s0; rs[slot][g][1] = s1; rs[slot][g][2] = s2; rs[slot][g][3] = s3;
    rq[slot][g][0] = q0; rq[slot][g][1] = q1; rq[slot][g][2] = q2; rq[slot][g][3] = q3;
    __syncthreads();
    if (t < 64) {
        int gg = t >> 2, comp = t & 3;
        float ss = 0.f, qq = 0.f;
        #pragma unroll
        for (int sl = 0; sl < 16; sl++) { ss += rs[sl][gg][comp]; qq += rq[sl][gg][comp]; }
        psum[(size_t)blockIdx.x*64 + t] = ss;
        psq [(size_t)blockIdx.x*64 + t] = qq;
    }
}

// ---------- finalize BN stats ----------
__global__ void k_statsfin(const float* __restrict__ psum, const float* __restrict__ psq,
                           int npart, int C, float invM,
                           const float* __restrict__ g, const float* __restrict__ be,
                           float* __restrict__ scale, float* __restrict__ shift) {
    int c = blockIdx.x, t = threadIdx.x;
    float s = 0.f, q = 0.f;
    for (int i = t; i < npart; i += 256) {
        s += psum[(size_t)i*C + c];
        q += psq [(size_t)i*C + c];
    }
    __shared__ float rs[256], rq[256];
    rs[t] = s; rq[t] = q; __syncthreads();
    for (int off = 128; off >= 1; off >>= 1) {
        if (t < off) { rs[t] += rs[t+off]; rq[t] += rq[t+off]; }
        __syncthreads();
    }
    if (t == 0) {
        float m   = rs[0]*invM;
        float var = rq[0]*invM - m*m;
        float inv = rsqrtf(var + EPSF);
        float sc  = g[c]*inv;
        scale[c] = sc;
        shift[c] = be[c] - m*sc;
    }
}

// ---------- fold BN affine into next linear ----------
__global__ void k_fold(const float* __restrict__ W, const float* __restrict__ b,
                       const float* __restrict__ scale, const float* __restrict__ shift,
                       float* __restrict__ Wp, float* __restrict__ bp, int Cin, int Cout) {
    int co = blockIdx.x, t = threadIdx.x;
    float acc = 0.f;
    for (int ci = t; ci < Cin; ci += 256) {
        float w = W[(size_t)ci*Cout + co];
        Wp[(size_t)ci*Cout + co] = scale[ci]*w;
        acc += shift[ci]*w;
    }
    __shared__ float r[256];
    r[t] = acc; __syncthreads();
    for (int off = 128; off >= 1; off >>= 1) { if (t < off) r[t] += r[t+off]; __syncthreads(); }
    if (t == 0) bp[co] = b[co] + r[0];
}

// ---------- edge layer 1: wave-per-point, LDS-broadcast dot (no readlane) ----------
__global__ __launch_bounds__(256, 4) void k_e2(const float* __restrict__ u, const float* __restrict__ v,
                                               const int* __restrict__ idx,
                                               const float* __restrict__ W1p, const float* __restrict__ b1p,
                                               float* __restrict__ pmax, float* __restrict__ pmin,
                                               float* __restrict__ psum, float* __restrict__ psq) {
    __shared__ float W1s[64][64];      // 16 KB: W1s[c][co]
    __shared__ float hbuf[4][64];      // wave-private h vectors
    int t = threadIdx.x, lane = t & 63, w = t >> 6;
    int p = blockIdx.x*4 + w;
    int b = p >> 11;
    for (int e = t; e < 4096; e += 256) W1s[e >> 6][e & 63] = W1p[e];
    __syncthreads();
    float wcol[64];
    #pragma unroll
    for (int c = 0; c < 64; c++) wcol[c] = W1s[c][lane];   // conflict-free column read
    float ureg = u[(size_t)p*64 + lane];
    float bias = b1p[lane];
    const int* myidx = idx + (size_t)p*KNN;
    const float* vb = v + (size_t)b*PNUM*64;
    float mx = -1e30f, mn = 1e30f, sm = 0.f, sq = 0.f;
    int q = myidx[0];
    float vk = vb[(size_t)q*64 + lane];
    #pragma unroll 1
    for (int k = 0; k < KNN; k++) {
        float h = fmaxf(ureg + vk, 0.f);
        hbuf[w][lane] = h;               // wave-private; in-order DS pipe -> no barrier
        if (k + 1 < KNN) {               // prefetch next neighbor row
            int qn = myidx[k + 1];
            vk = vb[(size_t)qn*64 + lane];
        }
        float a0 = 0.f, a1 = 0.f, a2 = 0.f, a3 = 0.f;
        #pragma unroll
        for (int c = 0; c < 64; c += 4) {
            float4 h4 = *(const float4*)&hbuf[w][c];   // uniform-address broadcast read
            a0 = fmaf(h4.x, wcol[c    ], a0);
            a1 = fmaf(h4.y, wcol[c + 1], a1);
            a2 = fmaf(h4.z, wcol[c + 2], a2);
            a3 = fmaf(h4.w, wcol[c + 3], a3);
        }
        float o = fmaxf((a0 + a1) + (a2 + a3) + bias, 0.f);
        mx = fmaxf(mx, o);
        mn = fminf(mn, o);
        sm += o;
        sq = fmaf(o, o, sq);
    }
    pmax[(size_t)p*64 + lane] = mx;
    pmin[(size_t)p*64 + lane] = mn;
    psum[(size_t)p*64 + lane] = sm;
    psq [(size_t)p*64 + lane] = sq;
}

// ---------- BN1 applied after pooling (max if scale>=0 else min) ----------
__global__ void k_applypool(const float* __restrict__ pmax, const float* __restrict__ pmin,
                            const float* __restrict__ scale, const float* __restrict__ shift,
                            float* __restrict__ out) {
    int i = blockIdx.x*256 + threadIdx.x;
    int c = i & 63;
    float sc = scale[c];
    float pooled = (sc >= 0.f) ? pmax[i] : pmin[i];
    out[i] = sc*pooled + shift[c];
}

// ---------- per-column partial sums over 64-row blocks ----------
__global__ void k_colstats(const float* __restrict__ Hbuf, float* __restrict__ psum,
                           float* __restrict__ psq, int Cout) {
    int m0 = blockIdx.x*64, c0 = blockIdx.y*64;
    int t = threadIdx.x;
    int c = t & 63, rg = t >> 6;
    float s = 0.f, q = 0.f;
    #pragma unroll 4
    for (int r = 0; r < 16; r++) {
        float hv = Hbuf[(size_t)(m0 + rg*16 + r)*Cout + c0 + c];
        s += hv; q += hv*hv;
    }
    __shared__ float rs[256], rq[256];
    rs[t] = s; rq[t] = q; __syncthreads();
    if (t < 128) { rs[t] += rs[t+128]; rq[t] += rq[t+128]; }
    __syncthreads();
    if (t < 64) {
        rs[t] += rs[t+64]; rq[t] += rq[t+64];
        psum[(size_t)blockIdx.x*Cout + c0 + t] = rs[t];
        psq [(size_t)blockIdx.x*Cout + c0 + t] = rq[t];
    }
}

// ---------- log_softmax over 50 cols, one wave per row ----------
__global__ void k_logsoftmax(const float* __restrict__ logits, float* __restrict__ out) {
    int t = threadIdx.x;
    int n = blockIdx.x*4 + (t >> 6);
    int l = t & 63;
    float z = (l < 50) ? logits[(size_t)n*50 + l] : -INFINITY;
    float mx = z;
    #pragma unroll
    for (int off = 32; off >= 1; off >>= 1) mx = fmaxf(mx, __shfl_xor(mx, off, 64));
    float ex = (l < 50) ? expf(z - mx) : 0.f;
    float sm = ex;
    #pragma unroll
    for (int off = 32; off >= 1; off >>= 1) sm += __shfl_xor(sm, off, 64);
    float lse = mx + logf(sm);
    if (l < 50) out[(size_t)n*50 + l] = z - lse;
}

extern "C" void kernel_launch(void* const* d_in, const int* in_sizes, int n_in,
                              void* d_out, int out_size, void* d_ws, size_t ws_size,
                              hipStream_t stream) {
    (void)in_sizes; (void)n_in; (void)out_size;
    const float* x   = (const float*)d_in[0];
    const float* pos = (const float*)d_in[1];
    const float* prm[38];
    for (int i = 0; i < 38; i++) prm[i] = (const float*)d_in[3 + i];
    // prm: c1[0..7] c2[8..15] c3[16..23] l1[24..27] h0[28..31] h1[32..35] ho[36..37]

    float* ws = (float*)d_ws;
    size_t off = 0;
    auto alloc = [&](size_t cnt) { float* p = ws + off; off += (cnt + 63) & ~((size_t)63); return p; };
    float* f0   = alloc((size_t)NPT*6);
    float* x1   = alloc((size_t)NPT*64);
    float* x2   = alloc((size_t)NPT*64);
    float* x3   = alloc((size_t)NPT*64);
    float* u    = alloc((size_t)NPT*64);
    float* v    = alloc((size_t)NPT*64);
    float* pmax = alloc((size_t)NPT*64);
    float* pmin = alloc((size_t)NPT*64);
    int*   idx  = (int*)alloc((size_t)NPT*KNN);
    int*   ccnt = (int*)alloc(NPT);
    float* W1p  = alloc(64*64);
    float* b1p  = alloc(64);
    float* scaleA = alloc(1024);
    float* shiftA = alloc(1024);
    float* Wp   = alloc(1024*256);
    float* bp   = alloc(1024);
    ushort_t* Wpk1 = (ushort_t*)alloc(98304);    // l1 packed weights (192*1024 bf16)
    ushort_t* Wpk2 = (ushort_t*)alloc(131072);   // h0/h1 packed weights (max 1024*256 bf16)
    float* psum = alloc((size_t)NPT*64);
    float* psq  = alloc((size_t)NPT*64);
    float* big  = alloc((size_t)BNUM*PNUM*PNUM);   // shared: Dk (u16), then head activations
    if (off*sizeof(float) > ws_size) return;       // insufficient workspace -> leave poisoned

    // cand (NPT*KCAP ints = 4 MB) aliases psum (4 MB): dead ranges don't overlap in time
    int* cand = (int*)psum;
    ushort_t* Dk = (ushort_t*)big;

    auto conv = [&](const float* F, int C, const float* const* pp, float* xout) {
        if (C == 6) k_dist<6><<<dim3(16,16,8), 256, 0, stream>>>(F, Dk);
        else        k_dist<64><<<dim3(16,16,8), 256, 0, stream>>>(F, Dk);
        k_topk<<<NPT, 256, 0, stream>>>(Dk, cand, ccnt);
        if (C == 6) k_refine<6><<<NPT/4, 256, 0, stream>>>(F, cand, ccnt, idx);
        else        k_refine<64><<<NPT/4, 256, 0, stream>>>(F, cand, ccnt, idx);
        if (C == 6) k_uv<6><<<NPT/64, 256, 0, stream>>>(F, pp[0], pp[1], u, v);
        else        k_uv<64><<<NPT/64, 256, 0, stream>>>(F, pp[0], pp[1], u, v);
        k_e1stats<<<3840, 256, 0, stream>>>(u, v, idx, psum, psq);
        k_statsfin<<<64, 256, 0, stream>>>(psum, psq, 3840, 64, 1.f/((float)NPT*KNN),
                                           pp[2], pp[3], scaleA, shiftA);
        k_fold<<<64, 256, 0, stream>>>(pp[4], pp[5], scaleA, shiftA, W1p, b1p, 64, 64);
        k_e2<<<NPT/4, 256, 0, stream>>>(u, v, idx, W1p, b1p, pmax, pmin, psum, psq);
        k_statsfin<<<64, 256, 0, stream>>>(psum, psq, NPT, 64, 1.f/((float)NPT*KNN),
                                           pp[6], pp[7], scaleA, shiftA);
        k_applypool<<<NPT*64/256, 256, 0, stream>>>(pmax, pmin, scaleA, shiftA, xout);
    };

    k_concat6<<<NPT*6/256, 256, 0, stream>>>(x, pos, f0);
    k_pack<<<96, 256, 0, stream>>>(prm[24], Wpk1, 192, 1024);   // l1 weights (no fold needed)
    conv(f0, 6,  &prm[0],  x1);
    conv(x1, 64, &prm[8],  x2);
    conv(x2, 64, &prm[16], x3);

    float* Hb1    = big + 3145728;
    float* Hb2    = big + 19922944;
    float* Hb3    = big + 24117248;
    float* logits = big + 26214400;

    // l1: [x1|x2|x3] (16384x192) @ W (192x1024) + bias, ReLU — bf16 MFMA
    k_mgemm<1,1><<<dim3(NPT/128, 8), 256, 0, stream>>>(x1, x2, x3, Wpk1, prm[25], Hb1, 192, 1024);
    k_colstats<<<dim3(NPT/64, 16), 256, 0, stream>>>(Hb1, psum, psq, 1024);
    k_statsfin<<<1024, 256, 0, stream>>>(psum, psq, NPT/64, 1024, 1.f/(float)NPT,
                                         prm[26], prm[27], scaleA, shiftA);
    k_fold<<<256, 256, 0, stream>>>(prm[28], prm[29], scaleA, shiftA, Wp, bp, 1024, 256);
    k_pack<<<128, 256, 0, stream>>>(Wp, Wpk2, 1024, 256);
    k_mgemm<0,1><<<dim3(NPT/128, 2), 256, 0, stream>>>(Hb1, nullptr, nullptr, Wpk2, bp, Hb2, 1024, 256);
    k_colstats<<<dim3(NPT/64, 4), 256, 0, stream>>>(Hb2, psum, psq, 256);
    k_statsfin<<<256, 256, 0, stream>>>(psum, psq, NPT/64, 256, 1.f/(float)NPT,
                                        prm[30], prm[31], scaleA, shiftA);
    k_fold<<<128, 256, 0, stream>>>(prm[32], prm[33], scaleA, shiftA, Wp, bp, 256, 128);
    k_pack<<<16, 256, 0, stream>>>(Wp, Wpk2, 256, 128);
    k_mgemm<0,1><<<dim3(NPT/128, 1), 256, 0, stream>>>(Hb2, nullptr, nullptr, Wpk2, bp, Hb3, 256, 128);
    k_colstats<<<dim3(NPT/64, 2), 256, 0, stream>>>(Hb3, psum, psq, 128);
    k_statsfin<<<128, 256, 0, stream>>>(psum, psq, NPT/64, 128, 1.f/(float)NPT,
                                        prm[34], prm[35], scaleA, shiftA);
    k_fold<<<50, 256, 0, stream>>>(prm[36], prm[37], scaleA, shiftA, Wp, bp, 128, 50);
    k_gemm<0><<<dim3(NPT/64, 1), 256, 0, stream>>>(Hb3, Wp, bp, logits, NPT, 128, 50);
    k_logsoftmax<<<NPT/4, 256, 0, stream>>>(logits, (float*)d_out);
}

// Round 10
// 1144.555 us; speedup vs baseline: 3.4377x; 1.0101x over previous
//
#include <hip/hip_runtime.h>
#include <hip/hip_bf16.h>
#include <stdint.h>

#define BNUM 8
#define PNUM 2048
#define KNN  30
#define KSEL 40      // rank threshold for candidate selection
#define KCAP 64      // max candidates per row (one wave in refine)
#define NPT  (BNUM*PNUM)   // 16384
#define EPSF 1e-5f

typedef unsigned long long u64;
typedef unsigned short ushort_t;
typedef __attribute__((ext_vector_type(8))) short short8v;   // 8 bf16 (4 VGPRs)
typedef __attribute__((ext_vector_type(4))) float f32x4;

__device__ __forceinline__ unsigned mono_key(float d) {
    unsigned u = __float_as_uint(d);
    return (u & 0x80000000u) ? ~u : (u | 0x80000000u);   // monotone float->uint
}

__device__ __forceinline__ unsigned f2bf(float f) {      // f32 -> bf16 bits, RNE
    unsigned u = __float_as_uint(f);
    u += 0x7fffu + ((u >> 16) & 1u);
    return u >> 16;
}

__device__ __forceinline__ double lane_bcast64(double x, int l) {   // uniform l -> v_readlane
    union { double d; int i[2]; } a; a.d = x;
    union { int i[2]; double d; } r;
    r.i[0] = __builtin_amdgcn_readlane(a.i[0], l);
    r.i[1] = __builtin_amdgcn_readlane(a.i[1], l);
    return r.d;
}

// ---------- f0 = concat(x, pos) ----------
__global__ void k_concat6(const float* __restrict__ x, const float* __restrict__ pos,
                          float* __restrict__ f0) {
    int i = blockIdx.x*256 + threadIdx.x;        // < N*6
    int n = i/6, c = i%6;
    f0[i] = (c < 3) ? x[n*3 + c] : pos[n*3 + c - 3];
}

// ---------- dist 128x128 tile (snorm fused): Dk = top16(monokey(s_p+s_q-2 f_p.f_q)) ----------
template<int C>
__global__ __launch_bounds__(256) void k_dist(const float* __restrict__ F,
                                              ushort_t* __restrict__ Dk) {
    __shared__ float FpT[C][132];
    __shared__ float FqT[C][132];
    __shared__ float sp[128], sq[128];
    int b = blockIdx.z;
    int p0 = blockIdx.x*128, q0 = blockIdx.y*128;
    int t = threadIdx.x;
    for (int e = t; e < 128*C; e += 256) {
        int r = e / C, c = e % C;
        FpT[c][r] = F[(size_t)(b*PNUM + p0 + r)*C + c];
        FqT[c][r] = F[(size_t)(b*PNUM + q0 + r)*C + c];
    }
    __syncthreads();
    if (t < 128) {
        float a = 0.f;
        for (int c = 0; c < C; c++) { float xv = FpT[c][t]; a = fmaf(xv, xv, a); }
        sp[t] = a;
    } else {
        int r = t - 128;
        float a = 0.f;
        for (int c = 0; c < C; c++) { float xv = FqT[c][r]; a = fmaf(xv, xv, a); }
        sq[r] = a;
    }
    __syncthreads();
    int tc = (t & 15)*8, tr = (t >> 4)*8;
    float acc[8][8] = {};
    #pragma unroll 4
    for (int c = 0; c < C; c++) {
        float4 p0v = *(const float4*)&FpT[c][tr];
        float4 p1v = *(const float4*)&FpT[c][tr+4];
        float4 q0v = *(const float4*)&FqT[c][tc];
        float4 q1v = *(const float4*)&FqT[c][tc+4];
        float av[8] = {p0v.x,p0v.y,p0v.z,p0v.w,p1v.x,p1v.y,p1v.z,p1v.w};
        float bv[8] = {q0v.x,q0v.y,q0v.z,q0v.w,q1v.x,q1v.y,q1v.z,q1v.w};
        #pragma unroll
        for (int i = 0; i < 8; i++)
            #pragma unroll
            for (int j = 0; j < 8; j++) acc[i][j] = fmaf(av[i], bv[j], acc[i][j]);
    }
    #pragma unroll
    for (int i = 0; i < 8; i++) {
        unsigned ks[8];
        #pragma unroll
        for (int j = 0; j < 8; j++) {
            float d = sp[tr + i] + sq[tc + j] - 2.0f*acc[i][j];
            ks[j] = mono_key(d) >> 16;
        }
        uint4 w;
        w.x = ks[0] | (ks[1] << 16);
        w.y = ks[2] | (ks[3] << 16);
        w.z = ks[4] | (ks[5] << 16);
        w.w = ks[6] | (ks[7] << 16);
        *(uint4*)&Dk[(size_t)(b*PNUM + p0 + tr + i)*PNUM + q0 + tc] = w;
    }
}

// ---------- candidate select: binary search threshold on u16 keys; no atomics ----------
__global__ __launch_bounds__(256) void k_topk(const ushort_t* __restrict__ Dk,
                                              int* __restrict__ cand, int* __restrict__ ccnt) {
    __shared__ int red[4];
    __shared__ int wbase[4];
    int n = blockIdx.x, t = threadIdx.x, lane = t & 63, w = t >> 6;
    uint4 wv = *(const uint4*)(Dk + (size_t)n*PNUM + t*8);
    int ks[8];
    ks[0] = wv.x & 0xffff; ks[1] = wv.x >> 16;
    ks[2] = wv.y & 0xffff; ks[3] = wv.y >> 16;
    ks[4] = wv.z & 0xffff; ks[5] = wv.z >> 16;
    ks[6] = wv.w & 0xffff; ks[7] = wv.w >> 16;
    int lo = 0, hi = 65535;
    while (lo < hi) {                      // 16 iterations, block-uniform
        int mid = (lo + hi) >> 1;
        int c = 0;
        #pragma unroll
        for (int e = 0; e < 8; e++) c += (ks[e] <= mid);
        #pragma unroll
        for (int o = 32; o >= 1; o >>= 1) c += __shfl_xor(c, o, 64);
        if (lane == 0) red[w] = c;
        __syncthreads();
        int tot = red[0] + red[1] + red[2] + red[3];
        __syncthreads();
        if (tot >= KSEL) hi = mid; else lo = mid + 1;
    }
    int P = lo;
    int lc = 0;
    #pragma unroll
    for (int e = 0; e < 8; e++) lc += (ks[e] <= P);
    int pre = lc;                          // inclusive prefix within wave
    #pragma unroll
    for (int o = 1; o < 64; o <<= 1) { int vv = __shfl_up(pre, o, 64); if (lane >= o) pre += vv; }
    int excl = pre - lc;
    if (lane == 63) red[w] = pre;          // wave totals
    __syncthreads();
    if (t == 0) {
        int s0 = 0;
        #pragma unroll
        for (int i = 0; i < 4; i++) { wbase[i] = s0; s0 += red[i]; }
        ccnt[n] = (s0 < KCAP) ? s0 : KCAP;
    }
    __syncthreads();
    int base = wbase[w] + excl;
    #pragma unroll
    for (int e = 0; e < 8; e++) {
        if (ks[e] <= P) {
            if (base < KCAP) cand[(size_t)n*KCAP + base] = t*8 + e;
            base++;
        }
    }
}

// ---------- refine: f64 distances + all-pairs rank (no serial extraction) ----------
template<int C>
__global__ __launch_bounds__(256) void k_refine(const float* __restrict__ F,
                                                const int* __restrict__ cand,
                                                const int* __restrict__ ccnt,
                                                int* __restrict__ idx) {
    int t = threadIdx.x;
    int lane = t & 63;
    int row = blockIdx.x*4 + (t >> 6);
    int b = row >> 11;
    const float* fp = F + (size_t)row*C;
    int cnt = ccnt[row];
    bool act = lane < cnt;
    int q = act ? cand[(size_t)row*KCAP + lane] : (lane | 0x40000000);
    const float* fq = F + (size_t)(b*PNUM + (act ? q : 0))*C;
    double d = 1e300;
    if (act) {
        d = 0.0;
        if (C == 64) {
            #pragma unroll
            for (int c4 = 0; c4 < C/4; c4++) {
                float4 a = ((const float4*)fp)[c4];
                float4 bb = ((const float4*)fq)[c4];
                double d0 = (double)a.x - (double)bb.x;
                double d1 = (double)a.y - (double)bb.y;
                double d2 = (double)a.z - (double)bb.z;
                double d3 = (double)a.w - (double)bb.w;
                d += d0*d0 + d1*d1 + d2*d2 + d3*d3;
            }
        } else {
            #pragma unroll
            for (int c = 0; c < C; c++) {
                double df = (double)fp[c] - (double)fq[c];
                d += df*df;
            }
        }
    }
    int rank = 0;
    #pragma unroll 16
    for (int l = 0; l < 64; l++) {
        double dl = lane_bcast64(d, l);
        int ql = __builtin_amdgcn_readlane(q, l);
        rank += (dl < d) || (dl == d && ql < q);
    }
    if (act && rank < KNN) idx[(size_t)row*KNN + rank] = q;
}

// ---------- fused u/v GEMM: u = F@(W0a-W0b)+b0, v = F@W0b ----------
template<int C>
__global__ __launch_bounds__(256) void k_uv(const float* __restrict__ F,
                                            const float* __restrict__ W0,
                                            const float* __restrict__ b0,
                                            float* __restrict__ u, float* __restrict__ v) {
    __shared__ float As[64][17];
    __shared__ float Wa[16][64];
    __shared__ float Wb[16][64];
    int m0 = blockIdx.x*64;
    int t = threadIdx.x;
    int cb = (t & 15)*4, rb = (t >> 4)*4;
    float aU[4][4] = {}, aV[4][4] = {};
    for (int k0 = 0; k0 < C; k0 += 16) {
        #pragma unroll
        for (int j = 0; j < 4; j++) {
            int e = t + 256*j;
            int r = e >> 4, c = e & 15;
            As[r][c] = (k0 + c < C) ? F[(size_t)(m0 + r)*C + k0 + c] : 0.f;
        }
        {
            int r = t >> 4, c4 = (t & 15)*4;
            bool ok = (k0 + r < C);
            float4 wa = ok ? *(const float4*)&W0[(size_t)(k0 + r)*64 + c4] : make_float4(0,0,0,0);
            float4 wb = ok ? *(const float4*)&W0[(size_t)(C + k0 + r)*64 + c4] : make_float4(0,0,0,0);
            *(float4*)&Wa[r][c4] = wa;
            *(float4*)&Wb[r][c4] = wb;
        }
        __syncthreads();
        #pragma unroll
        for (int kk = 0; kk < 16; kk++) {
            float a[4];
            #pragma unroll
            for (int i = 0; i < 4; i++) a[i] = As[rb + i][kk];
            float4 wa4 = *(const float4*)&Wa[kk][cb];
            float4 wb4 = *(const float4*)&Wb[kk][cb];
            float wa[4] = {wa4.x, wa4.y, wa4.z, wa4.w};
            float wb[4] = {wb4.x, wb4.y, wb4.z, wb4.w};
            #pragma unroll
            for (int i = 0; i < 4; i++)
                #pragma unroll
                for (int j = 0; j < 4; j++) {
                    aU[i][j] = fmaf(a[i], wa[j] - wb[j], aU[i][j]);
                    aV[i][j] = fmaf(a[i], wb[j], aV[i][j]);
                }
        }
        __syncthreads();
    }
    #pragma unroll
    for (int i = 0; i < 4; i++) {
        int row = m0 + rb + i;
        #pragma unroll
        for (int j = 0; j < 4; j++) {
            int col = cb + j;
            u[(size_t)row*64 + col] = aU[i][j] + b0[col];
            v[(size_t)row*64 + col] = aV[i][j];
        }
    }
}

// ---------- 64-wide tiled f32 GEMM (final ho layer) ----------
template<int RELU>
__global__ __launch_bounds__(256) void k_gemm(const float* __restrict__ A,
                                              const float* __restrict__ W,
                                              const float* __restrict__ bias,
                                              float* __restrict__ out,
                                              int M, int Kd, int Nd) {
    __shared__ float As[64][17];
    __shared__ float Bs[16][64];
    int m0 = blockIdx.x*64, n0 = blockIdx.y*64;
    int t = threadIdx.x;
    int cb = (t & 15)*4, rb = (t >> 4)*4;
    float acc[4][4] = {};
    for (int k0 = 0; k0 < Kd; k0 += 16) {
        #pragma unroll
        for (int j = 0; j < 4; j++) {
            int e = t + 256*j;
            int r = e >> 4, c = e & 15;
            As[r][c] = (k0 + c < Kd) ? A[(size_t)(m0 + r)*Kd + k0 + c] : 0.f;
        }
        #pragma unroll
        for (int j = 0; j < 4; j++) {
            int e = t + 256*j;
            int r = e >> 6, c = e & 63;
            Bs[r][c] = (k0 + r < Kd && n0 + c < Nd) ? W[(size_t)(k0 + r)*Nd + n0 + c] : 0.f;
        }
        __syncthreads();
        #pragma unroll
        for (int kk = 0; kk < 16; kk++) {
            float a[4];
            #pragma unroll
            for (int i = 0; i < 4; i++) a[i] = As[rb + i][kk];
            float4 w4 = *(const float4*)&Bs[kk][cb];
            float w[4] = {w4.x, w4.y, w4.z, w4.w};
            #pragma unroll
            for (int i = 0; i < 4; i++)
                #pragma unroll
                for (int j = 0; j < 4; j++) acc[i][j] += a[i]*w[j];
        }
        __syncthreads();
    }
    #pragma unroll
    for (int i = 0; i < 4; i++) {
        int row = m0 + rb + i;
        #pragma unroll
        for (int j = 0; j < 4; j++) {
            int col = n0 + cb + j;
            if (col < Nd) {
                float v = acc[i][j] + (bias ? bias[col] : 0.f);
                if (RELU) v = fmaxf(v, 0.f);
                out[(size_t)row*Nd + col] = v;
            }
        }
    }
}

// ---------- pack f32 weights [Kd][Nd] -> bf16 fragment layout [(Kd/8)][Nd][8] ----------
__global__ void k_pack(const float* __restrict__ W, ushort_t* __restrict__ Wpk,
                       int Kd, int Nd) {
    int cell = blockIdx.x*256 + threadIdx.x;
    int ncell = (Kd >> 3)*Nd;
    if (cell >= ncell) return;
    int kg = cell / Nd, n = cell - kg*Nd;
    unsigned b[8];
    #pragma unroll
    for (int j = 0; j < 8; j++) b[j] = f2bf(W[(size_t)(kg*8 + j)*Nd + n]);
    uint4 wv;
    wv.x = b[0] | (b[1] << 16); wv.y = b[2] | (b[3] << 16);
    wv.z = b[4] | (b[5] << 16); wv.w = b[6] | (b[7] << 16);
    *(uint4*)&Wpk[(size_t)cell*8] = wv;
}

// ---------- bf16 MFMA GEMM: 128x128 tile, 4 waves (2x2 of 64x64), f32 out ----------
template<int CONCAT, int RELU>
__global__ __launch_bounds__(256) void k_mgemm(const float* __restrict__ A,
                                               const float* __restrict__ A2,
                                               const float* __restrict__ A3,
                                               const ushort_t* __restrict__ Wpk,
                                               const float* __restrict__ bias,
                                               float* __restrict__ out,
                                               int Kd, int Nd) {
    __shared__ ushort_t Al[4][128][8];   // [kgroup][row][8 bf16] = 8 KB
    __shared__ ushort_t Bl[4][128][8];   // [kgroup][col][8 bf16] = 8 KB
    int m0 = blockIdx.x*128, n0 = blockIdx.y*128;
    int t = threadIdx.x, lane = t & 63, w = t >> 6;
    int wm = (w >> 1)*64, wn = (w & 1)*64;
    f32x4 acc[4][4] = {};
    int arow = t >> 2, akg = t & 3;
    for (int k0 = 0; k0 < Kd; k0 += 32) {
        #pragma unroll
        for (int i = 0; i < 2; i++) {          // A: 512 cells, 2 per thread
            int row = arow + 64*i;
            int kb = k0 + akg*8;
            const float* src;
            if (CONCAT) {
                const float* s0 = (kb < 64) ? A : (kb < 128) ? A2 : A3;
                src = s0 + (size_t)(m0 + row)*64 + (kb & 63);
            } else {
                src = A + (size_t)(m0 + row)*Kd + kb;
            }
            float4 fa = *(const float4*)src;
            float4 fb = *(const float4*)(src + 4);
            uint4 wv;
            wv.x = f2bf(fa.x) | (f2bf(fa.y) << 16);
            wv.y = f2bf(fa.z) | (f2bf(fa.w) << 16);
            wv.z = f2bf(fb.x) | (f2bf(fb.y) << 16);
            wv.w = f2bf(fb.z) | (f2bf(fb.w) << 16);
            *(uint4*)&Al[akg][row][0] = wv;
        }
        #pragma unroll
        for (int i = 0; i < 2; i++) {          // B: 512 cells, contiguous copy
            int cell = t + 256*i;
            int kg = cell >> 7, col = cell & 127;
            *(uint4*)&Bl[kg][col][0] =
                *(const uint4*)&Wpk[((size_t)(k0/8 + kg)*Nd + n0 + col)*8];
        }
        __syncthreads();
        short8v af[4], bf[4];
        #pragma unroll
        for (int mf = 0; mf < 4; mf++)
            af[mf] = *(const short8v*)&Al[lane >> 4][wm + mf*16 + (lane & 15)][0];
        #pragma unroll
        for (int nf = 0; nf < 4; nf++)
            bf[nf] = *(const short8v*)&Bl[lane >> 4][wn + nf*16 + (lane & 15)][0];
        #pragma unroll
        for (int mf = 0; mf < 4; mf++)
            #pragma unroll
            for (int nf = 0; nf < 4; nf++)
                acc[mf][nf] = __builtin_amdgcn_mfma_f32_16x16x32_bf16(af[mf], bf[nf], acc[mf][nf], 0, 0, 0);
        __syncthreads();
    }
    int crow = (lane >> 4)*4;
    int ccol = lane & 15;
    #pragma unroll
    for (int nf = 0; nf < 4; nf++) {
        int col = n0 + wn + nf*16 + ccol;
        float bv = bias[col];
        #pragma unroll
        for (int mf = 0; mf < 4; mf++) {
            #pragma unroll
            for (int r = 0; r < 4; r++) {
                int row = m0 + wm + mf*16 + crow + r;
                float vv = acc[mf][nf][r] + bv;
                if (RELU) vv = fmaxf(vv, 0.f);
                out[(size_t)row*Nd + col] = vv;
            }
        }
    }
}

// ---------- stats of relu(u_p + v_q) over all edges (float4 vectorized) ----------
__global__ __launch_bounds__(256) void k_e1stats(const float* __restrict__ u,
                                                 const float* __restrict__ v,
                                                 const int* __restrict__ idx,
                                                 float* __restrict__ psum, float* __restrict__ psq) {
    int t = threadIdx.x;
    float s0 = 0.f, s1 = 0.f, s2 = 0.f, s3 = 0.f;
    float q0 = 0.f, q1 = 0.f, q2 = 0.f, q3 = 0.f;
    const int stride = 3840*256;
    int i = blockIdx.x*256 + t;
    int c4 = (i & 15)*4;                    // invariant across iterations
    #pragma unroll 1
    for (int j = 0; j < 8; j++, i += stride) {   // 30*16384*16 / (3840*256) = 8
        int edge = i >> 4;
        int p = edge / KNN;
        int q = idx[edge];
        int b = p >> 11;
        float4 uv = *(const float4*)&u[(size_t)p*64 + c4];
        float4 vv = *(const float4*)&v[(size_t)(b*PNUM + q)*64 + c4];
        float h0 = fmaxf(uv.x + vv.x, 0.f);
        float h1 = fmaxf(uv.y + vv.y, 0.f);
        float h2 = fmaxf(uv.z + vv.z, 0.f);
        float h3 = fmaxf(uv.w + vv.w, 0.f);
        s0 += h0; s1 += h1; s2 += h2; s3 += h3;
        q0 = fmaf(h0, h0, q0); q1 = fmaf(h1, h1, q1);
        q2 = fmaf(h2, h2, q2); q3 = fmaf(h3, h3, q3);
    }
    __shared__ float rs[16][16][4];   // [edge-slot][chan-group][comp]
    __shared__ float rq[16][16][4];
    int slot = t >> 4, g = t & 15;
    rs[slot][g][0] = s0; rs[slot][g][1] = s1; rs[slot][g][2] = s2; rs[slot][g][3] = s3;
    rq[slot][g][0] = q0; rq[slot][g][1] = q1; rq[slot][g][2] = q2; rq[slot][g][3] = q3;
    __syncthreads();
    if (t < 64) {
        int gg = t >> 2, comp = t & 3;
        float ss = 0.f, qq = 0.f;
        #pragma unroll
        for (int sl = 0; sl < 16; sl++) { ss += rs[sl][gg][comp]; qq += rq[sl][gg][comp]; }
        psum[(size_t)blockIdx.x*64 + t] = ss;
        psq [(size_t)blockIdx.x*64 + t] = qq;
    }
}

// ---------- finalize BN stats ----------
__global__ void k_statsfin(const float* __restrict__ psum, const float* __restrict__ psq,
                           int npart, int C, float invM,
                           const float* __restrict__ g, const float* __restrict__ be,
                           float* __restrict__ scale, float* __restrict__ shift) {
    int c = blockIdx.x, t = threadIdx.x;
    float s = 0.f, q = 0.f;
    for (int i = t; i < npart; i += 256) {
        s += psum[(size_t)i*C + c];
        q += psq [(size_t)i*C + c];
    }
    __shared__ float rs[256], rq[256];
    rs[t] = s; rq[t] = q; __syncthreads();
    for (int off = 128; off >= 1; off >>= 1) {
        if (t < off) { rs[t] += rs[t+off]; rq[t] += rq[t+off]; }
        __syncthreads();
    }
    if (t == 0) {
        float m   = rs[0]*invM;
        float var = rq[0]*invM - m*m;
        float inv = rsqrtf(var + EPSF);
        float sc  = g[c]*inv;
        scale[c] = sc;
        shift[c] = be[c] - m*sc;
    }
}

// ---------- fold BN affine into next linear ----------
__global__ void k_fold(const float* __restrict__ W, const float* __restrict__ b,
                       const float* __restrict__ scale, const float* __restrict__ shift,
                       float* __restrict__ Wp, float* __restrict__ bp, int Cin, int Cout) {
    int co = blockIdx.x, t = threadIdx.x;
    float acc = 0.f;
    for (int ci = t; ci < Cin; ci += 256) {
        float w = W[(size_t)ci*Cout + co];
        Wp[(size_t)ci*Cout + co] = scale[ci]*w;
        acc += shift[ci]*w;
    }
    __shared__ float r[256];
    r[t] = acc; __syncthreads();
    for (int off = 128; off >= 1; off >>= 1) { if (t < off) r[t] += r[t+off]; __syncthreads(); }
    if (t == 0) bp[co] = b[co] + r[0];
}

// ---------- edge layer 1: wave-per-point; wcol pinned in VGPRs; LDS only for h broadcast ----------
__global__ __launch_bounds__(256, 4) void k_e2(const float* __restrict__ u, const float* __restrict__ v,
                                               const int* __restrict__ idx,
                                               const float* __restrict__ W1p, const float* __restrict__ b1p,
                                               float* __restrict__ pmax, float* __restrict__ pmin,
                                               float* __restrict__ psum, float* __restrict__ psq) {
    __shared__ float hbuf[4][64];      // wave-private h vectors (1 KB)
    int t = threadIdx.x, lane = t & 63, w = t >> 6;
    int p = blockIdx.x*4 + w;
    int b = p >> 11;
    // W1 column for this lane, loaded from global (L2-resident) and PINNED in VGPRs:
    // the empty asm with "+v" forces materialization — compiler cannot rematerialize
    // these as per-use LDS/global reads inside the k-loop (round-9: VGPR=52 proved it did).
    float wcol[64];
    #pragma unroll
    for (int c = 0; c < 64; c++) wcol[c] = W1p[c*64 + lane];
    #pragma unroll
    for (int c = 0; c < 64; c++) asm volatile("" : "+v"(wcol[c]));
    float ureg = u[(size_t)p*64 + lane];
    float bias = b1p[lane];
    const int* myidx = idx + (size_t)p*KNN;
    const float* vb = v + (size_t)b*PNUM*64;
    float mx = -1e30f, mn = 1e30f, sm = 0.f, sq = 0.f;
    int q = myidx[0];
    float vk = vb[(size_t)q*64 + lane];
    #pragma unroll 1
    for (int k = 0; k < KNN; k++) {
        float h = fmaxf(ureg + vk, 0.f);
        hbuf[w][lane] = h;               // wave-private; in-order DS pipe -> no barrier
        if (k + 1 < KNN) {               // prefetch next neighbor row
            int qn = myidx[k + 1];
            vk = vb[(size_t)qn*64 + lane];
        }
        float a0 = 0.f, a1 = 0.f, a2 = 0.f, a3 = 0.f;
        #pragma unroll
        for (int c = 0; c < 64; c += 4) {
            float4 h4 = *(const float4*)&hbuf[w][c];   // uniform-address broadcast read
            a0 = fmaf(h4.x, wcol[c    ], a0);
            a1 = fmaf(h4.y, wcol[c + 1], a1);
            a2 = fmaf(h4.z, wcol[c + 2], a2);
            a3 = fmaf(h4.w, wcol[c + 3], a3);
        }
        float o = fmaxf((a0 + a1) + (a2 + a3) + bias, 0.f);
        mx = fmaxf(mx, o);
        mn = fminf(mn, o);
        sm += o;
        sq = fmaf(o, o, sq);
    }
    pmax[(size_t)p*64 + lane] = mx;
    pmin[(size_t)p*64 + lane] = mn;
    psum[(size_t)p*64 + lane] = sm;
    psq [(size_t)p*64 + lane] = sq;
}

// ---------- BN1 applied after pooling (max if scale>=0 else min) ----------
__global__ void k_applypool(const float* __restrict__ pmax, const float* __restrict__ pmin,
                            const float* __restrict__ scale, const float* __restrict__ shift,
                            float* __restrict__ out) {
    int i = blockIdx.x*256 + threadIdx.x;
    int c = i & 63;
    float sc = scale[c];
    float pooled = (sc >= 0.f) ? pmax[i] : pmin[i];
    out[i] = sc*pooled + shift[c];
}

// ---------- per-column partial sums over 64-row blocks ----------
__global__ void k_colstats(const float* __restrict__ Hbuf, float* __restrict__ psum,
                           float* __restrict__ psq, int Cout) {
    int m0 = blockIdx.x*64, c0 = blockIdx.y*64;
    int t = threadIdx.x;
    int c = t & 63, rg = t >> 6;
    float s = 0.f, q = 0.f;
    #pragma unroll 4
    for (int r = 0; r < 16; r++) {
        float hv = Hbuf[(size_t)(m0 + rg*16 + r)*Cout + c0 + c];
        s += hv; q += hv*hv;
    }
    __shared__ float rs[256], rq[256];
    rs[t] = s; rq[t] = q; __syncthreads();
    if (t < 128) { rs[t] += rs[t+128]; rq[t] += rq[t+128]; }
    __syncthreads();
    if (t < 64) {
        rs[t] += rs[t+64]; rq[t] += rq[t+64];
        psum[(size_t)blockIdx.x*Cout + c0 + t] = rs[t];
        psq [(size_t)blockIdx.x*Cout + c0 + t] = rq[t];
    }
}

// ---------- log_softmax over 50 cols, one wave per row ----------
__global__ void k_logsoftmax(const float* __restrict__ logits, float* __restrict__ out) {
    int t = threadIdx.x;
    int n = blockIdx.x*4 + (t >> 6);
    int l = t & 63;
    float z = (l < 50) ? logits[(size_t)n*50 + l] : -INFINITY;
    float mx = z;
    #pragma unroll
    for (int off = 32; off >= 1; off >>= 1) mx = fmaxf(mx, __shfl_xor(mx, off, 64));
    float ex = (l < 50) ? expf(z - mx) : 0.f;
    float sm = ex;
    #pragma unroll
    for (int off = 32; off >= 1; off >>= 1) sm += __shfl_xor(sm, off, 64);
    float lse = mx + logf(sm);
    if (l < 50) out[(size_t)n*50 + l] = z - lse;
}

extern "C" void kernel_launch(void* const* d_in, const int* in_sizes, int n_in,
                              void* d_out, int out_size, void* d_ws, size_t ws_size,
                              hipStream_t stream) {
    (void)in_sizes; (void)n_in; (void)out_size;
    const float* x   = (const float*)d_in[0];
    const float* pos = (const float*)d_in[1];
    const float* prm[38];
    for (int i = 0; i < 38; i++) prm[i] = (const float*)d_in[3 + i];
    // prm: c1[0..7] c2[8..15] c3[16..23] l1[24..27] h0[28..31] h1[32..35] ho[36..37]

    float* ws = (float*)d_ws;
    size_t off = 0;
    auto alloc = [&](size_t cnt) { float* p = ws + off; off += (cnt + 63) & ~((size_t)63); return p; };
    float* f0   = alloc((size_t)NPT*6);
    float* x1   = alloc((size_t)NPT*64);
    float* x2   = alloc((size_t)NPT*64);
    float* x3   = alloc((size_t)NPT*64);
    float* u    = alloc((size_t)NPT*64);
    float* v    = alloc((size_t)NPT*64);
    float* pmax = alloc((size_t)NPT*64);
    float* pmin = alloc((size_t)NPT*64);
    int*   idx  = (int*)alloc((size_t)NPT*KNN);
    int*   ccnt = (int*)alloc(NPT);
    float* W1p  = alloc(64*64);
    float* b1p  = alloc(64);
    float* scaleA = alloc(1024);
    float* shiftA = alloc(1024);
    float* Wp   = alloc(1024*256);
    float* bp   = alloc(1024);
    ushort_t* Wpk1 = (ushort_t*)alloc(98304);    // l1 packed weights (192*1024 bf16)
    ushort_t* Wpk2 = (ushort_t*)alloc(131072);   // h0/h1 packed weights (max 1024*256 bf16)
    float* psum = alloc((size_t)NPT*64);
    float* psq  = alloc((size_t)NPT*64);
    float* big  = alloc((size_t)BNUM*PNUM*PNUM);   // shared: Dk (u16), then head activations
    if (off*sizeof(float) > ws_size) return;       // insufficient workspace -> leave poisoned

    // cand (NPT*KCAP ints = 4 MB) aliases psum (4 MB): dead ranges don't overlap in time
    int* cand = (int*)psum;
    ushort_t* Dk = (ushort_t*)big;

    auto conv = [&](const float* F, int C, const float* const* pp, float* xout) {
        if (C == 6) k_dist<6><<<dim3(16,16,8), 256, 0, stream>>>(F, Dk);
        else        k_dist<64><<<dim3(16,16,8), 256, 0, stream>>>(F, Dk);
        k_topk<<<NPT, 256, 0, stream>>>(Dk, cand, ccnt);
        if (C == 6) k_refine<6><<<NPT/4, 256, 0, stream>>>(F, cand, ccnt, idx);
        else        k_refine<64><<<NPT/4, 256, 0, stream>>>(F, cand, ccnt, idx);
        if (C == 6) k_uv<6><<<NPT/64, 256, 0, stream>>>(F, pp[0], pp[1], u, v);
        else        k_uv<64><<<NPT/64, 256, 0, stream>>>(F, pp[0], pp[1], u, v);
        k_e1stats<<<3840, 256, 0, stream>>>(u, v, idx, psum, psq);
        k_statsfin<<<64, 256, 0, stream>>>(psum, psq, 3840, 64, 1.f/((float)NPT*KNN),
                                           pp[2], pp[3], scaleA, shiftA);
        k_fold<<<64, 256, 0, stream>>>(pp[4], pp[5], scaleA, shiftA, W1p, b1p, 64, 64);
        k_e2<<<NPT/4, 256, 0, stream>>>(u, v, idx, W1p, b1p, pmax, pmin, psum, psq);
        k_statsfin<<<64, 256, 0, stream>>>(psum, psq, NPT, 64, 1.f/((float)NPT*KNN),
                                           pp[6], pp[7], scaleA, shiftA);
        k_applypool<<<NPT*64/256, 256, 0, stream>>>(pmax, pmin, scaleA, shiftA, xout);
    };

    k_concat6<<<NPT*6/256, 256, 0, stream>>>(x, pos, f0);
    k_pack<<<96, 256, 0, stream>>>(prm[24], Wpk1, 192, 1024);   // l1 weights (no fold needed)
    conv(f0, 6,  &prm[0],  x1);
    conv(x1, 64, &prm[8],  x2);
    conv(x2, 64, &prm[16], x3);

    float* Hb1    = big + 3145728;
    float* Hb2    = big + 19922944;
    float* Hb3    = big + 24117248;
    float* logits = big + 26214400;

    // l1: [x1|x2|x3] (16384x192) @ W (192x1024) + bias, ReLU — bf16 MFMA
    k_mgemm<1,1><<<dim3(NPT/128, 8), 256, 0, stream>>>(x1, x2, x3, Wpk1, prm[25], Hb1, 192, 1024);
    k_colstats<<<dim3(NPT/64, 16), 256, 0, stream>>>(Hb1, psum, psq, 1024);
    k_statsfin<<<1024, 256, 0, stream>>>(psum, psq, NPT/64, 1024, 1.f/(float)NPT,
                                         prm[26], prm[27], scaleA, shiftA);
    k_fold<<<256, 256, 0, stream>>>(prm[28], prm[29], scaleA, shiftA, Wp, bp, 1024, 256);
    k_pack<<<128, 256, 0, stream>>>(Wp, Wpk2, 1024, 256);
    k_mgemm<0,1><<<dim3(NPT/128, 2), 256, 0, stream>>>(Hb1, nullptr, nullptr, Wpk2, bp, Hb2, 1024, 256);
    k_colstats<<<dim3(NPT/64, 4), 256, 0, stream>>>(Hb2, psum, psq, 256);
    k_statsfin<<<256, 256, 0, stream>>>(psum, psq, NPT/64, 256, 1.f/(float)NPT,
                                        prm[30], prm[31], scaleA, shiftA);
    k_fold<<<128, 256, 0, stream>>>(prm[32], prm[33], scaleA, shiftA, Wp, bp, 256, 128);
    k_pack<<<16, 256, 0, stream>>>(Wp, Wpk2, 256, 128);
    k_mgemm<0,1><<<dim3(NPT/128, 1), 256, 0, stream>>>(Hb2, nullptr, nullptr, Wpk2, bp, Hb3, 256, 128);
    k_colstats<<<dim3(NPT/64, 2), 256, 0, stream>>>(Hb3, psum, psq, 128);
    k_statsfin<<<128, 256, 0, stream>>>(psum, psq, NPT/64, 128, 1.f/(float)NPT,
                                        prm[34], prm[35], scaleA, shiftA);
    k_fold<<<50, 256, 0, stream>>>(prm[36], prm[37], scaleA, shiftA, Wp, bp, 128, 50);
    k_gemm<0><<<dim3(NPT/64, 1), 256, 0, stream>>>(Hb3, Wp, bp, logits, NPT, 128, 50);
    k_logsoftmax<<<NPT/4, 256, 0, stream>>>(logits, (float*)d_out);
}